// Round 14
// baseline (1562.767 us; speedup 1.0000x reference)
//
#include <hip/hip_runtime.h>
#include <math.h>

#define BB 2
#define SEQ 4096
#define HID 2048
#define HV 32
#define HK 16
#define DK 128
#define DV 128
#define CHUNK 64
#define NCH 64
#define KEY_DIM 2048
#define VAL_DIM 4096
#define CONV_DIM 8192
#define BS 8192   // BB*SEQ
#define CTS 8     // conv s-tile

typedef unsigned short u16;
typedef __attribute__((ext_vector_type(8))) __bf16 bf16x8;
typedef __attribute__((ext_vector_type(4))) float f32x4;
typedef __attribute__((ext_vector_type(4))) unsigned short u16x4;
typedef __attribute__((ext_vector_type(8))) unsigned short u16x8;

__device__ __forceinline__ float bf2f(u16 x){
  return (float)__builtin_bit_cast(__bf16, x);
}
__device__ __forceinline__ u16 f2bf(float f){
  return __builtin_bit_cast(u16, (__bf16)f);
}

// async global->LDS, 16B per lane; LDS dest is wave-uniform base + lane*16
__device__ __forceinline__ void gl_lds16(const u16* g, u16* l){
  __builtin_amdgcn_global_load_lds((const __attribute__((address_space(1))) void*)g,
                                   (__attribute__((address_space(3))) void*)l, 16, 0, 0);
}

// ---------------------------------------------------------------- f32 -> bf16 cast (vectorized, grid-stride)
__global__ __launch_bounds__(256) void cast_bf(const float* __restrict__ in, u16* __restrict__ out, int n8){
  int i = blockIdx.x*256 + threadIdx.x;
  const int stride = gridDim.x*256;
  for(; i < n8; i += stride){
    float4 a = ((const float4*)in)[(size_t)i*2];
    float4 b = ((const float4*)in)[(size_t)i*2+1];
    u16x8 t;
    t[0]=f2bf(a.x); t[1]=f2bf(a.y); t[2]=f2bf(a.z); t[3]=f2bf(a.w);
    t[4]=f2bf(b.x); t[5]=f2bf(b.y); t[6]=f2bf(b.z); t[7]=f2bf(b.w);
    ((u16x8*)out)[i] = t;
  }
}

// ---------------------------------------------------------------- weight transpose: src [R,C] f32 -> dst [C,R] bf16
__global__ __launch_bounds__(256) void transpose_cast(const float* __restrict__ src, u16* __restrict__ dst, int R, int C){
  __shared__ float tile[32][33];
  int c0 = blockIdx.x*32, r0 = blockIdx.y*32;
  int tx = threadIdx.x & 31, ty = threadIdx.x >> 5;   // ty 0..7
  for(int i = ty; i < 32; i += 8) tile[i][tx] = src[(size_t)(r0+i)*C + c0 + tx];
  __syncthreads();
  for(int i = ty; i < 32; i += 8) dst[(size_t)(c0+i)*R + r0 + tx] = f2bf(tile[tx][i]);
}

// ---------------------------------------------------------------- k transpose (per batch): kb [HK][SEQ][DK] -> kbT [HK][DK][SEQ]
__global__ __launch_bounds__(256) void transpose_k(const u16* __restrict__ kb, u16* __restrict__ kbT){
  __shared__ u16 tile[32][33];
  const int h = blockIdx.z, d0 = blockIdx.y*32, s0 = blockIdx.x*32;
  const int tx = threadIdx.x & 31, ty = threadIdx.x >> 5;
  const u16* src = kb + (size_t)h*SEQ*DK;
  for(int i = ty; i < 32; i += 8) tile[i][tx] = src[(size_t)(s0+i)*DK + d0 + tx];
  __syncthreads();
  u16* dst = kbT + (size_t)h*DK*SEQ;
  for(int i = ty; i < 32; i += 8) dst[(size_t)(d0+i)*SEQ + s0 + tx] = tile[tx][i];
}

// ---------------------------------------------------------------- GEMM bf16, 256x256 tile, BK=32, 8 waves, dbuf gl_lds
// LDS 64KB -> 2 blocks/CU (TLP covers the barrier drain).
// Swizzle (64B rows, 4 granules): phys granule = row*4 + (logical ^ ((row>>1)&3));
// applied inversely on the global source (linear gl_lds dest) and directly on ds_read.
__device__ __forceinline__ void store_c(float* C, size_t idx, float v){ C[idx] = v; }
__device__ __forceinline__ void store_c(u16*   C, size_t idx, float v){ C[idx] = f2bf(v); }

__device__ __forceinline__ void stage32(const u16* __restrict__ A, const u16* __restrict__ Bt,
                                        size_t bm, size_t bn, int K, int k0,
                                        u16* Ab, u16* Bb, int tid){
  const int wave = tid >> 6;
  #pragma unroll
  for(int j = 0; j < 2; ++j){
    const int p = j*512 + tid;          // this thread's phys granule
    const int row = p >> 2;             // 0..255
    const int g = (p & 3) ^ ((row >> 1) & 3);
    const int dst = (j*512 + wave*64) * 8;   // wave-uniform base (u16 units)
    gl_lds16(&A [(bm + row)*K + k0 + g*8], &Ab[dst]);
    gl_lds16(&Bt[(bn + row)*K + k0 + g*8], &Bb[dst]);
  }
}

template<typename CT>
__global__ __launch_bounds__(512) void gemm256(const u16* __restrict__ A, const u16* __restrict__ Bt,
                                               CT* __restrict__ C, int M, int N, int K){
  (void)M;
  __shared__ u16 As[2][8192];   // [buf][256 rows x 32 cols], 16KB each
  __shared__ u16 Bs[2][8192];
  const int tid  = threadIdx.x;
  const int lane = tid & 63;
  const int wave = tid >> 6;       // 0..7
  // bijective XCD-chunked swizzle (all grids have nwg % 8 == 0)
  const int nwg = gridDim.x * gridDim.y;
  const int old = blockIdx.y * gridDim.x + blockIdx.x;
  const int nid = (old & 7) * (nwg >> 3) + (old >> 3);
  const int bx = nid % gridDim.x, by = nid / gridDim.x;
  const size_t bm = (size_t)by * 256;
  const size_t bn = (size_t)bx * 256;
  const int wm = (wave >> 2) * 128;     // 0 / 128
  const int wn = (wave & 3) * 64;       // 0 / 64 / 128 / 192
  const int ah = wave >> 2;             // A half (rows ah*128..)
  const int bh = (wave & 3) >> 1;       // B half
  const int lwn = wn & 64;              // B row base within half
  const int cL15 = lane & 15, qq = lane >> 4;
  f32x4 acc[8][4] = {};
  const int nk = K >> 5;
  stage32(A, Bt, bm, bn, K, 0, As[0], Bs[0], tid);
  __syncthreads();
  int cur = 0;
  for(int kt = 0; kt < nk; ++kt){
    if(kt+1 < nk)
      stage32(A, Bt, bm, bn, K, (kt+1) << 5, As[cur^1], Bs[cur^1], tid);
    const u16* Ah = &As[cur][ah*4096];
    const u16* Bh = &Bs[cur][bh*4096];
    __builtin_amdgcn_s_setprio(1);
    bf16x8 af[8], bfr[4];
    #pragma unroll
    for(int mi = 0; mi < 8; ++mi){
      int lr = mi*16 + cL15;
      int gr = lr*4 + (qq ^ ((lr >> 1) & 3));
      af[mi] = *(const bf16x8*)&Ah[gr*8];
    }
    #pragma unroll
    for(int ni = 0; ni < 4; ++ni){
      int lr = lwn + ni*16 + cL15;
      int gr = lr*4 + (qq ^ ((lr >> 1) & 3));
      bfr[ni] = *(const bf16x8*)&Bh[gr*8];
    }
    #pragma unroll
    for(int mi = 0; mi < 8; ++mi)
      #pragma unroll
      for(int ni = 0; ni < 4; ++ni)
        acc[mi][ni] = __builtin_amdgcn_mfma_f32_16x16x32_bf16(af[mi], bfr[ni], acc[mi][ni], 0, 0, 0);
    __builtin_amdgcn_s_setprio(0);
    __syncthreads();   // drains gl_lds (vmcnt0) + all waves done with buf cur
    cur ^= 1;
  }
  const int c0 = (int)bn + wn + cL15;
  const int r0 = (int)bm + wm + qq*4;
  #pragma unroll
  for(int mi = 0; mi < 8; ++mi)
    #pragma unroll
    for(int ni = 0; ni < 4; ++ni)
      #pragma unroll
      for(int rr = 0; rr < 4; ++rr)
        store_c(C, (size_t)(r0 + mi*16 + rr)*N + (c0 + ni*16), acc[mi][ni][rr]);
}

// ---------------------------------------------------------------- beta/g projections (per batch), fp32 exact
__global__ __launch_bounds__(256) void proj_bg(const float* __restrict__ hs, const float* __restrict__ Wb,
      const float* __restrict__ Wa, const float* __restrict__ dtb, const float* __restrict__ A_log,
      float* __restrict__ betab, float* __restrict__ gbuf){
  __shared__ float h4[4][HID];          // 32KB: 4 rows of hs
  __shared__ float part[4][64][4];
  const int r0 = blockIdx.x * 4;
  const int tid = threadIdx.x;
  for(int i = tid; i < 4*HID/4; i += 256)
    ((float4*)&h4[0][0])[i] = ((const float4*)&hs[(size_t)r0*HID])[i];
  __syncthreads();
  const int o = tid & 63, pp = tid >> 6;
  const float* W = (o < 32) ? (Wb + o) : (Wa + (o - 32));
  float a0=0.f,a1=0.f,a2=0.f,a3=0.f;
  const int kbeg = pp*512;
  for(int kk = kbeg; kk < kbeg+512; ++kk){
    float wv = W[(size_t)kk*32];
    a0 += wv*h4[0][kk]; a1 += wv*h4[1][kk]; a2 += wv*h4[2][kk]; a3 += wv*h4[3][kk];
  }
  part[0][o][pp]=a0; part[1][o][pp]=a1; part[2][o][pp]=a2; part[3][o][pp]=a3;
  __syncthreads();
  {
    const int row = tid >> 6, oo = tid & 63;
    float sdot = part[row][oo][0]+part[row][oo][1]+part[row][oo][2]+part[row][oo][3];
    const int s = r0 + row;
    if(oo < 32){
      betab[(size_t)oo*SEQ + s] = 1.f/(1.f + __expf(-sdot));
    } else {
      const int hh = oo - 32;
      float x = sdot + dtb[hh];
      float sp = (x > 20.f) ? x : log1pf(__expf(x));
      gbuf[(size_t)hh*SEQ + s] = -__expf(A_log[hh]) * sp;
    }
  }
}

// ---------------------------------------------------------------- conv(4) + SiLU + split + l2norm -> bf16 (per batch)
__global__ __launch_bounds__(128) void conv_qkv(const u16* __restrict__ mixed, const float* __restrict__ conv_w,
      u16* __restrict__ qb, u16* __restrict__ kb, u16* __restrict__ vb){
  const int slot = blockIdx.x;          // 0..63  (16 q heads, 16 k heads, 32 v heads)
  const int s0 = blockIdx.y * CTS;      // 0..4095 step CTS
  const int t = threadIdx.x;            // 0..127
  const int c = slot*128 + t;
  __shared__ float red[CTS][2];
  float m[CTS+3];
  #pragma unroll
  for(int j = 0; j < CTS+3; ++j){
    int ss = s0 - 3 + j;
    m[j] = (ss >= 0) ? bf2f(mixed[(size_t)ss*CONV_DIM + c]) : 0.f;
  }
  const float w0 = conv_w[c*4+0], w1 = conv_w[c*4+1], w2 = conv_w[c*4+2], w3 = conv_w[c*4+3];
  float acc[CTS];
  #pragma unroll
  for(int i = 0; i < CTS; ++i){
    float a = 0.f;
    a += w0*m[i]; a += w1*m[i+1]; a += w2*m[i+2]; a += w3*m[i+3];
    acc[i] = a / (1.f + __expf(-a));    // SiLU
  }
  if(slot < 32){
    #pragma unroll
    for(int i = 0; i < CTS; ++i){
      float sq = acc[i]*acc[i];
      #pragma unroll
      for(int off = 1; off < 64; off <<= 1) sq += __shfl_xor(sq, off, 64);
      if((t & 63) == 0) red[i][t >> 6] = sq;
    }
    __syncthreads();
    #pragma unroll
    for(int i = 0; i < CTS; ++i){
      const int s = s0 + i;
      float rn = rsqrtf(red[i][0] + red[i][1] + 1e-6f);
      if(slot < 16)
        qb[((size_t)slot*SEQ + s)*DK + t] = f2bf(acc[i] * rn * 0.08838834764831845f); // * DK^-0.5
      else
        kb[((size_t)(slot-16)*SEQ + s)*DK + t] = f2bf(acc[i] * rn);
    }
  } else {
    #pragma unroll
    for(int i = 0; i < CTS; ++i)
      vb[((size_t)(slot-32)*SEQ + s0+i)*DV + t] = f2bf(acc[i]);
  }
}

// ---------------------------------------------------------------- phase A (per batch), MFMA version
__global__ __launch_bounds__(256) void phaseA(const u16* __restrict__ qb, const u16* __restrict__ kb,
      const u16* __restrict__ vb, const float* __restrict__ betab, const float* __restrict__ gb,
      float* __restrict__ gcb, u16* __restrict__ ub, u16* __restrict__ wb, u16* __restrict__ attnb){
  __shared__ __align__(16) char arena[63232];
  u16*   kS  = (u16*)(arena);
  u16*   qS  = (u16*)(arena + 17408);
  u16*   XT  = (u16*)(arena + 17408);
  u16*   VT  = (u16*)(arena + 17408);
  float* Ms  = (float*)(arena + 35840);
  u16*   vS  = (u16*)(arena + 35840);
  u16*   Tb  = (u16*)(arena + 53248);
  float* gcs   = (float*)(arena + 62464);
  float* betas = gcs + 64;
  float* wsc   = gcs + 128;

  const int n = blockIdx.x, h = blockIdx.y;
  const int hk = h >> 1;
  const int s0 = n * CHUNK;
  const int tid = threadIdx.x;
  const int lane = tid & 63;
  const int wave = tid >> 6;
  const int R0 = wave * 16;
  const size_t hS = (size_t)h*SEQ;
  const u16* kbase = kb + ((size_t)hk*SEQ + s0)*DK;
  const u16* qbase = qb + ((size_t)hk*SEQ + s0)*DK;
  const u16* vbase = vb + ((size_t)h*SEQ + s0)*DV;
  const size_t atbase = ((size_t)h*NCH + n)*64*64;
  const size_t uwbase = ((size_t)h*NCH + n)*64*128;

  // ---- phase 1: stage k,q; prefetch v into regs (used phase 5); gc scan ----
  u16x8 pv[4];
  #pragma unroll
  for(int e2 = 0; e2 < 4; ++e2){
    int e = tid + e2*256;
    int r = e >> 4, c8 = (e & 15)*8;
    pv[e2] = *(const u16x8*)&vbase[(size_t)r*128 + c8];
  }
  for(int e = tid; e < 1024; e += 256){
    int r = e >> 4, c8 = (e & 15)*8;
    *(u16x8*)&kS[r*136 + c8] = *(const u16x8*)&kbase[(size_t)r*128 + c8];
    *(u16x8*)&qS[r*136 + c8] = *(const u16x8*)&qbase[(size_t)r*128 + c8];
  }
  if(wave == 0){
    float v = gb[hS + s0 + lane];
    #pragma unroll
    for(int off = 1; off < 64; off <<= 1){
      float t = __shfl(v, (lane >= off) ? (lane - off) : lane, 64);
      if(lane >= off) v += t;
    }
    gcs[lane] = v;
    gcb[hS + s0 + lane] = v;
    float b = betab[hS + s0 + lane];
    betas[lane] = b;
    wsc[lane] = b * __expf(v);
  }
  __syncthreads();

  // ---- phase 2: S1 = k.k^T, S2 = q.k^T via MFMA; write Ms (f32) + attn (bf16) ----
  {
    f32x4 a1[4] = {}, a2[4] = {};
    #pragma unroll
    for(int ks = 0; ks < 4; ++ks){
      const int ab = (R0 + (lane & 15))*272 + ks*64 + (lane >> 4)*16;
      bf16x8 afk = *(const bf16x8*)((const char*)kS + ab);
      bf16x8 afq = *(const bf16x8*)((const char*)qS + ab);
      #pragma unroll
      for(int jt = 0; jt < 4; ++jt){
        const int bb = (jt*16 + (lane & 15))*272 + ks*64 + (lane >> 4)*16;
        bf16x8 bf = *(const bf16x8*)((const char*)kS + bb);
        a1[jt] = __builtin_amdgcn_mfma_f32_16x16x32_bf16(afk, bf, a1[jt], 0, 0, 0);
        a2[jt] = __builtin_amdgcn_mfma_f32_16x16x32_bf16(afq, bf, a2[jt], 0, 0, 0);
      }
    }
    #pragma unroll
    for(int jt = 0; jt < 4; ++jt){
      int j = jt*16 + (lane & 15);
      float gj = gcs[j];
      #pragma unroll
      for(int r = 0; r < 4; ++r){
        int i = R0 + (lane >> 4)*4 + r;
        float gi = gcs[i];
        float dec = (j <= i) ? __expf(gi - gj) : 0.f;
        Ms[i*64 + j] = (j < i) ? betas[i]*a1[jt][r]*dec : 0.f;
        attnb[atbase + (size_t)i*64 + j] = f2bf(a2[jt][r]*dec);
      }
    }
  }
  __syncthreads();

  // ---- phase 3: blocked inversion, f32 exact: Ms -> X = inv(I+M) ----
  {
    const int b0 = R0;
    const int j  = lane & 15;
    float x[16];
    #pragma unroll
    for(int i = 0; i < 16; ++i){
      float acc2 = (i == j) ? 1.f : 0.f;
      #pragma unroll
      for(int m = 0; m < 16; ++m){
        if(m < i) acc2 -= Ms[(b0+i)*64 + (b0+m)] * x[m];
      }
      x[i] = acc2;
    }
    if(lane < 16){
      #pragma unroll
      for(int i = 0; i < 16; ++i) Ms[(b0+i)*64 + (b0+j)] = x[i];
    }
  }
  __syncthreads();
  {
    float* Pscr = (float*)(arena + 17408);
    const int i = (tid >> 4) & 15, j = tid & 15;
    float P[2];
    #pragma unroll
    for(int gg = 0; gg < 2; ++gg){
      const int rb = 32*gg + 16, cb = 32*gg;
      float a = 0.f;
      #pragma unroll
      for(int k = 0; k < 16; ++k)
        a += Ms[(rb+i)*64 + cb+k] * Ms[(cb+k)*64 + cb+j];
      Pscr[gg*256 + i*16 + j] = a;
    }
    __syncthreads();
    #pragma unroll
    for(int gg = 0; gg < 2; ++gg){
      const int rb = 32*gg + 16;
      float a = 0.f;
      #pragma unroll
      for(int k = 0; k < 16; ++k)
        a -= Ms[(rb+i)*64 + rb+k] * Pscr[gg*256 + k*16 + j];
      P[gg] = a;
    }
    #pragma unroll
    for(int gg = 0; gg < 2; ++gg){
      const int rb = 32*gg + 16, cb = 32*gg;
      Ms[(rb+i)*64 + cb + j] = P[gg];
    }
  }
  __syncthreads();
  {
    float* Pscr = (float*)(arena + 17408);
    const int i = tid >> 3;
    const int j4 = (tid & 7) * 4;
    float p[4] = {0.f,0.f,0.f,0.f};
    #pragma unroll 8
    for(int k = 0; k < 32; ++k){
      float b = Ms[(32+i)*64 + k];
      #pragma unroll
      for(int c = 0; c < 4; ++c) p[c] += b * Ms[k*64 + j4 + c];
    }
    #pragma unroll
    for(int c = 0; c < 4; ++c) Pscr[i*32 + j4 + c] = p[c];
    __syncthreads();
    float q2[4] = {0.f,0.f,0.f,0.f};
    #pragma unroll 8
    for(int k = 0; k < 32; ++k){
      float xc = Ms[(32+i)*64 + 32+k];
      #pragma unroll
      for(int c = 0; c < 4; ++c) q2[c] -= xc * Pscr[k*32 + j4 + c];
    }
    #pragma unroll
    for(int c = 0; c < 4; ++c) Ms[(32+i)*64 + j4 + c] = q2[c];
  }
  __syncthreads();

  // ---- phase 4: Tb = bf16(T); XT[d][m] = bf16(k[m][d]*wsc[m]) ----
  for(int e = tid; e < 4096; e += 256){
    int i = e >> 6, j = e & 63;
    Tb[i*72 + j] = f2bf(Ms[e]);
  }
  {
    int m = tid & 63, dc = (tid >> 6)*32;
    float sc = wsc[m];
    #pragma unroll
    for(int d8 = 0; d8 < 32; d8 += 8){
      u16x8 kv = *(const u16x8*)&kS[m*136 + dc + d8];
      #pragma unroll
      for(int e = 0; e < 8; ++e)
        XT[(dc + d8 + e)*72 + m] = f2bf(bf2f(kv[e]) * sc);
    }
  }
  __syncthreads();

  // ---- phase 5: w = T @ (k*beta*e^gc) via MFMA; store prefetched v ----
  {
    f32x4 wa[8] = {};
    #pragma unroll
    for(int ks = 0; ks < 2; ++ks){
      bf16x8 at = *(const bf16x8*)((const char*)Tb + (R0 + (lane & 15))*144 + ks*64 + (lane >> 4)*16);
      #pragma unroll
      for(int dt = 0; dt < 8; ++dt){
        bf16x8 bx = *(const bf16x8*)((const char*)XT + (dt*16 + (lane & 15))*144 + ks*64 + (lane >> 4)*16);
        wa[dt] = __builtin_amdgcn_mfma_f32_16x16x32_bf16(at, bx, wa[dt], 0, 0, 0);
      }
    }
    #pragma unroll
    for(int dt = 0; dt < 8; ++dt){
      int d = dt*16 + (lane & 15);
      #pragma unroll
      for(int r = 0; r < 4; ++r){
        int i = R0 + (lane >> 4)*4 + r;
        wb[uwbase + (size_t)i*128 + d] = f2bf(wa[dt][r]);
      }
    }
  }
  #pragma unroll
  for(int e2 = 0; e2 < 4; ++e2){
    int e = tid + e2*256;
    int r = e >> 4, c8 = (e & 15)*8;
    *(u16x8*)&vS[r*136 + c8] = pv[e2];
  }
  __syncthreads();

  // ---- phase 6: VT[c][m] = bf16(v[m][c]*beta[m]) ----
  {
    int m = tid & 63, dc = (tid >> 6)*32;
    float bsc = betas[m];
    #pragma unroll
    for(int d8 = 0; d8 < 32; d8 += 8){
      u16x8 vv = *(const u16x8*)&vS[m*136 + dc + d8];
      #pragma unroll
      for(int e = 0; e < 8; ++e)
        VT[(dc + d8 + e)*72 + m] = f2bf(bf2f(vv[e]) * bsc);
    }
  }
  __syncthreads();

  // ---- phase 7: u = T @ (v*beta) via MFMA ----
  {
    f32x4 ua[8] = {};
    #pragma unroll
    for(int ks = 0; ks < 2; ++ks){
      bf16x8 at = *(const bf16x8*)((const char*)Tb + (R0 + (lane & 15))*144 + ks*64 + (lane >> 4)*16);
      #pragma unroll
      for(int dt = 0; dt < 8; ++dt){
        bf16x8 bx = *(const bf16x8*)((const char*)VT + (dt*16 + (lane & 15))*144 + ks*64 + (lane >> 4)*16);
        ua[dt] = __builtin_amdgcn_mfma_f32_16x16x32_bf16(at, bx, ua[dt], 0, 0, 0);
      }
    }
    #pragma unroll
    for(int dt = 0; dt < 8; ++dt){
      int d = dt*16 + (lane & 15);
      #pragma unroll
      for(int r = 0; r < 4; ++r){
        int i = R0 + (lane >> 4)*4 + r;
        ub[uwbase + (size_t)i*128 + d] = f2bf(ua[dt][r]);
      }
    }
  }
}

// ---------------------------------------------------------------- phase B (per batch): MFMA chunk scan, c-split x8
// T14: all global operands (w,q,attn,kbT) register-prefetched at chunk top.
__global__ __launch_bounds__(256) void phaseB(const u16* __restrict__ qb, const u16* __restrict__ kbT,
      const u16* __restrict__ ub, const u16* __restrict__ wb, const u16* __restrict__ attnb,
      const float* __restrict__ gcb, u16* __restrict__ core){
  __shared__ __align__(16) u16 STbf[16][136];   // S^T: [16 c][128 d] + pad
  __shared__ __align__(16) u16 vnT[16][72];     // vn^T (for attn@vn)
  __shared__ __align__(16) u16 vnT2[16][72];    // (vn*e^{gl-gc})^T (for state update)
  __shared__ __align__(16) u16 uS[64][24];
  __shared__ float gcs[64];
  __shared__ float egm[64];
  const int f = blockIdx.x;              // 0..255
  const int xcd = f & 7, idx = f >> 3;   // idx 0..31
  const int h = xcd*4 + (idx >> 3);      // 0..31 (4 heads per XCD)
  const int split = idx & 7;             // 0..7
  const int cbb = split*16;              // state col base
  const int hk = h >> 1;
  const int tid = threadIdx.x;
  const int lane = tid & 63, wave = tid >> 6;
  const int cL = lane & 15, qq = lane >> 4;
  const int i0w = wave*16, d0w = wave*32;
  const float* gcp = gcb + (size_t)h*SEQ;
  const u16* qbase = qb + (size_t)hk*SEQ*DK;
  const u16* kTb   = kbT + (size_t)hk*DK*SEQ;
  const size_t uwb = (size_t)h*NCH*64*128;
  const size_t atb = (size_t)h*NCH*64*64;
  u16* corep = core + (size_t)h*SEQ*DV;
  f32x4 accS[2] = {};
  for(int n = 0; n < NCH; ++n){
    const int s0 = n * CHUNK;
    // ---- chunk-top: prefetch ALL global operands into registers ----
    const u16* wrow = wb + uwb + (size_t)n*8192;
    const u16* arow = attnb + atb + (size_t)n*4096;
    bf16x8 pw[4], pq[4], pa[2], pk[4];
    #pragma unroll
    for(int ks = 0; ks < 4; ++ks){
      pw[ks] = *(const bf16x8*)&wrow[(size_t)(i0w+cL)*128 + ks*32 + qq*8];
      pq[ks] = *(const bf16x8*)&qbase[(size_t)(s0 + i0w + cL)*128 + ks*32 + qq*8];
    }
    #pragma unroll
    for(int ks = 0; ks < 2; ++ks)
      pa[ks] = *(const bf16x8*)&arow[(size_t)(i0w+cL)*64 + ks*32 + qq*8];
    if(n < NCH-1){
      #pragma unroll
      for(int ks = 0; ks < 2; ++ks)
        #pragma unroll
        for(int dt = 0; dt < 2; ++dt)
          pk[ks*2+dt] = *(const bf16x8*)&kTb[(size_t)(d0w + dt*16 + cL)*SEQ + s0 + ks*32 + qq*8];
    }
    #pragma unroll
    for(int dt = 0; dt < 2; ++dt){
      u16x4 p;
      #pragma unroll
      for(int r = 0; r < 4; ++r) p[r] = f2bf(accS[dt][r]);
      *(u16x4*)&STbf[cL][d0w + dt*16 + qq*4] = p;
    }
    {
      const u16* urow = ub + uwb + (size_t)n*8192;
      int rr = tid >> 2, c4 = (tid & 3)*4;
      *(u16x4*)&uS[rr][c4] = *(const u16x4*)&urow[(size_t)rr*128 + cbb + c4];
    }
    if(wave == 0){
      float g = gcp[s0 + lane];
      gcs[lane] = g;
      float gl = __shfl(g, 63, 64);
      egm[lane] = __expf(gl - g);
    }
    __syncthreads();
    // ---- M1: vn = u - w@S; write vnT and vnT2 ----
    bf16x8 bS[4];
    f32x4 accvn = {};
    #pragma unroll
    for(int ks = 0; ks < 4; ++ks){
      bS[ks] = *(const bf16x8*)&STbf[cL][ks*32 + qq*8];
      accvn = __builtin_amdgcn_mfma_f32_16x16x32_bf16(pw[ks], bS[ks], accvn, 0, 0, 0);
    }
    {
      u16x4 p, p2;
      #pragma unroll
      for(int r = 0; r < 4; ++r){
        int i = i0w + qq*4 + r;
        float vnv = bf2f(uS[i][cL]) - accvn[r];
        p[r]  = f2bf(vnv);
        p2[r] = f2bf(vnv * egm[i]);
      }
      *(u16x4*)&vnT [cL][i0w + qq*4] = p;
      *(u16x4*)&vnT2[cL][i0w + qq*4] = p2;
    }
    __syncthreads();
    // ---- tail: M2 o = q@S * e^gc; M3 o += attn@vn; store core; M4 state update ----
    f32x4 accO = {};
    #pragma unroll
    for(int ks = 0; ks < 4; ++ks)
      accO = __builtin_amdgcn_mfma_f32_16x16x32_bf16(pq[ks], bS[ks], accO, 0, 0, 0);
    #pragma unroll
    for(int r = 0; r < 4; ++r)
      accO[r] *= __expf(gcs[i0w + qq*4 + r]);
    #pragma unroll
    for(int ks = 0; ks < 2; ++ks){
      bf16x8 bV = *(const bf16x8*)&vnT[cL][ks*32 + qq*8];
      accO = __builtin_amdgcn_mfma_f32_16x16x32_bf16(pa[ks], bV, accO, 0, 0, 0);
    }
    #pragma unroll
    for(int r = 0; r < 4; ++r)
      corep[(size_t)(s0 + i0w + qq*4 + r)*DV + cbb + cL] = f2bf(accO[r]);
    if(n < NCH-1){
      float egl = __expf(gcs[63]);
      #pragma unroll
      for(int dt = 0; dt < 2; ++dt)
        accS[dt] *= egl;
      #pragma unroll
      for(int ks = 0; ks < 2; ++ks){
        bf16x8 bV2 = *(const bf16x8*)&vnT2[cL][ks*32 + qq*8];
        #pragma unroll
        for(int dt = 0; dt < 2; ++dt)
          accS[dt] = __builtin_amdgcn_mfma_f32_16x16x32_bf16(pk[ks*2+dt], bV2, accS[dt], 0, 0, 0);
      }
    }
    __syncthreads();
  }
}

// ---------------------------------------------------------------- gated RMSNorm * silu(z) -> bf16 (per batch)
__global__ __launch_bounds__(128) void norm_gate(const u16* __restrict__ core, const u16* __restrict__ z_bf,
      const float* __restrict__ nw, u16* __restrict__ core2){
  const int h = blockIdx.y;
  const int s = blockIdx.x;
  const int t = threadIdx.x;    // 0..127
  __shared__ float red[2];
  float x = bf2f(core[((size_t)h*SEQ + s)*DV + t]);
  float sq = x*x;
  #pragma unroll
  for(int off = 1; off < 64; off <<= 1) sq += __shfl_xor(sq, off, 64);
  if((t & 63) == 0) red[t >> 6] = sq;
  __syncthreads();
  float var = (red[0] + red[1]) * (1.f/128.f);
  float y = x * rsqrtf(var + 1e-6f) * nw[t];
  float zv = bf2f(z_bf[(size_t)s*VAL_DIM + h*DV + t]);
  y *= zv / (1.f + __expf(-zv));
  core2[(size_t)s*VAL_DIM + h*DV + t] = f2bf(y);
}

// ---------------------------------------------------------------- launch
extern "C" void kernel_launch(void* const* d_in, const int* in_sizes, int n_in,
                              void* d_out, int out_size, void* d_ws, size_t ws_size,
                              hipStream_t stream){
  (void)in_sizes; (void)n_in; (void)out_size;
  const float* hs     = (const float*)d_in[0];
  const float* W_qkv  = (const float*)d_in[1];
  const float* conv_w = (const float*)d_in[2];
  const float* W_z    = (const float*)d_in[3];
  const float* W_b    = (const float*)d_in[4];
  const float* W_a    = (const float*)d_in[5];
  const float* dt_b   = (const float*)d_in[6];
  const float* A_log  = (const float*)d_in[7];
  const float* norm_w = (const float*)d_in[8];
  const float* W_out  = (const float*)d_in[9];
  float* out = (float*)d_out;

  const size_t MB = 1024ULL*1024ULL;
  if (ws_size < 160*MB) return;   // diagnostic: clean absmax-fail if ws too small

  char* ws = (char*)d_ws;
  // ws map: [0,64M)=B  [64,96M)=C  [96,128M)=E  [128,160M)=D
  u16*   mixed  = (u16*)ws;                      // B: gemm1 -> conv
  u16*   attnB  = (u16*)ws;                      // B[0,16M): phaseA -> phaseB
  u16*   core_b = (u16*)(ws + 16*MB);            // B[16,48M): phaseB -> norm
  float* betab  = (float*)(ws + 48*MB);          // B[48M..): proj -> phaseA
  float* gbuf   = (float*)(ws + 48*MB + 512*1024);
  float* gcbuf  = (float*)(ws + 49*MB);          // phaseA -> phaseB
  u16*   WoutT  = (u16*)ws;                      // B[0,16M): after norm_b1
  u16*   qb     = (u16*)(ws + 64*MB);            // C[0,16M)
  u16*   kb     = (u16*)(ws + 80*MB);            // C[16,32M)
  u16*   zb     = (u16*)(ws + 64*MB);            // C: gemm2 -> norm (q,k dead after phaseB/transpose_k)
  u16*   core2  = (u16*)(ws + 96*MB);            // E+D: 64M contiguous [8192][4096]
  u16*   vb     = (u16*)(ws + 128*MB);           // D: conv -> phaseA
  u16*   kbT    = (u16*)(ws + 144*MB);           // D[16,32M): transpose_k -> phaseB (v dead)
  u16*   WzT    = (u16*)(ws + 128*MB);           // D[0,16M): after phaseB (v dead)
  // d_out scratch (64M): WqkvT [0,32M) + hs_bf1 [32,48.7M) during gemm1;
  // u [0,32M) + w [32,64M) phaseA->phaseB; hs_bf2 [0,16.7M) for gemm2 (after phaseB).
  u16*   WqkvT  = (u16*)d_out;
  u16*   hs_bf1 = (u16*)((char*)d_out + 32*MB);
  u16*   u_d    = (u16*)d_out;
  u16*   w_d    = (u16*)((char*)d_out + 32*MB);
  u16*   hs_bf2 = (u16*)d_out;

  for(int b = 0; b < BB; ++b){
    const float* hs_b = hs + (size_t)b*SEQ*HID;
    u16* core2_b = core2 + (size_t)b*SEQ*VAL_DIM;
    cast_bf<<<1024, 256, 0, stream>>>(hs_b, hs_bf1, SEQ*HID/8);
    transpose_cast<<<dim3(CONV_DIM/32, HID/32), 256, 0, stream>>>(W_qkv, WqkvT, HID, CONV_DIM);
    gemm256<u16><<<dim3(CONV_DIM/256, SEQ/256), 512, 0, stream>>>(hs_bf1, WqkvT, mixed, SEQ, CONV_DIM, HID);
    conv_qkv<<<dim3(64, SEQ/CTS), 128, 0, stream>>>(mixed, conv_w, qb, kb, vb);
    proj_bg<<<SEQ/4, 256, 0, stream>>>(hs_b, W_b, W_a, dt_b, A_log, betab, gbuf);
    phaseA<<<dim3(NCH, HV), 256, 0, stream>>>(qb, kb, vb, betab, gbuf, gcbuf, u_d, w_d, attnB);
    transpose_k<<<dim3(SEQ/32, DK/32, HK), 256, 0, stream>>>(kb, kbT);   // after phaseA (vb dead)
    phaseB<<<256, 256, 0, stream>>>(qb, kbT, u_d, w_d, attnB, gcbuf, core_b);
    cast_bf<<<1024, 256, 0, stream>>>(hs_b, hs_bf2, SEQ*HID/8);
    transpose_cast<<<dim3(VAL_DIM/32, HID/32), 256, 0, stream>>>(W_z, WzT, HID, VAL_DIM);
    gemm256<u16><<<dim3(VAL_DIM/256, SEQ/256), 512, 0, stream>>>(hs_bf2, WzT, zb, SEQ, VAL_DIM, HID);
    norm_gate<<<dim3(SEQ, HV), 128, 0, stream>>>(core_b, zb, norm_w, core2_b);
  }
  transpose_cast<<<dim3(HID/32, VAL_DIM/32), 256, 0, stream>>>(W_out, WoutT, VAL_DIM, HID);
  gemm256<float><<<dim3(HID/256, BS/256), 512, 0, stream>>>(core2, WoutT, out, BS, HID, VAL_DIM);
}

// Round 15
// 1393.796 us; speedup vs baseline: 1.1212x; 1.1212x over previous
//
#include <hip/hip_runtime.h>
#include <math.h>

#define BB 2
#define SEQ 4096
#define HID 2048
#define HV 32
#define HK 16
#define DK 128
#define DV 128
#define CHUNK 64
#define NCH 64
#define KEY_DIM 2048
#define VAL_DIM 4096
#define CONV_DIM 8192
#define BS 8192   // BB*SEQ
#define CTS 8     // conv s-tile

typedef unsigned short u16;
typedef __attribute__((ext_vector_type(8))) __bf16 bf16x8;
typedef __attribute__((ext_vector_type(4))) float f32x4;
typedef __attribute__((ext_vector_type(4))) unsigned short u16x4;
typedef __attribute__((ext_vector_type(8))) unsigned short u16x8;

__device__ __forceinline__ float bf2f(u16 x){
  return (float)__builtin_bit_cast(__bf16, x);
}
__device__ __forceinline__ u16 f2bf(float f){
  return __builtin_bit_cast(u16, (__bf16)f);
}

// async global->LDS, 16B per lane; LDS dest is wave-uniform base + lane*16
__device__ __forceinline__ void gl_lds16(const u16* g, u16* l){
  __builtin_amdgcn_global_load_lds((const __attribute__((address_space(1))) void*)g,
                                   (__attribute__((address_space(3))) void*)l, 16, 0, 0);
}

// ---------------------------------------------------------------- f32 -> bf16 cast (vectorized, grid-stride)
__global__ __launch_bounds__(256) void cast_bf(const float* __restrict__ in, u16* __restrict__ out, int n8){
  int i = blockIdx.x*256 + threadIdx.x;
  const int stride = gridDim.x*256;
  for(; i < n8; i += stride){
    float4 a = ((const float4*)in)[(size_t)i*2];
    float4 b = ((const float4*)in)[(size_t)i*2+1];
    u16x8 t;
    t[0]=f2bf(a.x); t[1]=f2bf(a.y); t[2]=f2bf(a.z); t[3]=f2bf(a.w);
    t[4]=f2bf(b.x); t[5]=f2bf(b.y); t[6]=f2bf(b.z); t[7]=f2bf(b.w);
    ((u16x8*)out)[i] = t;
  }
}

// ---------------------------------------------------------------- weight transpose: src [R,C] f32 -> dst [C,R] bf16
__global__ __launch_bounds__(256) void transpose_cast(const float* __restrict__ src, u16* __restrict__ dst, int R, int C){
  __shared__ float tile[32][33];
  int c0 = blockIdx.x*32, r0 = blockIdx.y*32;
  int tx = threadIdx.x & 31, ty = threadIdx.x >> 5;   // ty 0..7
  for(int i = ty; i < 32; i += 8) tile[i][tx] = src[(size_t)(r0+i)*C + c0 + tx];
  __syncthreads();
  for(int i = ty; i < 32; i += 8) dst[(size_t)(c0+i)*R + r0 + tx] = f2bf(tile[tx][i]);
}

// ---------------------------------------------------------------- k transpose (per batch): kb [HK][SEQ][DK] -> kbT [HK][DK][SEQ]
__global__ __launch_bounds__(256) void transpose_k(const u16* __restrict__ kb, u16* __restrict__ kbT){
  __shared__ u16 tile[32][33];
  const int h = blockIdx.z, d0 = blockIdx.y*32, s0 = blockIdx.x*32;
  const int tx = threadIdx.x & 31, ty = threadIdx.x >> 5;
  const u16* src = kb + (size_t)h*SEQ*DK;
  for(int i = ty; i < 32; i += 8) tile[i][tx] = src[(size_t)(s0+i)*DK + d0 + tx];
  __syncthreads();
  u16* dst = kbT + (size_t)h*DK*SEQ;
  for(int i = ty; i < 32; i += 8) dst[(size_t)(d0+i)*SEQ + s0 + tx] = tile[tx][i];
}

// ---------------------------------------------------------------- GEMM bf16, 256x256 tile, BK=64, 8 waves, dbuf gl_lds (r13 proven)
__device__ __forceinline__ void store_c(float* C, size_t idx, float v){ C[idx] = v; }
__device__ __forceinline__ void store_c(u16*   C, size_t idx, float v){ C[idx] = f2bf(v); }

__device__ __forceinline__ void stage256(const u16* __restrict__ A, const u16* __restrict__ Bt,
                                         size_t bm, size_t bn, int K, int k0,
                                         u16* Ab, u16* Bb, int wave, int lrow, int lg){
  const int g = lg ^ lrow;          // row&7 == lrow for all staged rows
  #pragma unroll
  for(int r = 0; r < 4; ++r){
    const int grow = r*64 + wave*8 + lrow;
    const int dst = (r>>1)*8192 + ((r&1)*64 + wave*8)*64;
    gl_lds16(&A [(bm + grow)*K + k0 + g*8], &Ab[dst]);
    gl_lds16(&Bt[(bn + grow)*K + k0 + g*8], &Bb[dst]);
  }
}

template<typename CT>
__global__ __launch_bounds__(512) void gemm256(const u16* __restrict__ A, const u16* __restrict__ Bt,
                                               CT* __restrict__ C, int M, int N, int K){
  (void)M;
  __shared__ u16 As[2][2][8192];   // [buf][half][128x64], 64KB
  __shared__ u16 Bs[2][2][8192];   // 64KB
  const int tid  = threadIdx.x;
  const int lane = tid & 63;
  const int wave = tid >> 6;       // 0..7
  const int lrow = lane >> 3, lg = lane & 7;
  // bijective XCD-chunked swizzle (all grids have nwg % 8 == 0)
  const int nwg = gridDim.x * gridDim.y;
  const int old = blockIdx.y * gridDim.x + blockIdx.x;
  const int nid = (old & 7) * (nwg >> 3) + (old >> 3);
  const int bx = nid % gridDim.x, by = nid / gridDim.x;
  const size_t bm = (size_t)by * 256;
  const size_t bn = (size_t)bx * 256;
  const int wm = (wave >> 2) * 128;     // 0 / 128
  const int wn = (wave & 3) * 64;       // 0 / 64 / 128 / 192
  const int ah = wave >> 2;             // this wave's A half
  const int bh = (wave & 3) >> 1;       // this wave's B half
  const int lwn = wn & 64;              // B row base within half
  const int cL15 = lane & 15, qq = lane >> 4;
  f32x4 acc[8][4] = {};
  const int nk = K >> 6;
  stage256(A, Bt, bm, bn, K, 0, &As[0][0][0], &Bs[0][0][0], wave, lrow, lg);
  __syncthreads();
  int cur = 0;
  for(int kt = 0; kt < nk; ++kt){
    if(kt+1 < nk)
      stage256(A, Bt, bm, bn, K, (kt+1) << 6, &As[cur^1][0][0], &Bs[cur^1][0][0], wave, lrow, lg);
    const u16* Ah = As[cur][ah];
    const u16* Bh = Bs[cur][bh];
    __builtin_amdgcn_s_setprio(1);
    #pragma unroll
    for(int kk = 0; kk < 2; ++kk){
      bf16x8 af[8], bfr[4];
      #pragma unroll
      for(int mi = 0; mi < 8; ++mi){
        int lr = mi*16 + cL15;
        int cb = (kk*64 + qq*16) ^ ((lr & 7) << 4);
        af[mi] = *(const bf16x8*)((const char*)Ah + lr*128 + cb);
      }
      #pragma unroll
      for(int ni = 0; ni < 4; ++ni){
        int lr = lwn + ni*16 + cL15;
        int cb = (kk*64 + qq*16) ^ ((lr & 7) << 4);
        bfr[ni] = *(const bf16x8*)((const char*)Bh + lr*128 + cb);
      }
      #pragma unroll
      for(int mi = 0; mi < 8; ++mi)
        #pragma unroll
        for(int ni = 0; ni < 4; ++ni)
          acc[mi][ni] = __builtin_amdgcn_mfma_f32_16x16x32_bf16(af[mi], bfr[ni], acc[mi][ni], 0, 0, 0);
    }
    __builtin_amdgcn_s_setprio(0);
    __syncthreads();   // drains gl_lds (vmcnt0) + all waves done with buf cur
    cur ^= 1;
  }
  const int c0 = (int)bn + wn + cL15;
  const int r0 = (int)bm + wm + qq*4;
  #pragma unroll
  for(int mi = 0; mi < 8; ++mi)
    #pragma unroll
    for(int ni = 0; ni < 4; ++ni)
      #pragma unroll
      for(int rr = 0; rr < 4; ++rr)
        store_c(C, (size_t)(r0 + mi*16 + rr)*N + (c0 + ni*16), acc[mi][ni][rr]);
}

// ---------------------------------------------------------------- beta/g projections (per batch), fp32 exact
__global__ __launch_bounds__(256) void proj_bg(const float* __restrict__ hs, const float* __restrict__ Wb,
      const float* __restrict__ Wa, const float* __restrict__ dtb, const float* __restrict__ A_log,
      float* __restrict__ betab, float* __restrict__ gbuf){
  __shared__ float h4[4][HID];          // 32KB: 4 rows of hs
  __shared__ float part[4][64][4];
  const int r0 = blockIdx.x * 4;
  const int tid = threadIdx.x;
  for(int i = tid; i < 4*HID/4; i += 256)
    ((float4*)&h4[0][0])[i] = ((const float4*)&hs[(size_t)r0*HID])[i];
  __syncthreads();
  const int o = tid & 63, pp = tid >> 6;
  const float* W = (o < 32) ? (Wb + o) : (Wa + (o - 32));
  float a0=0.f,a1=0.f,a2=0.f,a3=0.f;
  const int kbeg = pp*512;
  for(int kk = kbeg; kk < kbeg+512; ++kk){
    float wv = W[(size_t)kk*32];
    a0 += wv*h4[0][kk]; a1 += wv*h4[1][kk]; a2 += wv*h4[2][kk]; a3 += wv*h4[3][kk];
  }
  part[0][o][pp]=a0; part[1][o][pp]=a1; part[2][o][pp]=a2; part[3][o][pp]=a3;
  __syncthreads();
  {
    const int row = tid >> 6, oo = tid & 63;
    float sdot = part[row][oo][0]+part[row][oo][1]+part[row][oo][2]+part[row][oo][3];
    const int s = r0 + row;
    if(oo < 32){
      betab[(size_t)oo*SEQ + s] = 1.f/(1.f + __expf(-sdot));
    } else {
      const int hh = oo - 32;
      float x = sdot + dtb[hh];
      float sp = (x > 20.f) ? x : log1pf(__expf(x));
      gbuf[(size_t)hh*SEQ + s] = -__expf(A_log[hh]) * sp;
    }
  }
}

// ---------------------------------------------------------------- conv(4) + SiLU + split + l2norm -> bf16 (per batch)
__global__ __launch_bounds__(128) void conv_qkv(const u16* __restrict__ mixed, const float* __restrict__ conv_w,
      u16* __restrict__ qb, u16* __restrict__ kb, u16* __restrict__ vb){
  const int slot = blockIdx.x;          // 0..63  (16 q heads, 16 k heads, 32 v heads)
  const int s0 = blockIdx.y * CTS;      // 0..4095 step CTS
  const int t = threadIdx.x;            // 0..127
  const int c = slot*128 + t;
  __shared__ float red[CTS][2];
  float m[CTS+3];
  #pragma unroll
  for(int j = 0; j < CTS+3; ++j){
    int ss = s0 - 3 + j;
    m[j] = (ss >= 0) ? bf2f(mixed[(size_t)ss*CONV_DIM + c]) : 0.f;
  }
  const float w0 = conv_w[c*4+0], w1 = conv_w[c*4+1], w2 = conv_w[c*4+2], w3 = conv_w[c*4+3];
  float acc[CTS];
  #pragma unroll
  for(int i = 0; i < CTS; ++i){
    float a = 0.f;
    a += w0*m[i]; a += w1*m[i+1]; a += w2*m[i+2]; a += w3*m[i+3];
    acc[i] = a / (1.f + __expf(-a));    // SiLU
  }
  if(slot < 32){
    #pragma unroll
    for(int i = 0; i < CTS; ++i){
      float sq = acc[i]*acc[i];
      #pragma unroll
      for(int off = 1; off < 64; off <<= 1) sq += __shfl_xor(sq, off, 64);
      if((t & 63) == 0) red[i][t >> 6] = sq;
    }
    __syncthreads();
    #pragma unroll
    for(int i = 0; i < CTS; ++i){
      const int s = s0 + i;
      float rn = rsqrtf(red[i][0] + red[i][1] + 1e-6f);
      if(slot < 16)
        qb[((size_t)slot*SEQ + s)*DK + t] = f2bf(acc[i] * rn * 0.08838834764831845f); // * DK^-0.5
      else
        kb[((size_t)(slot-16)*SEQ + s)*DK + t] = f2bf(acc[i] * rn);
    }
  } else {
    #pragma unroll
    for(int i = 0; i < CTS; ++i)
      vb[((size_t)(slot-32)*SEQ + s0+i)*DV + t] = f2bf(acc[i]);
  }
}

// ---------------------------------------------------------------- phase A (per batch), MFMA version
__global__ __launch_bounds__(256) void phaseA(const u16* __restrict__ qb, const u16* __restrict__ kb,
      const u16* __restrict__ vb, const float* __restrict__ betab, const float* __restrict__ gb,
      float* __restrict__ gcb, u16* __restrict__ ub, u16* __restrict__ wb, u16* __restrict__ attnb){
  __shared__ __align__(16) char arena[63232];
  u16*   kS  = (u16*)(arena);
  u16*   qS  = (u16*)(arena + 17408);
  u16*   XT  = (u16*)(arena + 17408);
  u16*   VT  = (u16*)(arena + 17408);
  float* Ms  = (float*)(arena + 35840);
  u16*   vS  = (u16*)(arena + 35840);
  u16*   Tb  = (u16*)(arena + 53248);
  float* gcs   = (float*)(arena + 62464);
  float* betas = gcs + 64;
  float* wsc   = gcs + 128;

  const int n = blockIdx.x, h = blockIdx.y;
  const int hk = h >> 1;
  const int s0 = n * CHUNK;
  const int tid = threadIdx.x;
  const int lane = tid & 63;
  const int wave = tid >> 6;
  const int R0 = wave * 16;
  const size_t hS = (size_t)h*SEQ;
  const u16* kbase = kb + ((size_t)hk*SEQ + s0)*DK;
  const u16* qbase = qb + ((size_t)hk*SEQ + s0)*DK;
  const u16* vbase = vb + ((size_t)h*SEQ + s0)*DV;
  const size_t atbase = ((size_t)h*NCH + n)*64*64;
  const size_t uwbase = ((size_t)h*NCH + n)*64*128;

  // ---- phase 1: stage k,q; prefetch v into regs (used phase 5); gc scan ----
  u16x8 pv[4];
  #pragma unroll
  for(int e2 = 0; e2 < 4; ++e2){
    int e = tid + e2*256;
    int r = e >> 4, c8 = (e & 15)*8;
    pv[e2] = *(const u16x8*)&vbase[(size_t)r*128 + c8];
  }
  for(int e = tid; e < 1024; e += 256){
    int r = e >> 4, c8 = (e & 15)*8;
    *(u16x8*)&kS[r*136 + c8] = *(const u16x8*)&kbase[(size_t)r*128 + c8];
    *(u16x8*)&qS[r*136 + c8] = *(const u16x8*)&qbase[(size_t)r*128 + c8];
  }
  if(wave == 0){
    float v = gb[hS + s0 + lane];
    #pragma unroll
    for(int off = 1; off < 64; off <<= 1){
      float t = __shfl(v, (lane >= off) ? (lane - off) : lane, 64);
      if(lane >= off) v += t;
    }
    gcs[lane] = v;
    gcb[hS + s0 + lane] = v;
    float b = betab[hS + s0 + lane];
    betas[lane] = b;
    wsc[lane] = b * __expf(v);
  }
  __syncthreads();

  // ---- phase 2: S1 = k.k^T, S2 = q.k^T via MFMA; write Ms (f32) + attn (bf16) ----
  {
    f32x4 a1[4] = {}, a2[4] = {};
    #pragma unroll
    for(int ks = 0; ks < 4; ++ks){
      const int ab = (R0 + (lane & 15))*272 + ks*64 + (lane >> 4)*16;
      bf16x8 afk = *(const bf16x8*)((const char*)kS + ab);
      bf16x8 afq = *(const bf16x8*)((const char*)qS + ab);
      #pragma unroll
      for(int jt = 0; jt < 4; ++jt){
        const int bb = (jt*16 + (lane & 15))*272 + ks*64 + (lane >> 4)*16;
        bf16x8 bf = *(const bf16x8*)((const char*)kS + bb);
        a1[jt] = __builtin_amdgcn_mfma_f32_16x16x32_bf16(afk, bf, a1[jt], 0, 0, 0);
        a2[jt] = __builtin_amdgcn_mfma_f32_16x16x32_bf16(afq, bf, a2[jt], 0, 0, 0);
      }
    }
    #pragma unroll
    for(int jt = 0; jt < 4; ++jt){
      int j = jt*16 + (lane & 15);
      float gj = gcs[j];
      #pragma unroll
      for(int r = 0; r < 4; ++r){
        int i = R0 + (lane >> 4)*4 + r;
        float gi = gcs[i];
        float dec = (j <= i) ? __expf(gi - gj) : 0.f;
        Ms[i*64 + j] = (j < i) ? betas[i]*a1[jt][r]*dec : 0.f;
        attnb[atbase + (size_t)i*64 + j] = f2bf(a2[jt][r]*dec);
      }
    }
  }
  __syncthreads();

  // ---- phase 3: blocked inversion, f32 exact: Ms -> X = inv(I+M) ----
  {
    const int b0 = R0;
    const int j  = lane & 15;
    float x[16];
    #pragma unroll
    for(int i = 0; i < 16; ++i){
      float acc2 = (i == j) ? 1.f : 0.f;
      #pragma unroll
      for(int m = 0; m < 16; ++m){
        if(m < i) acc2 -= Ms[(b0+i)*64 + (b0+m)] * x[m];
      }
      x[i] = acc2;
    }
    if(lane < 16){
      #pragma unroll
      for(int i = 0; i < 16; ++i) Ms[(b0+i)*64 + (b0+j)] = x[i];
    }
  }
  __syncthreads();
  {
    float* Pscr = (float*)(arena + 17408);
    const int i = (tid >> 4) & 15, j = tid & 15;
    float P[2];
    #pragma unroll
    for(int gg = 0; gg < 2; ++gg){
      const int rb = 32*gg + 16, cb = 32*gg;
      float a = 0.f;
      #pragma unroll
      for(int k = 0; k < 16; ++k)
        a += Ms[(rb+i)*64 + cb+k] * Ms[(cb+k)*64 + cb+j];
      Pscr[gg*256 + i*16 + j] = a;
    }
    __syncthreads();
    #pragma unroll
    for(int gg = 0; gg < 2; ++gg){
      const int rb = 32*gg + 16;
      float a = 0.f;
      #pragma unroll
      for(int k = 0; k < 16; ++k)
        a -= Ms[(rb+i)*64 + rb+k] * Pscr[gg*256 + k*16 + j];
      P[gg] = a;
    }
    #pragma unroll
    for(int gg = 0; gg < 2; ++gg){
      const int rb = 32*gg + 16, cb = 32*gg;
      Ms[(rb+i)*64 + cb + j] = P[gg];
    }
  }
  __syncthreads();
  {
    float* Pscr = (float*)(arena + 17408);
    const int i = tid >> 3;
    const int j4 = (tid & 7) * 4;
    float p[4] = {0.f,0.f,0.f,0.f};
    #pragma unroll 8
    for(int k = 0; k < 32; ++k){
      float b = Ms[(32+i)*64 + k];
      #pragma unroll
      for(int c = 0; c < 4; ++c) p[c] += b * Ms[k*64 + j4 + c];
    }
    #pragma unroll
    for(int c = 0; c < 4; ++c) Pscr[i*32 + j4 + c] = p[c];
    __syncthreads();
    float q2[4] = {0.f,0.f,0.f,0.f};
    #pragma unroll 8
    for(int k = 0; k < 32; ++k){
      float xc = Ms[(32+i)*64 + 32+k];
      #pragma unroll
      for(int c = 0; c < 4; ++c) q2[c] -= xc * Pscr[k*32 + j4 + c];
    }
    #pragma unroll
    for(int c = 0; c < 4; ++c) Ms[(32+i)*64 + j4 + c] = q2[c];
  }
  __syncthreads();

  // ---- phase 4: Tb = bf16(T); XT[d][m] = bf16(k[m][d]*wsc[m]) ----
  for(int e = tid; e < 4096; e += 256){
    int i = e >> 6, j = e & 63;
    Tb[i*72 + j] = f2bf(Ms[e]);
  }
  {
    int m = tid & 63, dc = (tid >> 6)*32;
    float sc = wsc[m];
    #pragma unroll
    for(int d8 = 0; d8 < 32; d8 += 8){
      u16x8 kv = *(const u16x8*)&kS[m*136 + dc + d8];
      #pragma unroll
      for(int e = 0; e < 8; ++e)
        XT[(dc + d8 + e)*72 + m] = f2bf(bf2f(kv[e]) * sc);
    }
  }
  __syncthreads();

  // ---- phase 5: w = T @ (k*beta*e^gc) via MFMA; store prefetched v ----
  {
    f32x4 wa[8] = {};
    #pragma unroll
    for(int ks = 0; ks < 2; ++ks){
      bf16x8 at = *(const bf16x8*)((const char*)Tb + (R0 + (lane & 15))*144 + ks*64 + (lane >> 4)*16);
      #pragma unroll
      for(int dt = 0; dt < 8; ++dt){
        bf16x8 bx = *(const bf16x8*)((const char*)XT + (dt*16 + (lane & 15))*144 + ks*64 + (lane >> 4)*16);
        wa[dt] = __builtin_amdgcn_mfma_f32_16x16x32_bf16(at, bx, wa[dt], 0, 0, 0);
      }
    }
    #pragma unroll
    for(int dt = 0; dt < 8; ++dt){
      int d = dt*16 + (lane & 15);
      #pragma unroll
      for(int r = 0; r < 4; ++r){
        int i = R0 + (lane >> 4)*4 + r;
        wb[uwbase + (size_t)i*128 + d] = f2bf(wa[dt][r]);
      }
    }
  }
  #pragma unroll
  for(int e2 = 0; e2 < 4; ++e2){
    int e = tid + e2*256;
    int r = e >> 4, c8 = (e & 15)*8;
    *(u16x8*)&vS[r*136 + c8] = pv[e2];
  }
  __syncthreads();

  // ---- phase 6: VT[c][m] = bf16(v[m][c]*beta[m]) ----
  {
    int m = tid & 63, dc = (tid >> 6)*32;
    float bsc = betas[m];
    #pragma unroll
    for(int d8 = 0; d8 < 32; d8 += 8){
      u16x8 vv = *(const u16x8*)&vS[m*136 + dc + d8];
      #pragma unroll
      for(int e = 0; e < 8; ++e)
        VT[(dc + d8 + e)*72 + m] = f2bf(bf2f(vv[e]) * bsc);
    }
  }
  __syncthreads();

  // ---- phase 7: u = T @ (v*beta) via MFMA ----
  {
    f32x4 ua[8] = {};
    #pragma unroll
    for(int ks = 0; ks < 2; ++ks){
      bf16x8 at = *(const bf16x8*)((const char*)Tb + (R0 + (lane & 15))*144 + ks*64 + (lane >> 4)*16);
      #pragma unroll
      for(int dt = 0; dt < 8; ++dt){
        bf16x8 bx = *(const bf16x8*)((const char*)VT + (dt*16 + (lane & 15))*144 + ks*64 + (lane >> 4)*16);
        ua[dt] = __builtin_amdgcn_mfma_f32_16x16x32_bf16(at, bx, ua[dt], 0, 0, 0);
      }
    }
    #pragma unroll
    for(int dt = 0; dt < 8; ++dt){
      int d = dt*16 + (lane & 15);
      #pragma unroll
      for(int r = 0; r < 4; ++r){
        int i = R0 + (lane >> 4)*4 + r;
        ub[uwbase + (size_t)i*128 + d] = f2bf(ua[dt][r]);
      }
    }
  }
}

// ---------------------------------------------------------------- phase B (per batch): MFMA chunk scan, c-split x8
// T14: all global operands (w,q,attn,kbT) register-prefetched at chunk top.
__global__ __launch_bounds__(256) void phaseB(const u16* __restrict__ qb, const u16* __restrict__ kbT,
      const u16* __restrict__ ub, const u16* __restrict__ wb, const u16* __restrict__ attnb,
      const float* __restrict__ gcb, u16* __restrict__ core){
  __shared__ __align__(16) u16 STbf[16][136];   // S^T: [16 c][128 d] + pad
  __shared__ __align__(16) u16 vnT[16][72];     // vn^T (for attn@vn)
  __shared__ __align__(16) u16 vnT2[16][72];    // (vn*e^{gl-gc})^T (for state update)
  __shared__ __align__(16) u16 uS[64][24];
  __shared__ float gcs[64];
  __shared__ float egm[64];
  const int f = blockIdx.x;              // 0..255
  const int xcd = f & 7, idx = f >> 3;   // idx 0..31
  const int h = xcd*4 + (idx >> 3);      // 0..31 (4 heads per XCD)
  const int split = idx & 7;             // 0..7
  const int cbb = split*16;              // state col base
  const int hk = h >> 1;
  const int tid = threadIdx.x;
  const int lane = tid & 63, wave = tid >> 6;
  const int cL = lane & 15, qq = lane >> 4;
  const int i0w = wave*16, d0w = wave*32;
  const float* gcp = gcb + (size_t)h*SEQ;
  const u16* qbase = qb + (size_t)hk*SEQ*DK;
  const u16* kTb   = kbT + (size_t)hk*DK*SEQ;
  const size_t uwb = (size_t)h*NCH*64*128;
  const size_t atb = (size_t)h*NCH*64*64;
  u16* corep = core + (size_t)h*SEQ*DV;
  f32x4 accS[2] = {};
  for(int n = 0; n < NCH; ++n){
    const int s0 = n * CHUNK;
    // ---- chunk-top: prefetch ALL global operands into registers ----
    const u16* wrow = wb + uwb + (size_t)n*8192;
    const u16* arow = attnb + atb + (size_t)n*4096;
    bf16x8 pw[4], pq[4], pa[2], pk[4];
    #pragma unroll
    for(int ks = 0; ks < 4; ++ks){
      pw[ks] = *(const bf16x8*)&wrow[(size_t)(i0w+cL)*128 + ks*32 + qq*8];
      pq[ks] = *(const bf16x8*)&qbase[(size_t)(s0 + i0w + cL)*128 + ks*32 + qq*8];
    }
    #pragma unroll
    for(int ks = 0; ks < 2; ++ks)
      pa[ks] = *(const bf16x8*)&arow[(size_t)(i0w+cL)*64 + ks*32 + qq*8];
    if(n < NCH-1){
      #pragma unroll
      for(int ks = 0; ks < 2; ++ks)
        #pragma unroll
        for(int dt = 0; dt < 2; ++dt)
          pk[ks*2+dt] = *(const bf16x8*)&kTb[(size_t)(d0w + dt*16 + cL)*SEQ + s0 + ks*32 + qq*8];
    }
    #pragma unroll
    for(int dt = 0; dt < 2; ++dt){
      u16x4 p;
      #pragma unroll
      for(int r = 0; r < 4; ++r) p[r] = f2bf(accS[dt][r]);
      *(u16x4*)&STbf[cL][d0w + dt*16 + qq*4] = p;
    }
    {
      const u16* urow = ub + uwb + (size_t)n*8192;
      int rr = tid >> 2, c4 = (tid & 3)*4;
      *(u16x4*)&uS[rr][c4] = *(const u16x4*)&urow[(size_t)rr*128 + cbb + c4];
    }
    if(wave == 0){
      float g = gcp[s0 + lane];
      gcs[lane] = g;
      float gl = __shfl(g, 63, 64);
      egm[lane] = __expf(gl - g);
    }
    __syncthreads();
    // ---- M1: vn = u - w@S; write vnT and vnT2 ----
    bf16x8 bS[4];
    f32x4 accvn = {};
    #pragma unroll
    for(int ks = 0; ks < 4; ++ks){
      bS[ks] = *(const bf16x8*)&STbf[cL][ks*32 + qq*8];
      accvn = __builtin_amdgcn_mfma_f32_16x16x32_bf16(pw[ks], bS[ks], accvn, 0, 0, 0);
    }
    {
      u16x4 p, p2;
      #pragma unroll
      for(int r = 0; r < 4; ++r){
        int i = i0w + qq*4 + r;
        float vnv = bf2f(uS[i][cL]) - accvn[r];
        p[r]  = f2bf(vnv);
        p2[r] = f2bf(vnv * egm[i]);
      }
      *(u16x4*)&vnT [cL][i0w + qq*4] = p;
      *(u16x4*)&vnT2[cL][i0w + qq*4] = p2;
    }
    __syncthreads();
    // ---- tail: M2 o = q@S * e^gc; M3 o += attn@vn; store core; M4 state update ----
    f32x4 accO = {};
    #pragma unroll
    for(int ks = 0; ks < 4; ++ks)
      accO = __builtin_amdgcn_mfma_f32_16x16x32_bf16(pq[ks], bS[ks], accO, 0, 0, 0);
    #pragma unroll
    for(int r = 0; r < 4; ++r)
      accO[r] *= __expf(gcs[i0w + qq*4 + r]);
    #pragma unroll
    for(int ks = 0; ks < 2; ++ks){
      bf16x8 bV = *(const bf16x8*)&vnT[cL][ks*32 + qq*8];
      accO = __builtin_amdgcn_mfma_f32_16x16x32_bf16(pa[ks], bV, accO, 0, 0, 0);
    }
    #pragma unroll
    for(int r = 0; r < 4; ++r)
      corep[(size_t)(s0 + i0w + qq*4 + r)*DV + cbb + cL] = f2bf(accO[r]);
    if(n < NCH-1){
      float egl = __expf(gcs[63]);
      #pragma unroll
      for(int dt = 0; dt < 2; ++dt)
        accS[dt] *= egl;
      #pragma unroll
      for(int ks = 0; ks < 2; ++ks){
        bf16x8 bV2 = *(const bf16x8*)&vnT2[cL][ks*32 + qq*8];
        #pragma unroll
        for(int dt = 0; dt < 2; ++dt)
          accS[dt] = __builtin_amdgcn_mfma_f32_16x16x32_bf16(pk[ks*2+dt], bV2, accS[dt], 0, 0, 0);
      }
    }
    __syncthreads();
  }
}

// ---------------------------------------------------------------- gated RMSNorm * silu(z) -> bf16 (per batch)
// 8 rows per 256-thread block (2 rows concurrently x 4 iters): 8x fewer blocks.
__global__ __launch_bounds__(256) void norm_gate(const u16* __restrict__ core, const u16* __restrict__ z_bf,
      const float* __restrict__ nw, u16* __restrict__ core2){
  const int h = blockIdx.y;
  const int s0 = blockIdx.x * 8;
  const int t = threadIdx.x & 127;      // elem within row
  const int rh = threadIdx.x >> 7;      // row pair half: 0/1
  __shared__ float red[8][2];
  const float nwv = nw[t];
  #pragma unroll
  for(int i = 0; i < 8; i += 2){
    const int s = s0 + i + rh;
    float x = bf2f(core[((size_t)h*SEQ + s)*DV + t]);
    float sq = x*x;
    #pragma unroll
    for(int off = 1; off < 64; off <<= 1) sq += __shfl_xor(sq, off, 64);
    if((t & 63) == 0) red[i+rh][t >> 6] = sq;
    __syncthreads();
    float var = (red[i+rh][0] + red[i+rh][1]) * (1.f/128.f);
    float y = x * rsqrtf(var + 1e-6f) * nwv;
    float zv = bf2f(z_bf[(size_t)s*VAL_DIM + h*DV + t]);
    y *= zv / (1.f + __expf(-zv));
    core2[(size_t)s*VAL_DIM + h*DV + t] = f2bf(y);
  }
}

// ---------------------------------------------------------------- launch
extern "C" void kernel_launch(void* const* d_in, const int* in_sizes, int n_in,
                              void* d_out, int out_size, void* d_ws, size_t ws_size,
                              hipStream_t stream){
  (void)in_sizes; (void)n_in; (void)out_size;
  const float* hs     = (const float*)d_in[0];
  const float* W_qkv  = (const float*)d_in[1];
  const float* conv_w = (const float*)d_in[2];
  const float* W_z    = (const float*)d_in[3];
  const float* W_b    = (const float*)d_in[4];
  const float* W_a    = (const float*)d_in[5];
  const float* dt_b   = (const float*)d_in[6];
  const float* A_log  = (const float*)d_in[7];
  const float* norm_w = (const float*)d_in[8];
  const float* W_out  = (const float*)d_in[9];
  float* out = (float*)d_out;

  const size_t MB = 1024ULL*1024ULL;
  if (ws_size < 160*MB) return;   // diagnostic: clean absmax-fail if ws too small

  char* ws = (char*)d_ws;
  // ws map: [0,64M)=B  [64,96M)=C  [96,128M)=E  [128,160M)=D
  u16*   mixed  = (u16*)ws;                      // B: gemm1 -> conv
  u16*   attnB  = (u16*)ws;                      // B[0,16M): phaseA -> phaseB
  u16*   core_b = (u16*)(ws + 16*MB);            // B[16,48M): phaseB -> norm
  float* betab  = (float*)(ws + 48*MB);          // B[48M..): proj -> phaseA
  float* gbuf   = (float*)(ws + 48*MB + 512*1024);
  float* gcbuf  = (float*)(ws + 49*MB);          // phaseA -> phaseB
  u16*   WoutT  = (u16*)ws;                      // B[0,16M): after norm_b1
  u16*   qb     = (u16*)(ws + 64*MB);            // C[0,16M)
  u16*   kb     = (u16*)(ws + 80*MB);            // C[16,32M)
  u16*   zb     = (u16*)(ws + 64*MB);            // C: gemm2 -> norm (q,k dead after phaseB/transpose_k)
  u16*   core2  = (u16*)(ws + 96*MB);            // E+D: 64M contiguous [8192][4096]
  u16*   vb     = (u16*)(ws + 128*MB);           // D: conv -> phaseA
  u16*   kbT    = (u16*)(ws + 144*MB);           // D[16,32M): transpose_k -> phaseB (v dead)
  u16*   WzT    = (u16*)(ws + 128*MB);           // D[0,16M): after phaseB (v dead)
  // d_out scratch (64M): WqkvT [0,32M) + hs_bf1 [32,48.7M) during gemm1;
  // u [0,32M) + w [32,64M) phaseA->phaseB; hs_bf2 [0,16.7M) for gemm2 (after phaseB).
  u16*   WqkvT  = (u16*)d_out;
  u16*   hs_bf1 = (u16*)((char*)d_out + 32*MB);
  u16*   u_d    = (u16*)d_out;
  u16*   w_d    = (u16*)((char*)d_out + 32*MB);
  u16*   hs_bf2 = (u16*)d_out;

  for(int b = 0; b < BB; ++b){
    const float* hs_b = hs + (size_t)b*SEQ*HID;
    u16* core2_b = core2 + (size_t)b*SEQ*VAL_DIM;
    cast_bf<<<1024, 256, 0, stream>>>(hs_b, hs_bf1, SEQ*HID/8);
    transpose_cast<<<dim3(CONV_DIM/32, HID/32), 256, 0, stream>>>(W_qkv, WqkvT, HID, CONV_DIM);
    gemm256<u16><<<dim3(CONV_DIM/256, SEQ/256), 512, 0, stream>>>(hs_bf1, WqkvT, mixed, SEQ, CONV_DIM, HID);
    conv_qkv<<<dim3(64, SEQ/CTS), 128, 0, stream>>>(mixed, conv_w, qb, kb, vb);
    proj_bg<<<SEQ/4, 256, 0, stream>>>(hs_b, W_b, W_a, dt_b, A_log, betab, gbuf);
    phaseA<<<dim3(NCH, HV), 256, 0, stream>>>(qb, kb, vb, betab, gbuf, gcbuf, u_d, w_d, attnB);
    transpose_k<<<dim3(SEQ/32, DK/32, HK), 256, 0, stream>>>(kb, kbT);   // after phaseA (vb dead)
    phaseB<<<256, 256, 0, stream>>>(qb, kbT, u_d, w_d, attnB, gcbuf, core_b);
    cast_bf<<<1024, 256, 0, stream>>>(hs_b, hs_bf2, SEQ*HID/8);
    transpose_cast<<<dim3(VAL_DIM/32, HID/32), 256, 0, stream>>>(W_z, WzT, HID, VAL_DIM);
    gemm256<u16><<<dim3(VAL_DIM/256, SEQ/256), 512, 0, stream>>>(hs_bf2, WzT, zb, SEQ, VAL_DIM, HID);
    norm_gate<<<dim3(SEQ/8, HV), 256, 0, stream>>>(core_b, zb, norm_w, core2_b);
  }
  transpose_cast<<<dim3(HID/32, VAL_DIM/32), 256, 0, stream>>>(W_out, WoutT, VAL_DIM, HID);
  gemm256<float><<<dim3(HID/256, BS/256), 512, 0, stream>>>(core2, WoutT, out, BS, HID, VAL_DIM);
}

// Round 17
// 1380.476 us; speedup vs baseline: 1.1320x; 1.0096x over previous
//
#include <hip/hip_runtime.h>
#include <math.h>

#define BB 2
#define SEQ 4096
#define HID 2048
#define HV 32
#define HK 16
#define DK 128
#define DV 128
#define CHUNK 64
#define NCH 64
#define KEY_DIM 2048
#define VAL_DIM 4096
#define CONV_DIM 8192
#define BS 8192   // BB*SEQ
#define CTS 8     // conv s-tile

typedef unsigned short u16;
typedef __attribute__((ext_vector_type(8))) __bf16 bf16x8;
typedef __attribute__((ext_vector_type(4))) float f32x4;
typedef __attribute__((ext_vector_type(4))) unsigned short u16x4;
typedef __attribute__((ext_vector_type(8))) unsigned short u16x8;

__device__ __forceinline__ float bf2f(u16 x){
  return (float)__builtin_bit_cast(__bf16, x);
}
__device__ __forceinline__ u16 f2bf(float f){
  return __builtin_bit_cast(u16, (__bf16)f);
}

// async global->LDS, 16B per lane; LDS dest is wave-uniform base + lane*16
__device__ __forceinline__ void gl_lds16(const u16* g, u16* l){
  __builtin_amdgcn_global_load_lds((const __attribute__((address_space(1))) void*)g,
                                   (__attribute__((address_space(3))) void*)l, 16, 0, 0);
}

// ---------------------------------------------------------------- f32 -> bf16 cast (vectorized, grid-stride)
__global__ __launch_bounds__(256) void cast_bf(const float* __restrict__ in, u16* __restrict__ out, int n8){
  int i = blockIdx.x*256 + threadIdx.x;
  const int stride = gridDim.x*256;
  for(; i < n8; i += stride){
    float4 a = ((const float4*)in)[(size_t)i*2];
    float4 b = ((const float4*)in)[(size_t)i*2+1];
    u16x8 t;
    t[0]=f2bf(a.x); t[1]=f2bf(a.y); t[2]=f2bf(a.z); t[3]=f2bf(a.w);
    t[4]=f2bf(b.x); t[5]=f2bf(b.y); t[6]=f2bf(b.z); t[7]=f2bf(b.w);
    ((u16x8*)out)[i] = t;
  }
}

// ---------------------------------------------------------------- weight transpose: src [R,C] f32 -> dst [C,R] bf16
__global__ __launch_bounds__(256) void transpose_cast(const float* __restrict__ src, u16* __restrict__ dst, int R, int C){
  __shared__ float tile[32][33];
  int c0 = blockIdx.x*32, r0 = blockIdx.y*32;
  int tx = threadIdx.x & 31, ty = threadIdx.x >> 5;   // ty 0..7
  for(int i = ty; i < 32; i += 8) tile[i][tx] = src[(size_t)(r0+i)*C + c0 + tx];
  __syncthreads();
  for(int i = ty; i < 32; i += 8) dst[(size_t)(c0+i)*R + r0 + tx] = f2bf(tile[tx][i]);
}

// ---------------------------------------------------------------- k transpose (per batch): kb [HK][SEQ][DK] -> kbT [HK][DK][SEQ]
__global__ __launch_bounds__(256) void transpose_k(const u16* __restrict__ kb, u16* __restrict__ kbT){
  __shared__ u16 tile[32][33];
  const int h = blockIdx.z, d0 = blockIdx.y*32, s0 = blockIdx.x*32;
  const int tx = threadIdx.x & 31, ty = threadIdx.x >> 5;
  const u16* src = kb + (size_t)h*SEQ*DK;
  for(int i = ty; i < 32; i += 8) tile[i][tx] = src[(size_t)(s0+i)*DK + d0 + tx];
  __syncthreads();
  u16* dst = kbT + (size_t)h*DK*SEQ;
  for(int i = ty; i < 32; i += 8) dst[(size_t)(d0+i)*SEQ + s0 + tx] = tile[tx][i];
}

// ---------------------------------------------------------------- GEMM bf16, 256x256 tile, BK=64, 8 waves, dbuf gl_lds (r13 proven)
__device__ __forceinline__ void store_c(float* C, size_t idx, float v){ C[idx] = v; }
__device__ __forceinline__ void store_c(u16*   C, size_t idx, float v){ C[idx] = f2bf(v); }

__device__ __forceinline__ void stage256(const u16* __restrict__ A, const u16* __restrict__ Bt,
                                         size_t bm, size_t bn, int K, int k0,
                                         u16* Ab, u16* Bb, int wave, int lrow, int lg){
  const int g = lg ^ lrow;          // row&7 == lrow for all staged rows
  #pragma unroll
  for(int r = 0; r < 4; ++r){
    const int grow = r*64 + wave*8 + lrow;
    const int dst = (r>>1)*8192 + ((r&1)*64 + wave*8)*64;
    gl_lds16(&A [(bm + grow)*K + k0 + g*8], &Ab[dst]);
    gl_lds16(&Bt[(bn + grow)*K + k0 + g*8], &Bb[dst]);
  }
}

template<typename CT>
__global__ __launch_bounds__(512) void gemm256(const u16* __restrict__ A, const u16* __restrict__ Bt,
                                               CT* __restrict__ C, int M, int N, int K){
  (void)M;
  __shared__ u16 As[2][2][8192];   // [buf][half][128x64], 64KB
  __shared__ u16 Bs[2][2][8192];   // 64KB
  const int tid  = threadIdx.x;
  const int lane = tid & 63;
  const int wave = tid >> 6;       // 0..7
  const int lrow = lane >> 3, lg = lane & 7;
  // bijective XCD-chunked swizzle (all grids have nwg % 8 == 0)
  const int nwg = gridDim.x * gridDim.y;
  const int old = blockIdx.y * gridDim.x + blockIdx.x;
  const int nid = (old & 7) * (nwg >> 3) + (old >> 3);
  const int bx = nid % gridDim.x, by = nid / gridDim.x;
  const size_t bm = (size_t)by * 256;
  const size_t bn = (size_t)bx * 256;
  const int wm = (wave >> 2) * 128;     // 0 / 128
  const int wn = (wave & 3) * 64;       // 0 / 64 / 128 / 192
  const int ah = wave >> 2;             // this wave's A half
  const int bh = (wave & 3) >> 1;       // this wave's B half
  const int lwn = wn & 64;              // B row base within half
  const int cL15 = lane & 15, qq = lane >> 4;
  f32x4 acc[8][4] = {};
  const int nk = K >> 6;
  stage256(A, Bt, bm, bn, K, 0, &As[0][0][0], &Bs[0][0][0], wave, lrow, lg);
  __syncthreads();
  int cur = 0;
  for(int kt = 0; kt < nk; ++kt){
    if(kt+1 < nk)
      stage256(A, Bt, bm, bn, K, (kt+1) << 6, &As[cur^1][0][0], &Bs[cur^1][0][0], wave, lrow, lg);
    const u16* Ah = As[cur][ah];
    const u16* Bh = Bs[cur][bh];
    __builtin_amdgcn_s_setprio(1);
    #pragma unroll
    for(int kk = 0; kk < 2; ++kk){
      bf16x8 af[8], bfr[4];
      #pragma unroll
      for(int mi = 0; mi < 8; ++mi){
        int lr = mi*16 + cL15;
        int cb = (kk*64 + qq*16) ^ ((lr & 7) << 4);
        af[mi] = *(const bf16x8*)((const char*)Ah + lr*128 + cb);
      }
      #pragma unroll
      for(int ni = 0; ni < 4; ++ni){
        int lr = lwn + ni*16 + cL15;
        int cb = (kk*64 + qq*16) ^ ((lr & 7) << 4);
        bfr[ni] = *(const bf16x8*)((const char*)Bh + lr*128 + cb);
      }
      #pragma unroll
      for(int mi = 0; mi < 8; ++mi)
        #pragma unroll
        for(int ni = 0; ni < 4; ++ni)
          acc[mi][ni] = __builtin_amdgcn_mfma_f32_16x16x32_bf16(af[mi], bfr[ni], acc[mi][ni], 0, 0, 0);
    }
    __builtin_amdgcn_s_setprio(0);
    __syncthreads();   // drains gl_lds (vmcnt0) + all waves done with buf cur
    cur ^= 1;
  }
  const int c0 = (int)bn + wn + cL15;
  const int r0 = (int)bm + wm + qq*4;
  #pragma unroll
  for(int mi = 0; mi < 8; ++mi)
    #pragma unroll
    for(int ni = 0; ni < 4; ++ni)
      #pragma unroll
      for(int rr = 0; rr < 4; ++rr)
        store_c(C, (size_t)(r0 + mi*16 + rr)*N + (c0 + ni*16), acc[mi][ni][rr]);
}

// ---------------------------------------------------------------- beta/g projections (per batch), fp32 exact
__global__ __launch_bounds__(256) void proj_bg(const float* __restrict__ hs, const float* __restrict__ Wb,
      const float* __restrict__ Wa, const float* __restrict__ dtb, const float* __restrict__ A_log,
      float* __restrict__ betab, float* __restrict__ gbuf){
  __shared__ float h4[4][HID];          // 32KB: 4 rows of hs
  __shared__ float part[4][64][4];
  const int r0 = blockIdx.x * 4;
  const int tid = threadIdx.x;
  for(int i = tid; i < 4*HID/4; i += 256)
    ((float4*)&h4[0][0])[i] = ((const float4*)&hs[(size_t)r0*HID])[i];
  __syncthreads();
  const int o = tid & 63, pp = tid >> 6;
  const float* W = (o < 32) ? (Wb + o) : (Wa + (o - 32));
  float a0=0.f,a1=0.f,a2=0.f,a3=0.f;
  const int kbeg = pp*512;
  for(int kk = kbeg; kk < kbeg+512; ++kk){
    float wv = W[(size_t)kk*32];
    a0 += wv*h4[0][kk]; a1 += wv*h4[1][kk]; a2 += wv*h4[2][kk]; a3 += wv*h4[3][kk];
  }
  part[0][o][pp]=a0; part[1][o][pp]=a1; part[2][o][pp]=a2; part[3][o][pp]=a3;
  __syncthreads();
  {
    const int row = tid >> 6, oo = tid & 63;
    float sdot = part[row][oo][0]+part[row][oo][1]+part[row][oo][2]+part[row][oo][3];
    const int s = r0 + row;
    if(oo < 32){
      betab[(size_t)oo*SEQ + s] = 1.f/(1.f + __expf(-sdot));
    } else {
      const int hh = oo - 32;
      float x = sdot + dtb[hh];
      float sp = (x > 20.f) ? x : log1pf(__expf(x));
      gbuf[(size_t)hh*SEQ + s] = -__expf(A_log[hh]) * sp;
    }
  }
}

// ---------------------------------------------------------------- conv(4) + SiLU + split + l2norm -> bf16 (per batch)
__global__ __launch_bounds__(128) void conv_qkv(const u16* __restrict__ mixed, const float* __restrict__ conv_w,
      u16* __restrict__ qb, u16* __restrict__ kb, u16* __restrict__ vb){
  const int slot = blockIdx.x;          // 0..63  (16 q heads, 16 k heads, 32 v heads)
  const int s0 = blockIdx.y * CTS;      // 0..4095 step CTS
  const int t = threadIdx.x;            // 0..127
  const int c = slot*128 + t;
  __shared__ float red[CTS][2];
  float m[CTS+3];
  #pragma unroll
  for(int j = 0; j < CTS+3; ++j){
    int ss = s0 - 3 + j;
    m[j] = (ss >= 0) ? bf2f(mixed[(size_t)ss*CONV_DIM + c]) : 0.f;
  }
  const float w0 = conv_w[c*4+0], w1 = conv_w[c*4+1], w2 = conv_w[c*4+2], w3 = conv_w[c*4+3];
  float acc[CTS];
  #pragma unroll
  for(int i = 0; i < CTS; ++i){
    float a = 0.f;
    a += w0*m[i]; a += w1*m[i+1]; a += w2*m[i+2]; a += w3*m[i+3];
    acc[i] = a / (1.f + __expf(-a));    // SiLU
  }
  if(slot < 32){
    #pragma unroll
    for(int i = 0; i < CTS; ++i){
      float sq = acc[i]*acc[i];
      #pragma unroll
      for(int off = 1; off < 64; off <<= 1) sq += __shfl_xor(sq, off, 64);
      if((t & 63) == 0) red[i][t >> 6] = sq;
    }
    __syncthreads();
    #pragma unroll
    for(int i = 0; i < CTS; ++i){
      const int s = s0 + i;
      float rn = rsqrtf(red[i][0] + red[i][1] + 1e-6f);
      if(slot < 16)
        qb[((size_t)slot*SEQ + s)*DK + t] = f2bf(acc[i] * rn * 0.08838834764831845f); // * DK^-0.5
      else
        kb[((size_t)(slot-16)*SEQ + s)*DK + t] = f2bf(acc[i] * rn);
    }
  } else {
    #pragma unroll
    for(int i = 0; i < CTS; ++i)
      vb[((size_t)(slot-32)*SEQ + s0+i)*DV + t] = f2bf(acc[i]);
  }
}

// ---------------------------------------------------------------- phase A (per batch), MFMA version
__global__ __launch_bounds__(256) void phaseA(const u16* __restrict__ qb, const u16* __restrict__ kb,
      const u16* __restrict__ vb, const float* __restrict__ betab, const float* __restrict__ gb,
      float* __restrict__ gcb, u16* __restrict__ ub, u16* __restrict__ wb, u16* __restrict__ attnb){
  __shared__ __align__(16) char arena[63232];
  u16*   kS  = (u16*)(arena);
  u16*   qS  = (u16*)(arena + 17408);
  u16*   XT  = (u16*)(arena + 17408);
  u16*   VT  = (u16*)(arena + 17408);
  float* Ms  = (float*)(arena + 35840);
  u16*   vS  = (u16*)(arena + 35840);
  u16*   Tb  = (u16*)(arena + 53248);
  float* gcs   = (float*)(arena + 62464);
  float* betas = gcs + 64;
  float* wsc   = gcs + 128;

  const int n = blockIdx.x, h = blockIdx.y;
  const int hk = h >> 1;
  const int s0 = n * CHUNK;
  const int tid = threadIdx.x;
  const int lane = tid & 63;
  const int wave = tid >> 6;
  const int R0 = wave * 16;
  const size_t hS = (size_t)h*SEQ;
  const u16* kbase = kb + ((size_t)hk*SEQ + s0)*DK;
  const u16* qbase = qb + ((size_t)hk*SEQ + s0)*DK;
  const u16* vbase = vb + ((size_t)h*SEQ + s0)*DV;
  const size_t atbase = ((size_t)h*NCH + n)*64*64;
  const size_t uwbase = ((size_t)h*NCH + n)*64*128;

  // ---- phase 1: stage k,q; prefetch v into regs (used phase 5); gc scan ----
  u16x8 pv[4];
  #pragma unroll
  for(int e2 = 0; e2 < 4; ++e2){
    int e = tid + e2*256;
    int r = e >> 4, c8 = (e & 15)*8;
    pv[e2] = *(const u16x8*)&vbase[(size_t)r*128 + c8];
  }
  for(int e = tid; e < 1024; e += 256){
    int r = e >> 4, c8 = (e & 15)*8;
    *(u16x8*)&kS[r*136 + c8] = *(const u16x8*)&kbase[(size_t)r*128 + c8];
    *(u16x8*)&qS[r*136 + c8] = *(const u16x8*)&qbase[(size_t)r*128 + c8];
  }
  if(wave == 0){
    float v = gb[hS + s0 + lane];
    #pragma unroll
    for(int off = 1; off < 64; off <<= 1){
      float t = __shfl(v, (lane >= off) ? (lane - off) : lane, 64);
      if(lane >= off) v += t;
    }
    gcs[lane] = v;
    gcb[hS + s0 + lane] = v;
    float b = betab[hS + s0 + lane];
    betas[lane] = b;
    wsc[lane] = b * __expf(v);
  }
  __syncthreads();

  // ---- phase 2: S1 = k.k^T, S2 = q.k^T via MFMA; write Ms (f32) + attn (bf16) ----
  {
    f32x4 a1[4] = {}, a2[4] = {};
    #pragma unroll
    for(int ks = 0; ks < 4; ++ks){
      const int ab = (R0 + (lane & 15))*272 + ks*64 + (lane >> 4)*16;
      bf16x8 afk = *(const bf16x8*)((const char*)kS + ab);
      bf16x8 afq = *(const bf16x8*)((const char*)qS + ab);
      #pragma unroll
      for(int jt = 0; jt < 4; ++jt){
        const int bb = (jt*16 + (lane & 15))*272 + ks*64 + (lane >> 4)*16;
        bf16x8 bf = *(const bf16x8*)((const char*)kS + bb);
        a1[jt] = __builtin_amdgcn_mfma_f32_16x16x32_bf16(afk, bf, a1[jt], 0, 0, 0);
        a2[jt] = __builtin_amdgcn_mfma_f32_16x16x32_bf16(afq, bf, a2[jt], 0, 0, 0);
      }
    }
    #pragma unroll
    for(int jt = 0; jt < 4; ++jt){
      int j = jt*16 + (lane & 15);
      float gj = gcs[j];
      #pragma unroll
      for(int r = 0; r < 4; ++r){
        int i = R0 + (lane >> 4)*4 + r;
        float gi = gcs[i];
        float dec = (j <= i) ? __expf(gi - gj) : 0.f;
        Ms[i*64 + j] = (j < i) ? betas[i]*a1[jt][r]*dec : 0.f;
        attnb[atbase + (size_t)i*64 + j] = f2bf(a2[jt][r]*dec);
      }
    }
  }
  __syncthreads();

  // ---- phase 3: blocked inversion, f32 exact: Ms -> X = inv(I+M) ----
  {
    const int b0 = R0;
    const int j  = lane & 15;
    float x[16];
    #pragma unroll
    for(int i = 0; i < 16; ++i){
      float acc2 = (i == j) ? 1.f : 0.f;
      #pragma unroll
      for(int m = 0; m < 16; ++m){
        if(m < i) acc2 -= Ms[(b0+i)*64 + (b0+m)] * x[m];
      }
      x[i] = acc2;
    }
    if(lane < 16){
      #pragma unroll
      for(int i = 0; i < 16; ++i) Ms[(b0+i)*64 + (b0+j)] = x[i];
    }
  }
  __syncthreads();
  {
    float* Pscr = (float*)(arena + 17408);
    const int i = (tid >> 4) & 15, j = tid & 15;
    float P[2];
    #pragma unroll
    for(int gg = 0; gg < 2; ++gg){
      const int rb = 32*gg + 16, cb = 32*gg;
      float a = 0.f;
      #pragma unroll
      for(int k = 0; k < 16; ++k)
        a += Ms[(rb+i)*64 + cb+k] * Ms[(cb+k)*64 + cb+j];
      Pscr[gg*256 + i*16 + j] = a;
    }
    __syncthreads();
    #pragma unroll
    for(int gg = 0; gg < 2; ++gg){
      const int rb = 32*gg + 16;
      float a = 0.f;
      #pragma unroll
      for(int k = 0; k < 16; ++k)
        a -= Ms[(rb+i)*64 + rb+k] * Pscr[gg*256 + k*16 + j];
      P[gg] = a;
    }
    #pragma unroll
    for(int gg = 0; gg < 2; ++gg){
      const int rb = 32*gg + 16, cb = 32*gg;
      Ms[(rb+i)*64 + cb + j] = P[gg];
    }
  }
  __syncthreads();
  {
    float* Pscr = (float*)(arena + 17408);
    const int i = tid >> 3;
    const int j4 = (tid & 7) * 4;
    float p[4] = {0.f,0.f,0.f,0.f};
    #pragma unroll 8
    for(int k = 0; k < 32; ++k){
      float b = Ms[(32+i)*64 + k];
      #pragma unroll
      for(int c = 0; c < 4; ++c) p[c] += b * Ms[k*64 + j4 + c];
    }
    #pragma unroll
    for(int c = 0; c < 4; ++c) Pscr[i*32 + j4 + c] = p[c];
    __syncthreads();
    float q2[4] = {0.f,0.f,0.f,0.f};
    #pragma unroll 8
    for(int k = 0; k < 32; ++k){
      float xc = Ms[(32+i)*64 + 32+k];
      #pragma unroll
      for(int c = 0; c < 4; ++c) q2[c] -= xc * Pscr[k*32 + j4 + c];
    }
    #pragma unroll
    for(int c = 0; c < 4; ++c) Ms[(32+i)*64 + j4 + c] = q2[c];
  }
  __syncthreads();

  // ---- phase 4: Tb = bf16(T); XT[d][m] = bf16(k[m][d]*wsc[m]) ----
  for(int e = tid; e < 4096; e += 256){
    int i = e >> 6, j = e & 63;
    Tb[i*72 + j] = f2bf(Ms[e]);
  }
  {
    int m = tid & 63, dc = (tid >> 6)*32;
    float sc = wsc[m];
    #pragma unroll
    for(int d8 = 0; d8 < 32; d8 += 8){
      u16x8 kv = *(const u16x8*)&kS[m*136 + dc + d8];
      #pragma unroll
      for(int e = 0; e < 8; ++e)
        XT[(dc + d8 + e)*72 + m] = f2bf(bf2f(kv[e]) * sc);
    }
  }
  __syncthreads();

  // ---- phase 5: w = T @ (k*beta*e^gc) via MFMA; store prefetched v ----
  {
    f32x4 wa[8] = {};
    #pragma unroll
    for(int ks = 0; ks < 2; ++ks){
      bf16x8 at = *(const bf16x8*)((const char*)Tb + (R0 + (lane & 15))*144 + ks*64 + (lane >> 4)*16);
      #pragma unroll
      for(int dt = 0; dt < 8; ++dt){
        bf16x8 bx = *(const bf16x8*)((const char*)XT + (dt*16 + (lane & 15))*144 + ks*64 + (lane >> 4)*16);
        wa[dt] = __builtin_amdgcn_mfma_f32_16x16x32_bf16(at, bx, wa[dt], 0, 0, 0);
      }
    }
    #pragma unroll
    for(int dt = 0; dt < 8; ++dt){
      int d = dt*16 + (lane & 15);
      #pragma unroll
      for(int r = 0; r < 4; ++r){
        int i = R0 + (lane >> 4)*4 + r;
        wb[uwbase + (size_t)i*128 + d] = f2bf(wa[dt][r]);
      }
    }
  }
  #pragma unroll
  for(int e2 = 0; e2 < 4; ++e2){
    int e = tid + e2*256;
    int r = e >> 4, c8 = (e & 15)*8;
    *(u16x8*)&vS[r*136 + c8] = pv[e2];
  }
  __syncthreads();

  // ---- phase 6: VT[c][m] = bf16(v[m][c]*beta[m]) ----
  {
    int m = tid & 63, dc = (tid >> 6)*32;
    float bsc = betas[m];
    #pragma unroll
    for(int d8 = 0; d8 < 32; d8 += 8){
      u16x8 vv = *(const u16x8*)&vS[m*136 + dc + d8];
      #pragma unroll
      for(int e = 0; e < 8; ++e)
        VT[(dc + d8 + e)*72 + m] = f2bf(bf2f(vv[e]) * bsc);
    }
  }
  __syncthreads();

  // ---- phase 7: u = T @ (v*beta) via MFMA ----
  {
    f32x4 ua[8] = {};
    #pragma unroll
    for(int ks = 0; ks < 2; ++ks){
      bf16x8 at = *(const bf16x8*)((const char*)Tb + (R0 + (lane & 15))*144 + ks*64 + (lane >> 4)*16);
      #pragma unroll
      for(int dt = 0; dt < 8; ++dt){
        bf16x8 bx = *(const bf16x8*)((const char*)VT + (dt*16 + (lane & 15))*144 + ks*64 + (lane >> 4)*16);
        ua[dt] = __builtin_amdgcn_mfma_f32_16x16x32_bf16(at, bx, ua[dt], 0, 0, 0);
      }
    }
    #pragma unroll
    for(int dt = 0; dt < 8; ++dt){
      int d = dt*16 + (lane & 15);
      #pragma unroll
      for(int r = 0; r < 4; ++r){
        int i = R0 + (lane >> 4)*4 + r;
        ub[uwbase + (size_t)i*128 + d] = f2bf(ua[dt][r]);
      }
    }
  }
}

// ---------------------------------------------------------------- phase B (per batch): MFMA chunk scan, c-split x8
// T14: all global operands (w,q,attn,kbT) register-prefetched at chunk top.
__global__ __launch_bounds__(256) void phaseB(const u16* __restrict__ qb, const u16* __restrict__ kbT,
      const u16* __restrict__ ub, const u16* __restrict__ wb, const u16* __restrict__ attnb,
      const float* __restrict__ gcb, u16* __restrict__ core){
  __shared__ __align__(16) u16 STbf[16][136];   // S^T: [16 c][128 d] + pad
  __shared__ __align__(16) u16 vnT[16][72];     // vn^T (for attn@vn)
  __shared__ __align__(16) u16 vnT2[16][72];    // (vn*e^{gl-gc})^T (for state update)
  __shared__ __align__(16) u16 uS[64][24];
  __shared__ float gcs[64];
  __shared__ float egm[64];
  const int f = blockIdx.x;              // 0..255
  const int xcd = f & 7, idx = f >> 3;   // idx 0..31
  const int h = xcd*4 + (idx >> 3);      // 0..31 (4 heads per XCD)
  const int split = idx & 7;             // 0..7
  const int cbb = split*16;              // state col base
  const int hk = h >> 1;
  const int tid = threadIdx.x;
  const int lane = tid & 63, wave = tid >> 6;
  const int cL = lane & 15, qq = lane >> 4;
  const int i0w = wave*16, d0w = wave*32;
  const float* gcp = gcb + (size_t)h*SEQ;
  const u16* qbase = qb + (size_t)hk*SEQ*DK;
  const u16* kTb   = kbT + (size_t)hk*DK*SEQ;
  const size_t uwb = (size_t)h*NCH*64*128;
  const size_t atb = (size_t)h*NCH*64*64;
  u16* corep = core + (size_t)h*SEQ*DV;
  f32x4 accS[2] = {};
  for(int n = 0; n < NCH; ++n){
    const int s0 = n * CHUNK;
    // ---- chunk-top: prefetch ALL global operands into registers ----
    const u16* wrow = wb + uwb + (size_t)n*8192;
    const u16* arow = attnb + atb + (size_t)n*4096;
    bf16x8 pw[4], pq[4], pa[2], pk[4];
    #pragma unroll
    for(int ks = 0; ks < 4; ++ks){
      pw[ks] = *(const bf16x8*)&wrow[(size_t)(i0w+cL)*128 + ks*32 + qq*8];
      pq[ks] = *(const bf16x8*)&qbase[(size_t)(s0 + i0w + cL)*128 + ks*32 + qq*8];
    }
    #pragma unroll
    for(int ks = 0; ks < 2; ++ks)
      pa[ks] = *(const bf16x8*)&arow[(size_t)(i0w+cL)*64 + ks*32 + qq*8];
    if(n < NCH-1){
      #pragma unroll
      for(int ks = 0; ks < 2; ++ks)
        #pragma unroll
        for(int dt = 0; dt < 2; ++dt)
          pk[ks*2+dt] = *(const bf16x8*)&kTb[(size_t)(d0w + dt*16 + cL)*SEQ + s0 + ks*32 + qq*8];
    }
    #pragma unroll
    for(int dt = 0; dt < 2; ++dt){
      u16x4 p;
      #pragma unroll
      for(int r = 0; r < 4; ++r) p[r] = f2bf(accS[dt][r]);
      *(u16x4*)&STbf[cL][d0w + dt*16 + qq*4] = p;
    }
    {
      const u16* urow = ub + uwb + (size_t)n*8192;
      int rr = tid >> 2, c4 = (tid & 3)*4;
      *(u16x4*)&uS[rr][c4] = *(const u16x4*)&urow[(size_t)rr*128 + cbb + c4];
    }
    if(wave == 0){
      float g = gcp[s0 + lane];
      gcs[lane] = g;
      float gl = __shfl(g, 63, 64);
      egm[lane] = __expf(gl - g);
    }
    __syncthreads();
    // ---- M1: vn = u - w@S; write vnT and vnT2 ----
    bf16x8 bS[4];
    f32x4 accvn = {};
    #pragma unroll
    for(int ks = 0; ks < 4; ++ks){
      bS[ks] = *(const bf16x8*)&STbf[cL][ks*32 + qq*8];
      accvn = __builtin_amdgcn_mfma_f32_16x16x32_bf16(pw[ks], bS[ks], accvn, 0, 0, 0);
    }
    {
      u16x4 p, p2;
      #pragma unroll
      for(int r = 0; r < 4; ++r){
        int i = i0w + qq*4 + r;
        float vnv = bf2f(uS[i][cL]) - accvn[r];
        p[r]  = f2bf(vnv);
        p2[r] = f2bf(vnv * egm[i]);
      }
      *(u16x4*)&vnT [cL][i0w + qq*4] = p;
      *(u16x4*)&vnT2[cL][i0w + qq*4] = p2;
    }
    __syncthreads();
    // ---- tail: M2 o = q@S * e^gc; M3 o += attn@vn; store core; M4 state update ----
    f32x4 accO = {};
    #pragma unroll
    for(int ks = 0; ks < 4; ++ks)
      accO = __builtin_amdgcn_mfma_f32_16x16x32_bf16(pq[ks], bS[ks], accO, 0, 0, 0);
    #pragma unroll
    for(int r = 0; r < 4; ++r)
      accO[r] *= __expf(gcs[i0w + qq*4 + r]);
    #pragma unroll
    for(int ks = 0; ks < 2; ++ks){
      bf16x8 bV = *(const bf16x8*)&vnT[cL][ks*32 + qq*8];
      accO = __builtin_amdgcn_mfma_f32_16x16x32_bf16(pa[ks], bV, accO, 0, 0, 0);
    }
    #pragma unroll
    for(int r = 0; r < 4; ++r)
      corep[(size_t)(s0 + i0w + qq*4 + r)*DV + cbb + cL] = f2bf(accO[r]);
    if(n < NCH-1){
      float egl = __expf(gcs[63]);
      #pragma unroll
      for(int dt = 0; dt < 2; ++dt)
        accS[dt] *= egl;
      #pragma unroll
      for(int ks = 0; ks < 2; ++ks){
        bf16x8 bV2 = *(const bf16x8*)&vnT2[cL][ks*32 + qq*8];
        #pragma unroll
        for(int dt = 0; dt < 2; ++dt)
          accS[dt] = __builtin_amdgcn_mfma_f32_16x16x32_bf16(pk[ks*2+dt], bV2, accS[dt], 0, 0, 0);
      }
    }
    __syncthreads();
  }
}

// ---------------------------------------------------------------- gated RMSNorm * silu(z) -> bf16 (per batch)
// 8 rows per 256-thread block (2 rows concurrently x 4 iters): 8x fewer blocks.
__global__ __launch_bounds__(256) void norm_gate(const u16* __restrict__ core, const u16* __restrict__ z_bf,
      const float* __restrict__ nw, u16* __restrict__ core2){
  const int h = blockIdx.y;
  const int s0 = blockIdx.x * 8;
  const int t = threadIdx.x & 127;      // elem within row
  const int rh = threadIdx.x >> 7;      // row pair half: 0/1
  __shared__ float red[8][2];
  const float nwv = nw[t];
  #pragma unroll
  for(int i = 0; i < 8; i += 2){
    const int s = s0 + i + rh;
    float x = bf2f(core[((size_t)h*SEQ + s)*DV + t]);
    float sq = x*x;
    #pragma unroll
    for(int off = 1; off < 64; off <<= 1) sq += __shfl_xor(sq, off, 64);
    if((t & 63) == 0) red[i+rh][t >> 6] = sq;
    __syncthreads();
    float var = (red[i+rh][0] + red[i+rh][1]) * (1.f/128.f);
    float y = x * rsqrtf(var + 1e-6f) * nwv;
    float zv = bf2f(z_bf[(size_t)s*VAL_DIM + h*DV + t]);
    y *= zv / (1.f + __expf(-zv));
    core2[(size_t)s*VAL_DIM + h*DV + t] = f2bf(y);
  }
}

// ---------------------------------------------------------------- launch
extern "C" void kernel_launch(void* const* d_in, const int* in_sizes, int n_in,
                              void* d_out, int out_size, void* d_ws, size_t ws_size,
                              hipStream_t stream){
  (void)in_sizes; (void)n_in; (void)out_size;
  const float* hs     = (const float*)d_in[0];
  const float* W_qkv  = (const float*)d_in[1];
  const float* conv_w = (const float*)d_in[2];
  const float* W_z    = (const float*)d_in[3];
  const float* W_b    = (const float*)d_in[4];
  const float* W_a    = (const float*)d_in[5];
  const float* dt_b   = (const float*)d_in[6];
  const float* A_log  = (const float*)d_in[7];
  const float* norm_w = (const float*)d_in[8];
  const float* W_out  = (const float*)d_in[9];
  float* out = (float*)d_out;

  const size_t MB = 1024ULL*1024ULL;
  if (ws_size < 160*MB) return;   // diagnostic: clean absmax-fail if ws too small
  const bool big = (ws_size >= 208*MB);   // deterministic layout choice

  char* ws = (char*)d_ws;
  // ws map: [0,64M)=B  [64,96M)=C  [96,128M)=E  [128,160M)=D  [160,208M)=persistent weights (big only)
  u16*   mixed  = (u16*)ws;                      // B: gemm1 -> conv
  u16*   attnB  = (u16*)ws;                      // B[0,16M): phaseA -> phaseB
  u16*   core_b = (u16*)(ws + 16*MB);            // B[16,48M): phaseB -> norm
  float* betab  = (float*)(ws + 48*MB);          // B[48M..): proj -> phaseA
  float* gbuf   = (float*)(ws + 48*MB + 512*1024);
  float* gcbuf  = (float*)(ws + 49*MB);          // phaseA -> phaseB
  u16*   WoutT  = (u16*)ws;                      // B[0,16M): after norm_b1
  u16*   qb     = (u16*)(ws + 64*MB);            // C[0,16M)
  u16*   kb     = (u16*)(ws + 80*MB);            // C[16,32M)
  u16*   zb     = (u16*)(ws + 64*MB);            // C: gemm2 -> norm (q,k dead after phaseB/transpose_k)
  u16*   core2  = (u16*)(ws + 96*MB);            // E+D: 64M contiguous [8192][4096]
  u16*   vb     = (u16*)(ws + 128*MB);           // D: conv -> phaseA
  u16*   kbT    = (u16*)(ws + 144*MB);           // D[16,32M): transpose_k -> phaseB (v dead)
  // weight homes: persistent (big) or per-batch scratch
  u16*   WqkvT  = big ? (u16*)(ws + 160*MB) : (u16*)d_out;           // 32MB
  u16*   WzT    = big ? (u16*)(ws + 192*MB) : (u16*)(ws + 128*MB);   // 16MB
  // d_out scratch (64M): (non-big) WqkvT [0,32M) + hs_bf1 [32,48.7M) during gemm1;
  // u [0,32M) + w [32,64M) phaseA->phaseB; hs_bf2 [0,16.7M) for gemm2 (after phaseB).
  u16*   hs_bf1 = (u16*)((char*)d_out + 32*MB);
  u16*   u_d    = (u16*)d_out;
  u16*   w_d    = (u16*)((char*)d_out + 32*MB);
  u16*   hs_bf2 = (u16*)d_out;

  if(big){
    transpose_cast<<<dim3(CONV_DIM/32, HID/32), 256, 0, stream>>>(W_qkv, WqkvT, HID, CONV_DIM);
    transpose_cast<<<dim3(VAL_DIM/32,  HID/32), 256, 0, stream>>>(W_z,   WzT,   HID, VAL_DIM);
  }
  for(int b = 0; b < BB; ++b){
    const float* hs_b = hs + (size_t)b*SEQ*HID;
    u16* core2_b = core2 + (size_t)b*SEQ*VAL_DIM;
    cast_bf<<<1024, 256, 0, stream>>>(hs_b, hs_bf1, SEQ*HID/8);
    if(!big) transpose_cast<<<dim3(CONV_DIM/32, HID/32), 256, 0, stream>>>(W_qkv, WqkvT, HID, CONV_DIM);
    gemm256<u16><<<dim3(CONV_DIM/256, SEQ/256), 512, 0, stream>>>(hs_bf1, WqkvT, mixed, SEQ, CONV_DIM, HID);
    conv_qkv<<<dim3(64, SEQ/CTS), 128, 0, stream>>>(mixed, conv_w, qb, kb, vb);
    proj_bg<<<SEQ/4, 256, 0, stream>>>(hs_b, W_b, W_a, dt_b, A_log, betab, gbuf);
    phaseA<<<dim3(NCH, HV), 256, 0, stream>>>(qb, kb, vb, betab, gbuf, gcbuf, u_d, w_d, attnB);
    transpose_k<<<dim3(SEQ/32, DK/32, HK), 256, 0, stream>>>(kb, kbT);   // after phaseA (vb dead)
    phaseB<<<256, 256, 0, stream>>>(qb, kbT, u_d, w_d, attnB, gcbuf, core_b);
    cast_bf<<<1024, 256, 0, stream>>>(hs_b, hs_bf2, SEQ*HID/8);
    if(!big) transpose_cast<<<dim3(VAL_DIM/32, HID/32), 256, 0, stream>>>(W_z, WzT, HID, VAL_DIM);
    gemm256<u16><<<dim3(VAL_DIM/256, SEQ/256), 512, 0, stream>>>(hs_bf2, WzT, zb, SEQ, VAL_DIM, HID);
    norm_gate<<<dim3(SEQ/8, HV), 256, 0, stream>>>(core_b, zb, norm_w, core2_b);
  }
  transpose_cast<<<dim3(HID/32, VAL_DIM/32), 256, 0, stream>>>(W_out, WoutT, VAL_DIM, HID);
  gemm256<float><<<dim3(HID/256, BS/256), 512, 0, stream>>>(core2, WoutT, out, BS, HID, VAL_DIM);
}

// Round 18
// 1379.338 us; speedup vs baseline: 1.1330x; 1.0008x over previous
//
#include <hip/hip_runtime.h>
#include <math.h>

#define BB 2
#define SEQ 4096
#define HID 2048
#define HV 32
#define HK 16
#define DK 128
#define DV 128
#define CHUNK 64
#define NCH 64
#define KEY_DIM 2048
#define VAL_DIM 4096
#define CONV_DIM 8192
#define BS 8192   // BB*SEQ
#define CTS 8     // conv s-tile

typedef unsigned short u16;
typedef __attribute__((ext_vector_type(8))) __bf16 bf16x8;
typedef __attribute__((ext_vector_type(4))) float f32x4;
typedef __attribute__((ext_vector_type(4))) unsigned short u16x4;
typedef __attribute__((ext_vector_type(8))) unsigned short u16x8;

__device__ __forceinline__ float bf2f(u16 x){
  return (float)__builtin_bit_cast(__bf16, x);
}
__device__ __forceinline__ u16 f2bf(float f){
  return __builtin_bit_cast(u16, (__bf16)f);
}

// async global->LDS, 16B per lane; LDS dest is wave-uniform base + lane*16
__device__ __forceinline__ void gl_lds16(const u16* g, u16* l){
  __builtin_amdgcn_global_load_lds((const __attribute__((address_space(1))) void*)g,
                                   (__attribute__((address_space(3))) void*)l, 16, 0, 0);
}

// ---------------------------------------------------------------- f32 -> bf16 cast (vectorized, grid-stride)
__global__ __launch_bounds__(256) void cast_bf(const float* __restrict__ in, u16* __restrict__ out, int n8){
  int i = blockIdx.x*256 + threadIdx.x;
  const int stride = gridDim.x*256;
  for(; i < n8; i += stride){
    float4 a = ((const float4*)in)[(size_t)i*2];
    float4 b = ((const float4*)in)[(size_t)i*2+1];
    u16x8 t;
    t[0]=f2bf(a.x); t[1]=f2bf(a.y); t[2]=f2bf(a.z); t[3]=f2bf(a.w);
    t[4]=f2bf(b.x); t[5]=f2bf(b.y); t[6]=f2bf(b.z); t[7]=f2bf(b.w);
    ((u16x8*)out)[i] = t;
  }
}

// ---------------------------------------------------------------- weight transpose: src [R,C] f32 -> dst [C,R] bf16
__global__ __launch_bounds__(256) void transpose_cast(const float* __restrict__ src, u16* __restrict__ dst, int R, int C){
  __shared__ float tile[32][33];
  int c0 = blockIdx.x*32, r0 = blockIdx.y*32;
  int tx = threadIdx.x & 31, ty = threadIdx.x >> 5;   // ty 0..7
  for(int i = ty; i < 32; i += 8) tile[i][tx] = src[(size_t)(r0+i)*C + c0 + tx];
  __syncthreads();
  for(int i = ty; i < 32; i += 8) dst[(size_t)(c0+i)*R + r0 + tx] = f2bf(tile[tx][i]);
}

// ---------------------------------------------------------------- k transpose (per batch): kb [HK][SEQ][DK] -> kbT [HK][DK][SEQ]
__global__ __launch_bounds__(256) void transpose_k(const u16* __restrict__ kb, u16* __restrict__ kbT){
  __shared__ u16 tile[32][33];
  const int h = blockIdx.z, d0 = blockIdx.y*32, s0 = blockIdx.x*32;
  const int tx = threadIdx.x & 31, ty = threadIdx.x >> 5;
  const u16* src = kb + (size_t)h*SEQ*DK;
  for(int i = ty; i < 32; i += 8) tile[i][tx] = src[(size_t)(s0+i)*DK + d0 + tx];
  __syncthreads();
  u16* dst = kbT + (size_t)h*DK*SEQ;
  for(int i = ty; i < 32; i += 8) dst[(size_t)(d0+i)*SEQ + s0 + tx] = tile[tx][i];
}

// ---------------------------------------------------------------- GEMM bf16, 256x256, BK=64, 8 waves, 2-buf counted-vmcnt pipeline
// r13 compute body unchanged. Schedule per iter: stage(t+1) -> vmcnt(8)
// [oldest 8 = tile t landed; tile t+1's 8 stay in flight] -> barrier ->
// compute(t) -> barrier. Never drains to 0 mid-loop. Sync pattern
// (counted vmcnt + raw s_barrier + sched_barrier) correctness-validated in r11.
__device__ __forceinline__ void store_c(float* C, size_t idx, float v){ C[idx] = v; }
__device__ __forceinline__ void store_c(u16*   C, size_t idx, float v){ C[idx] = f2bf(v); }

__device__ __forceinline__ void stage256(const u16* __restrict__ A, const u16* __restrict__ Bt,
                                         size_t bm, size_t bn, int K, int k0,
                                         u16* Ab, u16* Bb, int wave, int lrow, int lg){
  const int g = lg ^ lrow;          // row&7 == lrow for all staged rows
  #pragma unroll
  for(int r = 0; r < 4; ++r){
    const int grow = r*64 + wave*8 + lrow;
    const int dst = (r>>1)*8192 + ((r&1)*64 + wave*8)*64;
    gl_lds16(&A [(bm + grow)*K + k0 + g*8], &Ab[dst]);
    gl_lds16(&Bt[(bn + grow)*K + k0 + g*8], &Bb[dst]);
  }
}

template<typename CT>
__global__ __launch_bounds__(512) void gemm256(const u16* __restrict__ A, const u16* __restrict__ Bt,
                                               CT* __restrict__ C, int M, int N, int K){
  (void)M;
  __shared__ u16 As[2][2][8192];   // [buf][half][128x64], 64KB
  __shared__ u16 Bs[2][2][8192];   // 64KB
  const int tid  = threadIdx.x;
  const int lane = tid & 63;
  const int wave = tid >> 6;       // 0..7
  const int lrow = lane >> 3, lg = lane & 7;
  // bijective XCD-chunked swizzle (all grids have nwg % 8 == 0)
  const int nwg = gridDim.x * gridDim.y;
  const int old = blockIdx.y * gridDim.x + blockIdx.x;
  const int nid = (old & 7) * (nwg >> 3) + (old >> 3);
  const int bx = nid % gridDim.x, by = nid / gridDim.x;
  const size_t bm = (size_t)by * 256;
  const size_t bn = (size_t)bx * 256;
  const int wm = (wave >> 2) * 128;     // 0 / 128
  const int wn = (wave & 3) * 64;       // 0 / 64 / 128 / 192
  const int ah = wave >> 2;             // this wave's A half
  const int bh = (wave & 3) >> 1;       // this wave's B half
  const int lwn = wn & 64;              // B row base within half
  const int cL15 = lane & 15, qq = lane >> 4;
  f32x4 acc[8][4] = {};
  const int nk = K >> 6;
  stage256(A, Bt, bm, bn, K, 0, &As[0][0][0], &Bs[0][0][0], wave, lrow, lg);
  for(int kt = 0; kt < nk; ++kt){
    // stage tile kt+1 into buf (kt+1)&1 (freed by iter kt-1's end barrier)
    if(kt+1 < nk){
      stage256(A, Bt, bm, bn, K, (kt+1) << 6, &As[(kt+1)&1][0][0], &Bs[(kt+1)&1][0][0], wave, lrow, lg);
      asm volatile("s_waitcnt vmcnt(8)" ::: "memory");   // tile kt landed; kt+1 in flight
    } else {
      asm volatile("s_waitcnt vmcnt(0)" ::: "memory");   // last tile: full drain
    }
    __builtin_amdgcn_s_barrier();
    __builtin_amdgcn_sched_barrier(0);
    const u16* Ah = As[kt&1][ah];
    const u16* Bh = Bs[kt&1][bh];
    __builtin_amdgcn_s_setprio(1);
    #pragma unroll
    for(int kk = 0; kk < 2; ++kk){
      bf16x8 af[8], bfr[4];
      #pragma unroll
      for(int mi = 0; mi < 8; ++mi){
        int lr = mi*16 + cL15;
        int cb = (kk*64 + qq*16) ^ ((lr & 7) << 4);
        af[mi] = *(const bf16x8*)((const char*)Ah + lr*128 + cb);
      }
      #pragma unroll
      for(int ni = 0; ni < 4; ++ni){
        int lr = lwn + ni*16 + cL15;
        int cb = (kk*64 + qq*16) ^ ((lr & 7) << 4);
        bfr[ni] = *(const bf16x8*)((const char*)Bh + lr*128 + cb);
      }
      #pragma unroll
      for(int mi = 0; mi < 8; ++mi)
        #pragma unroll
        for(int ni = 0; ni < 4; ++ni)
          acc[mi][ni] = __builtin_amdgcn_mfma_f32_16x16x32_bf16(af[mi], bfr[ni], acc[mi][ni], 0, 0, 0);
    }
    __builtin_amdgcn_s_setprio(0);
    __builtin_amdgcn_s_barrier();        // all waves done reading buf kt&1
    __builtin_amdgcn_sched_barrier(0);
  }
  const int c0 = (int)bn + wn + cL15;
  const int r0 = (int)bm + wm + qq*4;
  #pragma unroll
  for(int mi = 0; mi < 8; ++mi)
    #pragma unroll
    for(int ni = 0; ni < 4; ++ni)
      #pragma unroll
      for(int rr = 0; rr < 4; ++rr)
        store_c(C, (size_t)(r0 + mi*16 + rr)*N + (c0 + ni*16), acc[mi][ni][rr]);
}

// ---------------------------------------------------------------- beta/g projections (per batch), fp32 exact
__global__ __launch_bounds__(256) void proj_bg(const float* __restrict__ hs, const float* __restrict__ Wb,
      const float* __restrict__ Wa, const float* __restrict__ dtb, const float* __restrict__ A_log,
      float* __restrict__ betab, float* __restrict__ gbuf){
  __shared__ float h4[4][HID];          // 32KB: 4 rows of hs
  __shared__ float part[4][64][4];
  const int r0 = blockIdx.x * 4;
  const int tid = threadIdx.x;
  for(int i = tid; i < 4*HID/4; i += 256)
    ((float4*)&h4[0][0])[i] = ((const float4*)&hs[(size_t)r0*HID])[i];
  __syncthreads();
  const int o = tid & 63, pp = tid >> 6;
  const float* W = (o < 32) ? (Wb + o) : (Wa + (o - 32));
  float a0=0.f,a1=0.f,a2=0.f,a3=0.f;
  const int kbeg = pp*512;
  for(int kk = kbeg; kk < kbeg+512; ++kk){
    float wv = W[(size_t)kk*32];
    a0 += wv*h4[0][kk]; a1 += wv*h4[1][kk]; a2 += wv*h4[2][kk]; a3 += wv*h4[3][kk];
  }
  part[0][o][pp]=a0; part[1][o][pp]=a1; part[2][o][pp]=a2; part[3][o][pp]=a3;
  __syncthreads();
  {
    const int row = tid >> 6, oo = tid & 63;
    float sdot = part[row][oo][0]+part[row][oo][1]+part[row][oo][2]+part[row][oo][3];
    const int s = r0 + row;
    if(oo < 32){
      betab[(size_t)oo*SEQ + s] = 1.f/(1.f + __expf(-sdot));
    } else {
      const int hh = oo - 32;
      float x = sdot + dtb[hh];
      float sp = (x > 20.f) ? x : log1pf(__expf(x));
      gbuf[(size_t)hh*SEQ + s] = -__expf(A_log[hh]) * sp;
    }
  }
}

// ---------------------------------------------------------------- conv(4) + SiLU + split + l2norm -> bf16 (per batch)
__global__ __launch_bounds__(128) void conv_qkv(const u16* __restrict__ mixed, const float* __restrict__ conv_w,
      u16* __restrict__ qb, u16* __restrict__ kb, u16* __restrict__ vb){
  const int slot = blockIdx.x;          // 0..63  (16 q heads, 16 k heads, 32 v heads)
  const int s0 = blockIdx.y * CTS;      // 0..4095 step CTS
  const int t = threadIdx.x;            // 0..127
  const int c = slot*128 + t;
  __shared__ float red[CTS][2];
  float m[CTS+3];
  #pragma unroll
  for(int j = 0; j < CTS+3; ++j){
    int ss = s0 - 3 + j;
    m[j] = (ss >= 0) ? bf2f(mixed[(size_t)ss*CONV_DIM + c]) : 0.f;
  }
  const float w0 = conv_w[c*4+0], w1 = conv_w[c*4+1], w2 = conv_w[c*4+2], w3 = conv_w[c*4+3];
  float acc[CTS];
  #pragma unroll
  for(int i = 0; i < CTS; ++i){
    float a = 0.f;
    a += w0*m[i]; a += w1*m[i+1]; a += w2*m[i+2]; a += w3*m[i+3];
    acc[i] = a / (1.f + __expf(-a));    // SiLU
  }
  if(slot < 32){
    #pragma unroll
    for(int i = 0; i < CTS; ++i){
      float sq = acc[i]*acc[i];
      #pragma unroll
      for(int off = 1; off < 64; off <<= 1) sq += __shfl_xor(sq, off, 64);
      if((t & 63) == 0) red[i][t >> 6] = sq;
    }
    __syncthreads();
    #pragma unroll
    for(int i = 0; i < CTS; ++i){
      const int s = s0 + i;
      float rn = rsqrtf(red[i][0] + red[i][1] + 1e-6f);
      if(slot < 16)
        qb[((size_t)slot*SEQ + s)*DK + t] = f2bf(acc[i] * rn * 0.08838834764831845f); // * DK^-0.5
      else
        kb[((size_t)(slot-16)*SEQ + s)*DK + t] = f2bf(acc[i] * rn);
    }
  } else {
    #pragma unroll
    for(int i = 0; i < CTS; ++i)
      vb[((size_t)(slot-32)*SEQ + s0+i)*DV + t] = f2bf(acc[i]);
  }
}

// ---------------------------------------------------------------- phase A (per batch), MFMA version
__global__ __launch_bounds__(256) void phaseA(const u16* __restrict__ qb, const u16* __restrict__ kb,
      const u16* __restrict__ vb, const float* __restrict__ betab, const float* __restrict__ gb,
      float* __restrict__ gcb, u16* __restrict__ ub, u16* __restrict__ wb, u16* __restrict__ attnb){
  __shared__ __align__(16) char arena[63232];
  u16*   kS  = (u16*)(arena);
  u16*   qS  = (u16*)(arena + 17408);
  u16*   XT  = (u16*)(arena + 17408);
  u16*   VT  = (u16*)(arena + 17408);
  float* Ms  = (float*)(arena + 35840);
  u16*   vS  = (u16*)(arena + 35840);
  u16*   Tb  = (u16*)(arena + 53248);
  float* gcs   = (float*)(arena + 62464);
  float* betas = gcs + 64;
  float* wsc   = gcs + 128;

  const int n = blockIdx.x, h = blockIdx.y;
  const int hk = h >> 1;
  const int s0 = n * CHUNK;
  const int tid = threadIdx.x;
  const int lane = tid & 63;
  const int wave = tid >> 6;
  const int R0 = wave * 16;
  const size_t hS = (size_t)h*SEQ;
  const u16* kbase = kb + ((size_t)hk*SEQ + s0)*DK;
  const u16* qbase = qb + ((size_t)hk*SEQ + s0)*DK;
  const u16* vbase = vb + ((size_t)h*SEQ + s0)*DV;
  const size_t atbase = ((size_t)h*NCH + n)*64*64;
  const size_t uwbase = ((size_t)h*NCH + n)*64*128;

  // ---- phase 1: stage k,q; prefetch v into regs (used phase 5); gc scan ----
  u16x8 pv[4];
  #pragma unroll
  for(int e2 = 0; e2 < 4; ++e2){
    int e = tid + e2*256;
    int r = e >> 4, c8 = (e & 15)*8;
    pv[e2] = *(const u16x8*)&vbase[(size_t)r*128 + c8];
  }
  for(int e = tid; e < 1024; e += 256){
    int r = e >> 4, c8 = (e & 15)*8;
    *(u16x8*)&kS[r*136 + c8] = *(const u16x8*)&kbase[(size_t)r*128 + c8];
    *(u16x8*)&qS[r*136 + c8] = *(const u16x8*)&qbase[(size_t)r*128 + c8];
  }
  if(wave == 0){
    float v = gb[hS + s0 + lane];
    #pragma unroll
    for(int off = 1; off < 64; off <<= 1){
      float t = __shfl(v, (lane >= off) ? (lane - off) : lane, 64);
      if(lane >= off) v += t;
    }
    gcs[lane] = v;
    gcb[hS + s0 + lane] = v;
    float b = betab[hS + s0 + lane];
    betas[lane] = b;
    wsc[lane] = b * __expf(v);
  }
  __syncthreads();

  // ---- phase 2: S1 = k.k^T, S2 = q.k^T via MFMA; write Ms (f32) + attn (bf16) ----
  {
    f32x4 a1[4] = {}, a2[4] = {};
    #pragma unroll
    for(int ks = 0; ks < 4; ++ks){
      const int ab = (R0 + (lane & 15))*272 + ks*64 + (lane >> 4)*16;
      bf16x8 afk = *(const bf16x8*)((const char*)kS + ab);
      bf16x8 afq = *(const bf16x8*)((const char*)qS + ab);
      #pragma unroll
      for(int jt = 0; jt < 4; ++jt){
        const int bb = (jt*16 + (lane & 15))*272 + ks*64 + (lane >> 4)*16;
        bf16x8 bf = *(const bf16x8*)((const char*)kS + bb);
        a1[jt] = __builtin_amdgcn_mfma_f32_16x16x32_bf16(afk, bf, a1[jt], 0, 0, 0);
        a2[jt] = __builtin_amdgcn_mfma_f32_16x16x32_bf16(afq, bf, a2[jt], 0, 0, 0);
      }
    }
    #pragma unroll
    for(int jt = 0; jt < 4; ++jt){
      int j = jt*16 + (lane & 15);
      float gj = gcs[j];
      #pragma unroll
      for(int r = 0; r < 4; ++r){
        int i = R0 + (lane >> 4)*4 + r;
        float gi = gcs[i];
        float dec = (j <= i) ? __expf(gi - gj) : 0.f;
        Ms[i*64 + j] = (j < i) ? betas[i]*a1[jt][r]*dec : 0.f;
        attnb[atbase + (size_t)i*64 + j] = f2bf(a2[jt][r]*dec);
      }
    }
  }
  __syncthreads();

  // ---- phase 3: blocked inversion, f32 exact: Ms -> X = inv(I+M) ----
  {
    const int b0 = R0;
    const int j  = lane & 15;
    float x[16];
    #pragma unroll
    for(int i = 0; i < 16; ++i){
      float acc2 = (i == j) ? 1.f : 0.f;
      #pragma unroll
      for(int m = 0; m < 16; ++m){
        if(m < i) acc2 -= Ms[(b0+i)*64 + (b0+m)] * x[m];
      }
      x[i] = acc2;
    }
    if(lane < 16){
      #pragma unroll
      for(int i = 0; i < 16; ++i) Ms[(b0+i)*64 + (b0+j)] = x[i];
    }
  }
  __syncthreads();
  {
    float* Pscr = (float*)(arena + 17408);
    const int i = (tid >> 4) & 15, j = tid & 15;
    float P[2];
    #pragma unroll
    for(int gg = 0; gg < 2; ++gg){
      const int rb = 32*gg + 16, cb = 32*gg;
      float a = 0.f;
      #pragma unroll
      for(int k = 0; k < 16; ++k)
        a += Ms[(rb+i)*64 + cb+k] * Ms[(cb+k)*64 + cb+j];
      Pscr[gg*256 + i*16 + j] = a;
    }
    __syncthreads();
    #pragma unroll
    for(int gg = 0; gg < 2; ++gg){
      const int rb = 32*gg + 16;
      float a = 0.f;
      #pragma unroll
      for(int k = 0; k < 16; ++k)
        a -= Ms[(rb+i)*64 + rb+k] * Pscr[gg*256 + k*16 + j];
      P[gg] = a;
    }
    #pragma unroll
    for(int gg = 0; gg < 2; ++gg){
      const int rb = 32*gg + 16, cb = 32*gg;
      Ms[(rb+i)*64 + cb + j] = P[gg];
    }
  }
  __syncthreads();
  {
    float* Pscr = (float*)(arena + 17408);
    const int i = tid >> 3;
    const int j4 = (tid & 7) * 4;
    float p[4] = {0.f,0.f,0.f,0.f};
    #pragma unroll 8
    for(int k = 0; k < 32; ++k){
      float b = Ms[(32+i)*64 + k];
      #pragma unroll
      for(int c = 0; c < 4; ++c) p[c] += b * Ms[k*64 + j4 + c];
    }
    #pragma unroll
    for(int c = 0; c < 4; ++c) Pscr[i*32 + j4 + c] = p[c];
    __syncthreads();
    float q2[4] = {0.f,0.f,0.f,0.f};
    #pragma unroll 8
    for(int k = 0; k < 32; ++k){
      float xc = Ms[(32+i)*64 + 32+k];
      #pragma unroll
      for(int c = 0; c < 4; ++c) q2[c] -= xc * Pscr[k*32 + j4 + c];
    }
    #pragma unroll
    for(int c = 0; c < 4; ++c) Ms[(32+i)*64 + j4 + c] = q2[c];
  }
  __syncthreads();

  // ---- phase 4: Tb = bf16(T); XT[d][m] = bf16(k[m][d]*wsc[m]) ----
  for(int e = tid; e < 4096; e += 256){
    int i = e >> 6, j = e & 63;
    Tb[i*72 + j] = f2bf(Ms[e]);
  }
  {
    int m = tid & 63, dc = (tid >> 6)*32;
    float sc = wsc[m];
    #pragma unroll
    for(int d8 = 0; d8 < 32; d8 += 8){
      u16x8 kv = *(const u16x8*)&kS[m*136 + dc + d8];
      #pragma unroll
      for(int e = 0; e < 8; ++e)
        XT[(dc + d8 + e)*72 + m] = f2bf(bf2f(kv[e]) * sc);
    }
  }
  __syncthreads();

  // ---- phase 5: w = T @ (k*beta*e^gc) via MFMA; store prefetched v ----
  {
    f32x4 wa[8] = {};
    #pragma unroll
    for(int ks = 0; ks < 2; ++ks){
      bf16x8 at = *(const bf16x8*)((const char*)Tb + (R0 + (lane & 15))*144 + ks*64 + (lane >> 4)*16);
      #pragma unroll
      for(int dt = 0; dt < 8; ++dt){
        bf16x8 bx = *(const bf16x8*)((const char*)XT + (dt*16 + (lane & 15))*144 + ks*64 + (lane >> 4)*16);
        wa[dt] = __builtin_amdgcn_mfma_f32_16x16x32_bf16(at, bx, wa[dt], 0, 0, 0);
      }
    }
    #pragma unroll
    for(int dt = 0; dt < 8; ++dt){
      int d = dt*16 + (lane & 15);
      #pragma unroll
      for(int r = 0; r < 4; ++r){
        int i = R0 + (lane >> 4)*4 + r;
        wb[uwbase + (size_t)i*128 + d] = f2bf(wa[dt][r]);
      }
    }
  }
  #pragma unroll
  for(int e2 = 0; e2 < 4; ++e2){
    int e = tid + e2*256;
    int r = e >> 4, c8 = (e & 15)*8;
    *(u16x8*)&vS[r*136 + c8] = pv[e2];
  }
  __syncthreads();

  // ---- phase 6: VT[c][m] = bf16(v[m][c]*beta[m]) ----
  {
    int m = tid & 63, dc = (tid >> 6)*32;
    float bsc = betas[m];
    #pragma unroll
    for(int d8 = 0; d8 < 32; d8 += 8){
      u16x8 vv = *(const u16x8*)&vS[m*136 + dc + d8];
      #pragma unroll
      for(int e = 0; e < 8; ++e)
        VT[(dc + d8 + e)*72 + m] = f2bf(bf2f(vv[e]) * bsc);
    }
  }
  __syncthreads();

  // ---- phase 7: u = T @ (v*beta) via MFMA ----
  {
    f32x4 ua[8] = {};
    #pragma unroll
    for(int ks = 0; ks < 2; ++ks){
      bf16x8 at = *(const bf16x8*)((const char*)Tb + (R0 + (lane & 15))*144 + ks*64 + (lane >> 4)*16);
      #pragma unroll
      for(int dt = 0; dt < 8; ++dt){
        bf16x8 bx = *(const bf16x8*)((const char*)VT + (dt*16 + (lane & 15))*144 + ks*64 + (lane >> 4)*16);
        ua[dt] = __builtin_amdgcn_mfma_f32_16x16x32_bf16(at, bx, ua[dt], 0, 0, 0);
      }
    }
    #pragma unroll
    for(int dt = 0; dt < 8; ++dt){
      int d = dt*16 + (lane & 15);
      #pragma unroll
      for(int r = 0; r < 4; ++r){
        int i = R0 + (lane >> 4)*4 + r;
        ub[uwbase + (size_t)i*128 + d] = f2bf(ua[dt][r]);
      }
    }
  }
}

// ---------------------------------------------------------------- phase B (per batch): MFMA chunk scan, c-split x8
// T14: all global operands (w,q,attn,kbT) register-prefetched at chunk top.
__global__ __launch_bounds__(256) void phaseB(const u16* __restrict__ qb, const u16* __restrict__ kbT,
      const u16* __restrict__ ub, const u16* __restrict__ wb, const u16* __restrict__ attnb,
      const float* __restrict__ gcb, u16* __restrict__ core){
  __shared__ __align__(16) u16 STbf[16][136];   // S^T: [16 c][128 d] + pad
  __shared__ __align__(16) u16 vnT[16][72];     // vn^T (for attn@vn)
  __shared__ __align__(16) u16 vnT2[16][72];    // (vn*e^{gl-gc})^T (for state update)
  __shared__ __align__(16) u16 uS[64][24];
  __shared__ float gcs[64];
  __shared__ float egm[64];
  const int f = blockIdx.x;              // 0..255
  const int xcd = f & 7, idx = f >> 3;   // idx 0..31
  const int h = xcd*4 + (idx >> 3);      // 0..31 (4 heads per XCD)
  const int split = idx & 7;             // 0..7
  const int cbb = split*16;              // state col base
  const int hk = h >> 1;
  const int tid = threadIdx.x;
  const int lane = tid & 63, wave = tid >> 6;
  const int cL = lane & 15, qq = lane >> 4;
  const int i0w = wave*16, d0w = wave*32;
  const float* gcp = gcb + (size_t)h*SEQ;
  const u16* qbase = qb + (size_t)hk*SEQ*DK;
  const u16* kTb   = kbT + (size_t)hk*DK*SEQ;
  const size_t uwb = (size_t)h*NCH*64*128;
  const size_t atb = (size_t)h*NCH*64*64;
  u16* corep = core + (size_t)h*SEQ*DV;
  f32x4 accS[2] = {};
  for(int n = 0; n < NCH; ++n){
    const int s0 = n * CHUNK;
    // ---- chunk-top: prefetch ALL global operands into registers ----
    const u16* wrow = wb + uwb + (size_t)n*8192;
    const u16* arow = attnb + atb + (size_t)n*4096;
    bf16x8 pw[4], pq[4], pa[2], pk[4];
    #pragma unroll
    for(int ks = 0; ks < 4; ++ks){
      pw[ks] = *(const bf16x8*)&wrow[(size_t)(i0w+cL)*128 + ks*32 + qq*8];
      pq[ks] = *(const bf16x8*)&qbase[(size_t)(s0 + i0w + cL)*128 + ks*32 + qq*8];
    }
    #pragma unroll
    for(int ks = 0; ks < 2; ++ks)
      pa[ks] = *(const bf16x8*)&arow[(size_t)(i0w+cL)*64 + ks*32 + qq*8];
    if(n < NCH-1){
      #pragma unroll
      for(int ks = 0; ks < 2; ++ks)
        #pragma unroll
        for(int dt = 0; dt < 2; ++dt)
          pk[ks*2+dt] = *(const bf16x8*)&kTb[(size_t)(d0w + dt*16 + cL)*SEQ + s0 + ks*32 + qq*8];
    }
    #pragma unroll
    for(int dt = 0; dt < 2; ++dt){
      u16x4 p;
      #pragma unroll
      for(int r = 0; r < 4; ++r) p[r] = f2bf(accS[dt][r]);
      *(u16x4*)&STbf[cL][d0w + dt*16 + qq*4] = p;
    }
    {
      const u16* urow = ub + uwb + (size_t)n*8192;
      int rr = tid >> 2, c4 = (tid & 3)*4;
      *(u16x4*)&uS[rr][c4] = *(const u16x4*)&urow[(size_t)rr*128 + cbb + c4];
    }
    if(wave == 0){
      float g = gcp[s0 + lane];
      gcs[lane] = g;
      float gl = __shfl(g, 63, 64);
      egm[lane] = __expf(gl - g);
    }
    __syncthreads();
    // ---- M1: vn = u - w@S; write vnT and vnT2 ----
    bf16x8 bS[4];
    f32x4 accvn = {};
    #pragma unroll
    for(int ks = 0; ks < 4; ++ks){
      bS[ks] = *(const bf16x8*)&STbf[cL][ks*32 + qq*8];
      accvn = __builtin_amdgcn_mfma_f32_16x16x32_bf16(pw[ks], bS[ks], accvn, 0, 0, 0);
    }
    {
      u16x4 p, p2;
      #pragma unroll
      for(int r = 0; r < 4; ++r){
        int i = i0w + qq*4 + r;
        float vnv = bf2f(uS[i][cL]) - accvn[r];
        p[r]  = f2bf(vnv);
        p2[r] = f2bf(vnv * egm[i]);
      }
      *(u16x4*)&vnT [cL][i0w + qq*4] = p;
      *(u16x4*)&vnT2[cL][i0w + qq*4] = p2;
    }
    __syncthreads();
    // ---- tail: M2 o = q@S * e^gc; M3 o += attn@vn; store core; M4 state update ----
    f32x4 accO = {};
    #pragma unroll
    for(int ks = 0; ks < 4; ++ks)
      accO = __builtin_amdgcn_mfma_f32_16x16x32_bf16(pq[ks], bS[ks], accO, 0, 0, 0);
    #pragma unroll
    for(int r = 0; r < 4; ++r)
      accO[r] *= __expf(gcs[i0w + qq*4 + r]);
    #pragma unroll
    for(int ks = 0; ks < 2; ++ks){
      bf16x8 bV = *(const bf16x8*)&vnT[cL][ks*32 + qq*8];
      accO = __builtin_amdgcn_mfma_f32_16x16x32_bf16(pa[ks], bV, accO, 0, 0, 0);
    }
    #pragma unroll
    for(int r = 0; r < 4; ++r)
      corep[(size_t)(s0 + i0w + qq*4 + r)*DV + cbb + cL] = f2bf(accO[r]);
    if(n < NCH-1){
      float egl = __expf(gcs[63]);
      #pragma unroll
      for(int dt = 0; dt < 2; ++dt)
        accS[dt] *= egl;
      #pragma unroll
      for(int ks = 0; ks < 2; ++ks){
        bf16x8 bV2 = *(const bf16x8*)&vnT2[cL][ks*32 + qq*8];
        #pragma unroll
        for(int dt = 0; dt < 2; ++dt)
          accS[dt] = __builtin_amdgcn_mfma_f32_16x16x32_bf16(pk[ks*2+dt], bV2, accS[dt], 0, 0, 0);
      }
    }
    __syncthreads();
  }
}

// ---------------------------------------------------------------- gated RMSNorm * silu(z) -> bf16 (per batch)
// 8 rows per 256-thread block (2 rows concurrently x 4 iters): 8x fewer blocks.
__global__ __launch_bounds__(256) void norm_gate(const u16* __restrict__ core, const u16* __restrict__ z_bf,
      const float* __restrict__ nw, u16* __restrict__ core2){
  const int h = blockIdx.y;
  const int s0 = blockIdx.x * 8;
  const int t = threadIdx.x & 127;      // elem within row
  const int rh = threadIdx.x >> 7;      // row pair half: 0/1
  __shared__ float red[8][2];
  const float nwv = nw[t];
  #pragma unroll
  for(int i = 0; i < 8; i += 2){
    const int s = s0 + i + rh;
    float x = bf2f(core[((size_t)h*SEQ + s)*DV + t]);
    float sq = x*x;
    #pragma unroll
    for(int off = 1; off < 64; off <<= 1) sq += __shfl_xor(sq, off, 64);
    if((t & 63) == 0) red[i+rh][t >> 6] = sq;
    __syncthreads();
    float var = (red[i+rh][0] + red[i+rh][1]) * (1.f/128.f);
    float y = x * rsqrtf(var + 1e-6f) * nwv;
    float zv = bf2f(z_bf[(size_t)s*VAL_DIM + h*DV + t]);
    y *= zv / (1.f + __expf(-zv));
    core2[(size_t)s*VAL_DIM + h*DV + t] = f2bf(y);
  }
}

// ---------------------------------------------------------------- launch
extern "C" void kernel_launch(void* const* d_in, const int* in_sizes, int n_in,
                              void* d_out, int out_size, void* d_ws, size_t ws_size,
                              hipStream_t stream){
  (void)in_sizes; (void)n_in; (void)out_size;
  const float* hs     = (const float*)d_in[0];
  const float* W_qkv  = (const float*)d_in[1];
  const float* conv_w = (const float*)d_in[2];
  const float* W_z    = (const float*)d_in[3];
  const float* W_b    = (const float*)d_in[4];
  const float* W_a    = (const float*)d_in[5];
  const float* dt_b   = (const float*)d_in[6];
  const float* A_log  = (const float*)d_in[7];
  const float* norm_w = (const float*)d_in[8];
  const float* W_out  = (const float*)d_in[9];
  float* out = (float*)d_out;

  const size_t MB = 1024ULL*1024ULL;
  if (ws_size < 160*MB) return;   // diagnostic: clean absmax-fail if ws too small
  const bool big = (ws_size >= 208*MB);   // deterministic layout choice

  char* ws = (char*)d_ws;
  // ws map: [0,64M)=B  [64,96M)=C  [96,128M)=E  [128,160M)=D  [160,208M)=persistent weights (big only)
  u16*   mixed  = (u16*)ws;                      // B: gemm1 -> conv
  u16*   attnB  = (u16*)ws;                      // B[0,16M): phaseA -> phaseB
  u16*   core_b = (u16*)(ws + 16*MB);            // B[16,48M): phaseB -> norm
  float* betab  = (float*)(ws + 48*MB);          // B[48M..): proj -> phaseA
  float* gbuf   = (float*)(ws + 48*MB + 512*1024);
  float* gcbuf  = (float*)(ws + 49*MB);          // phaseA -> phaseB
  u16*   WoutT  = (u16*)ws;                      // B[0,16M): after norm_b1
  u16*   qb     = (u16*)(ws + 64*MB);            // C[0,16M)
  u16*   kb     = (u16*)(ws + 80*MB);            // C[16,32M)
  u16*   zb     = (u16*)(ws + 64*MB);            // C: gemm2 -> norm (q,k dead after phaseB/transpose_k)
  u16*   core2  = (u16*)(ws + 96*MB);            // E+D: 64M contiguous [8192][4096]
  u16*   vb     = (u16*)(ws + 128*MB);           // D: conv -> phaseA
  u16*   kbT    = (u16*)(ws + 144*MB);           // D[16,32M): transpose_k -> phaseB (v dead)
  // weight homes: persistent (big) or per-batch scratch
  u16*   WqkvT  = big ? (u16*)(ws + 160*MB) : (u16*)d_out;           // 32MB
  u16*   WzT    = big ? (u16*)(ws + 192*MB) : (u16*)(ws + 128*MB);   // 16MB
  // d_out scratch (64M): (non-big) WqkvT [0,32M) + hs_bf1 [32,48.7M) during gemm1;
  // u [0,32M) + w [32,64M) phaseA->phaseB; hs_bf2 [0,16.7M) for gemm2 (after phaseB).
  u16*   hs_bf1 = (u16*)((char*)d_out + 32*MB);
  u16*   u_d    = (u16*)d_out;
  u16*   w_d    = (u16*)((char*)d_out + 32*MB);
  u16*   hs_bf2 = (u16*)d_out;

  if(big){
    transpose_cast<<<dim3(CONV_DIM/32, HID/32), 256, 0, stream>>>(W_qkv, WqkvT, HID, CONV_DIM);
    transpose_cast<<<dim3(VAL_DIM/32,  HID/32), 256, 0, stream>>>(W_z,   WzT,   HID, VAL_DIM);
  }
  for(int b = 0; b < BB; ++b){
    const float* hs_b = hs + (size_t)b*SEQ*HID;
    u16* core2_b = core2 + (size_t)b*SEQ*VAL_DIM;
    cast_bf<<<1024, 256, 0, stream>>>(hs_b, hs_bf1, SEQ*HID/8);
    if(!big) transpose_cast<<<dim3(CONV_DIM/32, HID/32), 256, 0, stream>>>(W_qkv, WqkvT, HID, CONV_DIM);
    gemm256<u16><<<dim3(CONV_DIM/256, SEQ/256), 512, 0, stream>>>(hs_bf1, WqkvT, mixed, SEQ, CONV_DIM, HID);
    conv_qkv<<<dim3(64, SEQ/CTS), 128, 0, stream>>>(mixed, conv_w, qb, kb, vb);
    proj_bg<<<SEQ/4, 256, 0, stream>>>(hs_b, W_b, W_a, dt_b, A_log, betab, gbuf);
    phaseA<<<dim3(NCH, HV), 256, 0, stream>>>(qb, kb, vb, betab, gbuf, gcbuf, u_d, w_d, attnB);
    transpose_k<<<dim3(SEQ/32, DK/32, HK), 256, 0, stream>>>(kb, kbT);   // after phaseA (vb dead)
    phaseB<<<256, 256, 0, stream>>>(qb, kbT, u_d, w_d, attnB, gcbuf, core_b);
    cast_bf<<<1024, 256, 0, stream>>>(hs_b, hs_bf2, SEQ*HID/8);
    if(!big) transpose_cast<<<dim3(VAL_DIM/32, HID/32), 256, 0, stream>>>(W_z, WzT, HID, VAL_DIM);
    gemm256<u16><<<dim3(VAL_DIM/256, SEQ/256), 512, 0, stream>>>(hs_bf2, WzT, zb, SEQ, VAL_DIM, HID);
    norm_gate<<<dim3(SEQ/8, HV), 256, 0, stream>>>(core_b, zb, norm_w, core2_b);
  }
  transpose_cast<<<dim3(HID/32, VAL_DIM/32), 256, 0, stream>>>(W_out, WoutT, VAL_DIM, HID);
  gemm256<float><<<dim3(HID/256, BS/256), 512, 0, stream>>>(core2, WoutT, out, BS, HID, VAL_DIM);
}

// Round 19
// 1372.583 us; speedup vs baseline: 1.1386x; 1.0049x over previous
//
#include <hip/hip_runtime.h>
#include <math.h>

#define BB 2
#define SEQ 4096
#define HID 2048
#define HV 32
#define HK 16
#define DK 128
#define DV 128
#define CHUNK 64
#define NCH 64
#define KEY_DIM 2048
#define VAL_DIM 4096
#define CONV_DIM 8192
#define BS 8192   // BB*SEQ
#define CTS 8     // conv s-tile

typedef unsigned short u16;
typedef __attribute__((ext_vector_type(8))) __bf16 bf16x8;
typedef __attribute__((ext_vector_type(4))) float f32x4;
typedef __attribute__((ext_vector_type(4))) unsigned short u16x4;
typedef __attribute__((ext_vector_type(8))) unsigned short u16x8;

__device__ __forceinline__ float bf2f(u16 x){
  return (float)__builtin_bit_cast(__bf16, x);
}
__device__ __forceinline__ u16 f2bf(float f){
  return __builtin_bit_cast(u16, (__bf16)f);
}

// async global->LDS, 16B per lane; LDS dest is wave-uniform base + lane*16
__device__ __forceinline__ void gl_lds16(const u16* g, u16* l){
  __builtin_amdgcn_global_load_lds((const __attribute__((address_space(1))) void*)g,
                                   (__attribute__((address_space(3))) void*)l, 16, 0, 0);
}

// ---------------------------------------------------------------- f32 -> bf16 cast (vectorized, grid-stride)
__global__ __launch_bounds__(256) void cast_bf(const float* __restrict__ in, u16* __restrict__ out, int n8){
  int i = blockIdx.x*256 + threadIdx.x;
  const int stride = gridDim.x*256;
  for(; i < n8; i += stride){
    float4 a = ((const float4*)in)[(size_t)i*2];
    float4 b = ((const float4*)in)[(size_t)i*2+1];
    u16x8 t;
    t[0]=f2bf(a.x); t[1]=f2bf(a.y); t[2]=f2bf(a.z); t[3]=f2bf(a.w);
    t[4]=f2bf(b.x); t[5]=f2bf(b.y); t[6]=f2bf(b.z); t[7]=f2bf(b.w);
    ((u16x8*)out)[i] = t;
  }
}

// ---------------------------------------------------------------- weight transpose: src [R,C] f32 -> dst [C,R] bf16
__global__ __launch_bounds__(256) void transpose_cast(const float* __restrict__ src, u16* __restrict__ dst, int R, int C){
  __shared__ float tile[32][33];
  int c0 = blockIdx.x*32, r0 = blockIdx.y*32;
  int tx = threadIdx.x & 31, ty = threadIdx.x >> 5;   // ty 0..7
  for(int i = ty; i < 32; i += 8) tile[i][tx] = src[(size_t)(r0+i)*C + c0 + tx];
  __syncthreads();
  for(int i = ty; i < 32; i += 8) dst[(size_t)(c0+i)*R + r0 + tx] = f2bf(tile[tx][i]);
}

// ---------------------------------------------------------------- k transpose (per batch): kb [HK][SEQ][DK] -> kbT [HK][DK][SEQ]
__global__ __launch_bounds__(256) void transpose_k(const u16* __restrict__ kb, u16* __restrict__ kbT){
  __shared__ u16 tile[32][33];
  const int h = blockIdx.z, d0 = blockIdx.y*32, s0 = blockIdx.x*32;
  const int tx = threadIdx.x & 31, ty = threadIdx.x >> 5;
  const u16* src = kb + (size_t)h*SEQ*DK;
  for(int i = ty; i < 32; i += 8) tile[i][tx] = src[(size_t)(s0+i)*DK + d0 + tx];
  __syncthreads();
  u16* dst = kbT + (size_t)h*DK*SEQ;
  for(int i = ty; i < 32; i += 8) dst[(size_t)(d0+i)*SEQ + s0 + tx] = tile[tx][i];
}

// ---------------------------------------------------------------- GEMM bf16, 256x256, BK=64, 8 waves, 2-buf counted-vmcnt pipeline
__device__ __forceinline__ void store_c(float* C, size_t idx, float v){ C[idx] = v; }
__device__ __forceinline__ void store_c(u16*   C, size_t idx, float v){ C[idx] = f2bf(v); }

__device__ __forceinline__ void stage256(const u16* __restrict__ A, const u16* __restrict__ Bt,
                                         size_t bm, size_t bn, int K, int k0,
                                         u16* Ab, u16* Bb, int wave, int lrow, int lg){
  const int g = lg ^ lrow;          // row&7 == lrow for all staged rows
  #pragma unroll
  for(int r = 0; r < 4; ++r){
    const int grow = r*64 + wave*8 + lrow;
    const int dst = (r>>1)*8192 + ((r&1)*64 + wave*8)*64;
    gl_lds16(&A [(bm + grow)*K + k0 + g*8], &Ab[dst]);
    gl_lds16(&Bt[(bn + grow)*K + k0 + g*8], &Bb[dst]);
  }
}

template<typename CT>
__global__ __launch_bounds__(512) void gemm256(const u16* __restrict__ A, const u16* __restrict__ Bt,
                                               CT* __restrict__ C, int M, int N, int K){
  (void)M;
  __shared__ u16 As[2][2][8192];   // [buf][half][128x64], 64KB
  __shared__ u16 Bs[2][2][8192];   // 64KB
  const int tid  = threadIdx.x;
  const int lane = tid & 63;
  const int wave = tid >> 6;       // 0..7
  const int lrow = lane >> 3, lg = lane & 7;
  // bijective XCD-chunked swizzle (all grids have nwg % 8 == 0)
  const int nwg = gridDim.x * gridDim.y;
  const int old = blockIdx.y * gridDim.x + blockIdx.x;
  const int nid = (old & 7) * (nwg >> 3) + (old >> 3);
  const int bx = nid % gridDim.x, by = nid / gridDim.x;
  const size_t bm = (size_t)by * 256;
  const size_t bn = (size_t)bx * 256;
  const int wm = (wave >> 2) * 128;     // 0 / 128
  const int wn = (wave & 3) * 64;       // 0 / 64 / 128 / 192
  const int ah = wave >> 2;             // this wave's A half
  const int bh = (wave & 3) >> 1;       // this wave's B half
  const int lwn = wn & 64;              // B row base within half
  const int cL15 = lane & 15, qq = lane >> 4;
  f32x4 acc[8][4] = {};
  const int nk = K >> 6;
  stage256(A, Bt, bm, bn, K, 0, &As[0][0][0], &Bs[0][0][0], wave, lrow, lg);
  for(int kt = 0; kt < nk; ++kt){
    if(kt+1 < nk){
      stage256(A, Bt, bm, bn, K, (kt+1) << 6, &As[(kt+1)&1][0][0], &Bs[(kt+1)&1][0][0], wave, lrow, lg);
      asm volatile("s_waitcnt vmcnt(8)" ::: "memory");   // tile kt landed; kt+1 in flight
    } else {
      asm volatile("s_waitcnt vmcnt(0)" ::: "memory");   // last tile: full drain
    }
    __builtin_amdgcn_s_barrier();
    __builtin_amdgcn_sched_barrier(0);
    const u16* Ah = As[kt&1][ah];
    const u16* Bh = Bs[kt&1][bh];
    __builtin_amdgcn_s_setprio(1);
    #pragma unroll
    for(int kk = 0; kk < 2; ++kk){
      bf16x8 af[8], bfr[4];
      #pragma unroll
      for(int mi = 0; mi < 8; ++mi){
        int lr = mi*16 + cL15;
        int cb = (kk*64 + qq*16) ^ ((lr & 7) << 4);
        af[mi] = *(const bf16x8*)((const char*)Ah + lr*128 + cb);
      }
      #pragma unroll
      for(int ni = 0; ni < 4; ++ni){
        int lr = lwn + ni*16 + cL15;
        int cb = (kk*64 + qq*16) ^ ((lr & 7) << 4);
        bfr[ni] = *(const bf16x8*)((const char*)Bh + lr*128 + cb);
      }
      #pragma unroll
      for(int mi = 0; mi < 8; ++mi)
        #pragma unroll
        for(int ni = 0; ni < 4; ++ni)
          acc[mi][ni] = __builtin_amdgcn_mfma_f32_16x16x32_bf16(af[mi], bfr[ni], acc[mi][ni], 0, 0, 0);
    }
    __builtin_amdgcn_s_setprio(0);
    __builtin_amdgcn_s_barrier();        // all waves done reading buf kt&1
    __builtin_amdgcn_sched_barrier(0);
  }
  const int c0 = (int)bn + wn + cL15;
  const int r0 = (int)bm + wm + qq*4;
  #pragma unroll
  for(int mi = 0; mi < 8; ++mi)
    #pragma unroll
    for(int ni = 0; ni < 4; ++ni)
      #pragma unroll
      for(int rr = 0; rr < 4; ++rr)
        store_c(C, (size_t)(r0 + mi*16 + rr)*N + (c0 + ni*16), acc[mi][ni][rr]);
}

// ---------------------------------------------------------------- beta/g projections (per batch), fp32 exact
__global__ __launch_bounds__(256) void proj_bg(const float* __restrict__ hs, const float* __restrict__ Wb,
      const float* __restrict__ Wa, const float* __restrict__ dtb, const float* __restrict__ A_log,
      float* __restrict__ betab, float* __restrict__ gbuf){
  __shared__ float h4[4][HID];          // 32KB: 4 rows of hs
  __shared__ float part[4][64][4];
  const int r0 = blockIdx.x * 4;
  const int tid = threadIdx.x;
  for(int i = tid; i < 4*HID/4; i += 256)
    ((float4*)&h4[0][0])[i] = ((const float4*)&hs[(size_t)r0*HID])[i];
  __syncthreads();
  const int o = tid & 63, pp = tid >> 6;
  const float* W = (o < 32) ? (Wb + o) : (Wa + (o - 32));
  float a0=0.f,a1=0.f,a2=0.f,a3=0.f;
  const int kbeg = pp*512;
  for(int kk = kbeg; kk < kbeg+512; ++kk){
    float wv = W[(size_t)kk*32];
    a0 += wv*h4[0][kk]; a1 += wv*h4[1][kk]; a2 += wv*h4[2][kk]; a3 += wv*h4[3][kk];
  }
  part[0][o][pp]=a0; part[1][o][pp]=a1; part[2][o][pp]=a2; part[3][o][pp]=a3;
  __syncthreads();
  {
    const int row = tid >> 6, oo = tid & 63;
    float sdot = part[row][oo][0]+part[row][oo][1]+part[row][oo][2]+part[row][oo][3];
    const int s = r0 + row;
    if(oo < 32){
      betab[(size_t)oo*SEQ + s] = 1.f/(1.f + __expf(-sdot));
    } else {
      const int hh = oo - 32;
      float x = sdot + dtb[hh];
      float sp = (x > 20.f) ? x : log1pf(__expf(x));
      gbuf[(size_t)hh*SEQ + s] = -__expf(A_log[hh]) * sp;
    }
  }
}

// ---------------------------------------------------------------- conv(4) + SiLU + split + l2norm -> bf16 (per batch)
__global__ __launch_bounds__(128) void conv_qkv(const u16* __restrict__ mixed, const float* __restrict__ conv_w,
      u16* __restrict__ qb, u16* __restrict__ kb, u16* __restrict__ vb){
  const int slot = blockIdx.x;          // 0..63  (16 q heads, 16 k heads, 32 v heads)
  const int s0 = blockIdx.y * CTS;      // 0..4095 step CTS
  const int t = threadIdx.x;            // 0..127
  const int c = slot*128 + t;
  __shared__ float red[CTS][2];
  float m[CTS+3];
  #pragma unroll
  for(int j = 0; j < CTS+3; ++j){
    int ss = s0 - 3 + j;
    m[j] = (ss >= 0) ? bf2f(mixed[(size_t)ss*CONV_DIM + c]) : 0.f;
  }
  const float w0 = conv_w[c*4+0], w1 = conv_w[c*4+1], w2 = conv_w[c*4+2], w3 = conv_w[c*4+3];
  float acc[CTS];
  #pragma unroll
  for(int i = 0; i < CTS; ++i){
    float a = 0.f;
    a += w0*m[i]; a += w1*m[i+1]; a += w2*m[i+2]; a += w3*m[i+3];
    acc[i] = a / (1.f + __expf(-a));    // SiLU
  }
  if(slot < 32){
    #pragma unroll
    for(int i = 0; i < CTS; ++i){
      float sq = acc[i]*acc[i];
      #pragma unroll
      for(int off = 1; off < 64; off <<= 1) sq += __shfl_xor(sq, off, 64);
      if((t & 63) == 0) red[i][t >> 6] = sq;
    }
    __syncthreads();
    #pragma unroll
    for(int i = 0; i < CTS; ++i){
      const int s = s0 + i;
      float rn = rsqrtf(red[i][0] + red[i][1] + 1e-6f);
      if(slot < 16)
        qb[((size_t)slot*SEQ + s)*DK + t] = f2bf(acc[i] * rn * 0.08838834764831845f); // * DK^-0.5
      else
        kb[((size_t)(slot-16)*SEQ + s)*DK + t] = f2bf(acc[i] * rn);
    }
  } else {
    #pragma unroll
    for(int i = 0; i < CTS; ++i)
      vb[((size_t)(slot-32)*SEQ + s0+i)*DV + t] = f2bf(acc[i]);
  }
}

// ---------------------------------------------------------------- phase A (per batch), MFMA version
__global__ __launch_bounds__(256) void phaseA(const u16* __restrict__ qb, const u16* __restrict__ kb,
      const u16* __restrict__ vb, const float* __restrict__ betab, const float* __restrict__ gb,
      float* __restrict__ gcb, u16* __restrict__ ub, u16* __restrict__ wb, u16* __restrict__ attnb){
  __shared__ __align__(16) char arena[63232];
  u16*   kS  = (u16*)(arena);
  u16*   qS  = (u16*)(arena + 17408);
  u16*   XT  = (u16*)(arena + 17408);
  u16*   VT  = (u16*)(arena + 17408);
  float* Ms  = (float*)(arena + 35840);
  u16*   vS  = (u16*)(arena + 35840);
  u16*   Tb  = (u16*)(arena + 53248);
  float* gcs   = (float*)(arena + 62464);
  float* betas = gcs + 64;
  float* wsc   = gcs + 128;

  const int n = blockIdx.x, h = blockIdx.y;
  const int hk = h >> 1;
  const int s0 = n * CHUNK;
  const int tid = threadIdx.x;
  const int lane = tid & 63;
  const int wave = tid >> 6;
  const int R0 = wave * 16;
  const size_t hS = (size_t)h*SEQ;
  const u16* kbase = kb + ((size_t)hk*SEQ + s0)*DK;
  const u16* qbase = qb + ((size_t)hk*SEQ + s0)*DK;
  const u16* vbase = vb + ((size_t)h*SEQ + s0)*DV;
  const size_t atbase = ((size_t)h*NCH + n)*64*64;
  const size_t uwbase = ((size_t)h*NCH + n)*64*128;

  // ---- phase 1: stage k,q; prefetch v into regs (used phase 5); gc scan ----
  u16x8 pv[4];
  #pragma unroll
  for(int e2 = 0; e2 < 4; ++e2){
    int e = tid + e2*256;
    int r = e >> 4, c8 = (e & 15)*8;
    pv[e2] = *(const u16x8*)&vbase[(size_t)r*128 + c8];
  }
  for(int e = tid; e < 1024; e += 256){
    int r = e >> 4, c8 = (e & 15)*8;
    *(u16x8*)&kS[r*136 + c8] = *(const u16x8*)&kbase[(size_t)r*128 + c8];
    *(u16x8*)&qS[r*136 + c8] = *(const u16x8*)&qbase[(size_t)r*128 + c8];
  }
  if(wave == 0){
    float v = gb[hS + s0 + lane];
    #pragma unroll
    for(int off = 1; off < 64; off <<= 1){
      float t = __shfl(v, (lane >= off) ? (lane - off) : lane, 64);
      if(lane >= off) v += t;
    }
    gcs[lane] = v;
    gcb[hS + s0 + lane] = v;
    float b = betab[hS + s0 + lane];
    betas[lane] = b;
    wsc[lane] = b * __expf(v);
  }
  __syncthreads();

  // ---- phase 2: S1 = k.k^T, S2 = q.k^T via MFMA; write Ms (f32) + attn (bf16) ----
  {
    f32x4 a1[4] = {}, a2[4] = {};
    #pragma unroll
    for(int ks = 0; ks < 4; ++ks){
      const int ab = (R0 + (lane & 15))*272 + ks*64 + (lane >> 4)*16;
      bf16x8 afk = *(const bf16x8*)((const char*)kS + ab);
      bf16x8 afq = *(const bf16x8*)((const char*)qS + ab);
      #pragma unroll
      for(int jt = 0; jt < 4; ++jt){
        const int bb = (jt*16 + (lane & 15))*272 + ks*64 + (lane >> 4)*16;
        bf16x8 bf = *(const bf16x8*)((const char*)kS + bb);
        a1[jt] = __builtin_amdgcn_mfma_f32_16x16x32_bf16(afk, bf, a1[jt], 0, 0, 0);
        a2[jt] = __builtin_amdgcn_mfma_f32_16x16x32_bf16(afq, bf, a2[jt], 0, 0, 0);
      }
    }
    #pragma unroll
    for(int jt = 0; jt < 4; ++jt){
      int j = jt*16 + (lane & 15);
      float gj = gcs[j];
      #pragma unroll
      for(int r = 0; r < 4; ++r){
        int i = R0 + (lane >> 4)*4 + r;
        float gi = gcs[i];
        float dec = (j <= i) ? __expf(gi - gj) : 0.f;
        Ms[i*64 + j] = (j < i) ? betas[i]*a1[jt][r]*dec : 0.f;
        attnb[atbase + (size_t)i*64 + j] = f2bf(a2[jt][r]*dec);
      }
    }
  }
  __syncthreads();

  // ---- phase 3: blocked inversion, f32 exact: Ms -> X = inv(I+M) ----
  {
    const int b0 = R0;
    const int j  = lane & 15;
    float x[16];
    #pragma unroll
    for(int i = 0; i < 16; ++i){
      float acc2 = (i == j) ? 1.f : 0.f;
      #pragma unroll
      for(int m = 0; m < 16; ++m){
        if(m < i) acc2 -= Ms[(b0+i)*64 + (b0+m)] * x[m];
      }
      x[i] = acc2;
    }
    if(lane < 16){
      #pragma unroll
      for(int i = 0; i < 16; ++i) Ms[(b0+i)*64 + (b0+j)] = x[i];
    }
  }
  __syncthreads();
  {
    float* Pscr = (float*)(arena + 17408);
    const int i = (tid >> 4) & 15, j = tid & 15;
    float P[2];
    #pragma unroll
    for(int gg = 0; gg < 2; ++gg){
      const int rb = 32*gg + 16, cb = 32*gg;
      float a = 0.f;
      #pragma unroll
      for(int k = 0; k < 16; ++k)
        a += Ms[(rb+i)*64 + cb+k] * Ms[(cb+k)*64 + cb+j];
      Pscr[gg*256 + i*16 + j] = a;
    }
    __syncthreads();
    #pragma unroll
    for(int gg = 0; gg < 2; ++gg){
      const int rb = 32*gg + 16;
      float a = 0.f;
      #pragma unroll
      for(int k = 0; k < 16; ++k)
        a -= Ms[(rb+i)*64 + rb+k] * Pscr[gg*256 + k*16 + j];
      P[gg] = a;
    }
    #pragma unroll
    for(int gg = 0; gg < 2; ++gg){
      const int rb = 32*gg + 16, cb = 32*gg;
      Ms[(rb+i)*64 + cb + j] = P[gg];
    }
  }
  __syncthreads();
  {
    float* Pscr = (float*)(arena + 17408);
    const int i = tid >> 3;
    const int j4 = (tid & 7) * 4;
    float p[4] = {0.f,0.f,0.f,0.f};
    #pragma unroll 8
    for(int k = 0; k < 32; ++k){
      float b = Ms[(32+i)*64 + k];
      #pragma unroll
      for(int c = 0; c < 4; ++c) p[c] += b * Ms[k*64 + j4 + c];
    }
    #pragma unroll
    for(int c = 0; c < 4; ++c) Pscr[i*32 + j4 + c] = p[c];
    __syncthreads();
    float q2[4] = {0.f,0.f,0.f,0.f};
    #pragma unroll 8
    for(int k = 0; k < 32; ++k){
      float xc = Ms[(32+i)*64 + 32+k];
      #pragma unroll
      for(int c = 0; c < 4; ++c) q2[c] -= xc * Pscr[k*32 + j4 + c];
    }
    #pragma unroll
    for(int c = 0; c < 4; ++c) Ms[(32+i)*64 + j4 + c] = q2[c];
  }
  __syncthreads();

  // ---- phase 4: Tb = bf16(T); XT[d][m] = bf16(k[m][d]*wsc[m]) ----
  for(int e = tid; e < 4096; e += 256){
    int i = e >> 6, j = e & 63;
    Tb[i*72 + j] = f2bf(Ms[e]);
  }
  {
    int m = tid & 63, dc = (tid >> 6)*32;
    float sc = wsc[m];
    #pragma unroll
    for(int d8 = 0; d8 < 32; d8 += 8){
      u16x8 kv = *(const u16x8*)&kS[m*136 + dc + d8];
      #pragma unroll
      for(int e = 0; e < 8; ++e)
        XT[(dc + d8 + e)*72 + m] = f2bf(bf2f(kv[e]) * sc);
    }
  }
  __syncthreads();

  // ---- phase 5: w = T @ (k*beta*e^gc) via MFMA; store prefetched v ----
  {
    f32x4 wa[8] = {};
    #pragma unroll
    for(int ks = 0; ks < 2; ++ks){
      bf16x8 at = *(const bf16x8*)((const char*)Tb + (R0 + (lane & 15))*144 + ks*64 + (lane >> 4)*16);
      #pragma unroll
      for(int dt = 0; dt < 8; ++dt){
        bf16x8 bx = *(const bf16x8*)((const char*)XT + (dt*16 + (lane & 15))*144 + ks*64 + (lane >> 4)*16);
        wa[dt] = __builtin_amdgcn_mfma_f32_16x16x32_bf16(at, bx, wa[dt], 0, 0, 0);
      }
    }
    #pragma unroll
    for(int dt = 0; dt < 8; ++dt){
      int d = dt*16 + (lane & 15);
      #pragma unroll
      for(int r = 0; r < 4; ++r){
        int i = R0 + (lane >> 4)*4 + r;
        wb[uwbase + (size_t)i*128 + d] = f2bf(wa[dt][r]);
      }
    }
  }
  #pragma unroll
  for(int e2 = 0; e2 < 4; ++e2){
    int e = tid + e2*256;
    int r = e >> 4, c8 = (e & 15)*8;
    *(u16x8*)&vS[r*136 + c8] = pv[e2];
  }
  __syncthreads();

  // ---- phase 6: VT[c][m] = bf16(v[m][c]*beta[m]) ----
  {
    int m = tid & 63, dc = (tid >> 6)*32;
    float bsc = betas[m];
    #pragma unroll
    for(int d8 = 0; d8 < 32; d8 += 8){
      u16x8 vv = *(const u16x8*)&vS[m*136 + dc + d8];
      #pragma unroll
      for(int e = 0; e < 8; ++e)
        VT[(dc + d8 + e)*72 + m] = f2bf(bf2f(vv[e]) * bsc);
    }
  }
  __syncthreads();

  // ---- phase 7: u = T @ (v*beta) via MFMA ----
  {
    f32x4 ua[8] = {};
    #pragma unroll
    for(int ks = 0; ks < 2; ++ks){
      bf16x8 at = *(const bf16x8*)((const char*)Tb + (R0 + (lane & 15))*144 + ks*64 + (lane >> 4)*16);
      #pragma unroll
      for(int dt = 0; dt < 8; ++dt){
        bf16x8 bx = *(const bf16x8*)((const char*)VT + (dt*16 + (lane & 15))*144 + ks*64 + (lane >> 4)*16);
        ua[dt] = __builtin_amdgcn_mfma_f32_16x16x32_bf16(at, bx, ua[dt], 0, 0, 0);
      }
    }
    #pragma unroll
    for(int dt = 0; dt < 8; ++dt){
      int d = dt*16 + (lane & 15);
      #pragma unroll
      for(int r = 0; r < 4; ++r){
        int i = R0 + (lane >> 4)*4 + r;
        ub[uwbase + (size_t)i*128 + d] = f2bf(ua[dt][r]);
      }
    }
  }
}

// ---------------------------------------------------------------- phase B (per batch): MFMA chunk scan, c-split x8
// T14: all global operands (w,q,attn,kbT) register-prefetched at chunk top.
__global__ __launch_bounds__(256) void phaseB(const u16* __restrict__ qb, const u16* __restrict__ kbT,
      const u16* __restrict__ ub, const u16* __restrict__ wb, const u16* __restrict__ attnb,
      const float* __restrict__ gcb, u16* __restrict__ core){
  __shared__ __align__(16) u16 STbf[16][136];   // S^T: [16 c][128 d] + pad
  __shared__ __align__(16) u16 vnT[16][72];     // vn^T (for attn@vn)
  __shared__ __align__(16) u16 vnT2[16][72];    // (vn*e^{gl-gc})^T (for state update)
  __shared__ __align__(16) u16 uS[64][24];
  __shared__ float gcs[64];
  __shared__ float egm[64];
  const int f = blockIdx.x;              // 0..255
  const int xcd = f & 7, idx = f >> 3;   // idx 0..31
  const int h = xcd*4 + (idx >> 3);      // 0..31 (4 heads per XCD)
  const int split = idx & 7;             // 0..7
  const int cbb = split*16;              // state col base
  const int hk = h >> 1;
  const int tid = threadIdx.x;
  const int lane = tid & 63, wave = tid >> 6;
  const int cL = lane & 15, qq = lane >> 4;
  const int i0w = wave*16, d0w = wave*32;
  const float* gcp = gcb + (size_t)h*SEQ;
  const u16* qbase = qb + (size_t)hk*SEQ*DK;
  const u16* kTb   = kbT + (size_t)hk*DK*SEQ;
  const size_t uwb = (size_t)h*NCH*64*128;
  const size_t atb = (size_t)h*NCH*64*64;
  u16* corep = core + (size_t)h*SEQ*DV;
  f32x4 accS[2] = {};
  for(int n = 0; n < NCH; ++n){
    const int s0 = n * CHUNK;
    // ---- chunk-top: prefetch ALL global operands into registers ----
    const u16* wrow = wb + uwb + (size_t)n*8192;
    const u16* arow = attnb + atb + (size_t)n*4096;
    bf16x8 pw[4], pq[4], pa[2], pk[4];
    #pragma unroll
    for(int ks = 0; ks < 4; ++ks){
      pw[ks] = *(const bf16x8*)&wrow[(size_t)(i0w+cL)*128 + ks*32 + qq*8];
      pq[ks] = *(const bf16x8*)&qbase[(size_t)(s0 + i0w + cL)*128 + ks*32 + qq*8];
    }
    #pragma unroll
    for(int ks = 0; ks < 2; ++ks)
      pa[ks] = *(const bf16x8*)&arow[(size_t)(i0w+cL)*64 + ks*32 + qq*8];
    if(n < NCH-1){
      #pragma unroll
      for(int ks = 0; ks < 2; ++ks)
        #pragma unroll
        for(int dt = 0; dt < 2; ++dt)
          pk[ks*2+dt] = *(const bf16x8*)&kTb[(size_t)(d0w + dt*16 + cL)*SEQ + s0 + ks*32 + qq*8];
    }
    #pragma unroll
    for(int dt = 0; dt < 2; ++dt){
      u16x4 p;
      #pragma unroll
      for(int r = 0; r < 4; ++r) p[r] = f2bf(accS[dt][r]);
      *(u16x4*)&STbf[cL][d0w + dt*16 + qq*4] = p;
    }
    {
      const u16* urow = ub + uwb + (size_t)n*8192;
      int rr = tid >> 2, c4 = (tid & 3)*4;
      *(u16x4*)&uS[rr][c4] = *(const u16x4*)&urow[(size_t)rr*128 + cbb + c4];
    }
    if(wave == 0){
      float g = gcp[s0 + lane];
      gcs[lane] = g;
      float gl = __shfl(g, 63, 64);
      egm[lane] = __expf(gl - g);
    }
    __syncthreads();
    // ---- M1: vn = u - w@S; write vnT and vnT2 ----
    bf16x8 bS[4];
    f32x4 accvn = {};
    #pragma unroll
    for(int ks = 0; ks < 4; ++ks){
      bS[ks] = *(const bf16x8*)&STbf[cL][ks*32 + qq*8];
      accvn = __builtin_amdgcn_mfma_f32_16x16x32_bf16(pw[ks], bS[ks], accvn, 0, 0, 0);
    }
    {
      u16x4 p, p2;
      #pragma unroll
      for(int r = 0; r < 4; ++r){
        int i = i0w + qq*4 + r;
        float vnv = bf2f(uS[i][cL]) - accvn[r];
        p[r]  = f2bf(vnv);
        p2[r] = f2bf(vnv * egm[i]);
      }
      *(u16x4*)&vnT [cL][i0w + qq*4] = p;
      *(u16x4*)&vnT2[cL][i0w + qq*4] = p2;
    }
    __syncthreads();
    // ---- tail: M2 o = q@S * e^gc; M3 o += attn@vn; store core; M4 state update ----
    f32x4 accO = {};
    #pragma unroll
    for(int ks = 0; ks < 4; ++ks)
      accO = __builtin_amdgcn_mfma_f32_16x16x32_bf16(pq[ks], bS[ks], accO, 0, 0, 0);
    #pragma unroll
    for(int r = 0; r < 4; ++r)
      accO[r] *= __expf(gcs[i0w + qq*4 + r]);
    #pragma unroll
    for(int ks = 0; ks < 2; ++ks){
      bf16x8 bV = *(const bf16x8*)&vnT[cL][ks*32 + qq*8];
      accO = __builtin_amdgcn_mfma_f32_16x16x32_bf16(pa[ks], bV, accO, 0, 0, 0);
    }
    #pragma unroll
    for(int r = 0; r < 4; ++r)
      corep[(size_t)(s0 + i0w + qq*4 + r)*DV + cbb + cL] = f2bf(accO[r]);
    if(n < NCH-1){
      float egl = __expf(gcs[63]);
      #pragma unroll
      for(int dt = 0; dt < 2; ++dt)
        accS[dt] *= egl;
      #pragma unroll
      for(int ks = 0; ks < 2; ++ks){
        bf16x8 bV2 = *(const bf16x8*)&vnT2[cL][ks*32 + qq*8];
        #pragma unroll
        for(int dt = 0; dt < 2; ++dt)
          accS[dt] = __builtin_amdgcn_mfma_f32_16x16x32_bf16(pk[ks*2+dt], bV2, accS[dt], 0, 0, 0);
      }
    }
    __syncthreads();
  }
}

// ---------------------------------------------------------------- gated RMSNorm * silu(z) -> bf16 (per batch)
// 8 rows per 256-thread block (2 rows concurrently x 4 iters): 8x fewer blocks.
__global__ __launch_bounds__(256) void norm_gate(const u16* __restrict__ core, const u16* __restrict__ z_bf,
      const float* __restrict__ nw, u16* __restrict__ core2){
  const int h = blockIdx.y;
  const int s0 = blockIdx.x * 8;
  const int t = threadIdx.x & 127;      // elem within row
  const int rh = threadIdx.x >> 7;      // row pair half: 0/1
  __shared__ float red[8][2];
  const float nwv = nw[t];
  #pragma unroll
  for(int i = 0; i < 8; i += 2){
    const int s = s0 + i + rh;
    float x = bf2f(core[((size_t)h*SEQ + s)*DV + t]);
    float sq = x*x;
    #pragma unroll
    for(int off = 1; off < 64; off <<= 1) sq += __shfl_xor(sq, off, 64);
    if((t & 63) == 0) red[i+rh][t >> 6] = sq;
    __syncthreads();
    float var = (red[i+rh][0] + red[i+rh][1]) * (1.f/128.f);
    float y = x * rsqrtf(var + 1e-6f) * nwv;
    float zv = bf2f(z_bf[(size_t)s*VAL_DIM + h*DV + t]);
    y *= zv / (1.f + __expf(-zv));
    core2[(size_t)s*VAL_DIM + h*DV + t] = f2bf(y);
  }
}

// ---------------------------------------------------------------- launch
extern "C" void kernel_launch(void* const* d_in, const int* in_sizes, int n_in,
                              void* d_out, int out_size, void* d_ws, size_t ws_size,
                              hipStream_t stream){
  (void)in_sizes; (void)n_in; (void)out_size;
  const float* hs     = (const float*)d_in[0];
  const float* W_qkv  = (const float*)d_in[1];
  const float* conv_w = (const float*)d_in[2];
  const float* W_z    = (const float*)d_in[3];
  const float* W_b    = (const float*)d_in[4];
  const float* W_a    = (const float*)d_in[5];
  const float* dt_b   = (const float*)d_in[6];
  const float* A_log  = (const float*)d_in[7];
  const float* norm_w = (const float*)d_in[8];
  const float* W_out  = (const float*)d_in[9];
  float* out = (float*)d_out;

  const size_t MB = 1024ULL*1024ULL;
  if (ws_size < 160*MB) return;   // diagnostic: clean absmax-fail if ws too small
  const bool big  = (ws_size >= 208*MB);   // persistent weight transposes
  const bool big2 = (ws_size >= 224*MB);   // + persistent per-batch hs_bf (single cast)

  char* ws = (char*)d_ws;
  // ws map: [0,64M)=B  [64,96M)=C  [96,128M)=E  [128,160M)=D
  //         [160,208M)=persistent weights (big)  [208,224M)=hs_bf (big2)
  u16*   mixed  = (u16*)ws;                      // B: gemm1 -> conv
  u16*   attnB  = (u16*)ws;                      // B[0,16M): phaseA -> phaseB
  u16*   core_b = (u16*)(ws + 16*MB);            // B[16,48M): phaseB -> norm
  float* betab  = (float*)(ws + 48*MB);          // B[48M..): proj -> phaseA
  float* gbuf   = (float*)(ws + 48*MB + 512*1024);
  float* gcbuf  = (float*)(ws + 49*MB);          // phaseA -> phaseB
  u16*   WoutT  = (u16*)ws;                      // B[0,16M): after norm_b1
  u16*   qb     = (u16*)(ws + 64*MB);            // C[0,16M)
  u16*   kb     = (u16*)(ws + 80*MB);            // C[16,32M)
  u16*   zb     = (u16*)(ws + 64*MB);            // C: gemm2 -> norm (q,k dead after phaseB/transpose_k)
  u16*   core2  = (u16*)(ws + 96*MB);            // E+D: 64M contiguous [8192][4096]
  u16*   vb     = (u16*)(ws + 128*MB);           // D: conv -> phaseA
  u16*   kbT    = (u16*)(ws + 144*MB);           // D[16,32M): transpose_k -> phaseB (v dead)
  // weight homes: persistent (big) or per-batch scratch
  u16*   WqkvT  = big ? (u16*)(ws + 160*MB) : (u16*)d_out;           // 32MB
  u16*   WzT    = big ? (u16*)(ws + 192*MB) : (u16*)(ws + 128*MB);   // 16MB
  // d_out scratch (64M): (non-big) WqkvT [0,32M) + hs_bf1 [32,48.7M) during gemm1;
  // u [0,32M) + w [32,64M) phaseA->phaseB; hs_bf2 [0,16.7M) for gemm2 (after phaseB).
  u16*   hs_bf1 = big2 ? (u16*)(ws + 208*MB) : (u16*)((char*)d_out + 32*MB);
  u16*   u_d    = (u16*)d_out;
  u16*   w_d    = (u16*)((char*)d_out + 32*MB);
  u16*   hs_bf2 = big2 ? (u16*)(ws + 208*MB) : (u16*)d_out;   // big2: same persistent buffer

  if(big){
    transpose_cast<<<dim3(CONV_DIM/32, HID/32), 256, 0, stream>>>(W_qkv, WqkvT, HID, CONV_DIM);
    transpose_cast<<<dim3(VAL_DIM/32,  HID/32), 256, 0, stream>>>(W_z,   WzT,   HID, VAL_DIM);
  }
  for(int b = 0; b < BB; ++b){
    const float* hs_b = hs + (size_t)b*SEQ*HID;
    u16* core2_b = core2 + (size_t)b*SEQ*VAL_DIM;
    cast_bf<<<1024, 256, 0, stream>>>(hs_b, hs_bf1, SEQ*HID/8);
    if(!big) transpose_cast<<<dim3(CONV_DIM/32, HID/32), 256, 0, stream>>>(W_qkv, WqkvT, HID, CONV_DIM);
    gemm256<u16><<<dim3(CONV_DIM/256, SEQ/256), 512, 0, stream>>>(hs_bf1, WqkvT, mixed, SEQ, CONV_DIM, HID);
    conv_qkv<<<dim3(64, SEQ/CTS), 128, 0, stream>>>(mixed, conv_w, qb, kb, vb);
    proj_bg<<<SEQ/4, 256, 0, stream>>>(hs_b, W_b, W_a, dt_b, A_log, betab, gbuf);
    phaseA<<<dim3(NCH, HV), 256, 0, stream>>>(qb, kb, vb, betab, gbuf, gcbuf, u_d, w_d, attnB);
    transpose_k<<<dim3(SEQ/32, DK/32, HK), 256, 0, stream>>>(kb, kbT);   // after phaseA (vb dead)
    phaseB<<<256, 256, 0, stream>>>(qb, kbT, u_d, w_d, attnB, gcbuf, core_b);
    if(!big2) cast_bf<<<1024, 256, 0, stream>>>(hs_b, hs_bf2, SEQ*HID/8);
    if(!big) transpose_cast<<<dim3(VAL_DIM/32, HID/32), 256, 0, stream>>>(W_z, WzT, HID, VAL_DIM);
    gemm256<u16><<<dim3(VAL_DIM/256, SEQ/256), 512, 0, stream>>>(hs_bf2, WzT, zb, SEQ, VAL_DIM, HID);
    norm_gate<<<dim3(SEQ/8, HV), 256, 0, stream>>>(core_b, zb, norm_w, core2_b);
  }
  transpose_cast<<<dim3(HID/32, VAL_DIM/32), 256, 0, stream>>>(W_out, WoutT, VAL_DIM, HID);
  gemm256<float><<<dim3(HID/256, BS/256), 512, 0, stream>>>(core2, WoutT, out, BS, HID, VAL_DIM);
}

// Round 20
// 1321.520 us; speedup vs baseline: 1.1826x; 1.0386x over previous
//
#include <hip/hip_runtime.h>
#include <math.h>

#define BB 2
#define SEQ 4096
#define HID 2048
#define HV 32
#define HK 16
#define DK 128
#define DV 128
#define CHUNK 64
#define NCH 64
#define KEY_DIM 2048
#define VAL_DIM 4096
#define CONV_DIM 8192
#define BS 8192   // BB*SEQ
#define CTS 8     // conv s-tile

typedef unsigned short u16;
typedef __attribute__((ext_vector_type(8))) __bf16 bf16x8;
typedef __attribute__((ext_vector_type(4))) float f32x4;
typedef __attribute__((ext_vector_type(4))) unsigned short u16x4;
typedef __attribute__((ext_vector_type(8))) unsigned short u16x8;

__device__ __forceinline__ float bf2f(u16 x){
  return (float)__builtin_bit_cast(__bf16, x);
}
__device__ __forceinline__ u16 f2bf(float f){
  return __builtin_bit_cast(u16, (__bf16)f);
}

// async global->LDS, 16B per lane; LDS dest is wave-uniform base + lane*16
__device__ __forceinline__ void gl_lds16(const u16* g, u16* l){
  __builtin_amdgcn_global_load_lds((const __attribute__((address_space(1))) void*)g,
                                   (__attribute__((address_space(3))) void*)l, 16, 0, 0);
}

// ---------------------------------------------------------------- f32 -> bf16 cast (vectorized, grid-stride)
__global__ __launch_bounds__(256) void cast_bf(const float* __restrict__ in, u16* __restrict__ out, int n8){
  int i = blockIdx.x*256 + threadIdx.x;
  const int stride = gridDim.x*256;
  for(; i < n8; i += stride){
    float4 a = ((const float4*)in)[(size_t)i*2];
    float4 b = ((const float4*)in)[(size_t)i*2+1];
    u16x8 t;
    t[0]=f2bf(a.x); t[1]=f2bf(a.y); t[2]=f2bf(a.z); t[3]=f2bf(a.w);
    t[4]=f2bf(b.x); t[5]=f2bf(b.y); t[6]=f2bf(b.z); t[7]=f2bf(b.w);
    ((u16x8*)out)[i] = t;
  }
}

// ---------------------------------------------------------------- weight transpose: src [R,C] f32 -> dst [C,R] bf16
__global__ __launch_bounds__(256) void transpose_cast(const float* __restrict__ src, u16* __restrict__ dst, int R, int C){
  __shared__ float tile[32][33];
  int c0 = blockIdx.x*32, r0 = blockIdx.y*32;
  int tx = threadIdx.x & 31, ty = threadIdx.x >> 5;   // ty 0..7
  for(int i = ty; i < 32; i += 8) tile[i][tx] = src[(size_t)(r0+i)*C + c0 + tx];
  __syncthreads();
  for(int i = ty; i < 32; i += 8) dst[(size_t)(c0+i)*R + r0 + tx] = f2bf(tile[tx][i]);
}

// ---------------------------------------------------------------- k transpose (per batch): kb [HK][SEQ][DK] -> kbT [HK][DK][SEQ]
__global__ __launch_bounds__(256) void transpose_k(const u16* __restrict__ kb, u16* __restrict__ kbT){
  __shared__ u16 tile[32][33];
  const int h = blockIdx.z, d0 = blockIdx.y*32, s0 = blockIdx.x*32;
  const int tx = threadIdx.x & 31, ty = threadIdx.x >> 5;
  const u16* src = kb + (size_t)h*SEQ*DK;
  for(int i = ty; i < 32; i += 8) tile[i][tx] = src[(size_t)(s0+i)*DK + d0 + tx];
  __syncthreads();
  u16* dst = kbT + (size_t)h*DK*SEQ;
  for(int i = ty; i < 32; i += 8) dst[(size_t)(d0+i)*SEQ + s0 + tx] = tile[tx][i];
}

// ---------------------------------------------------------------- GEMM bf16, 256x256, BK=64, 8 waves, 2-buf counted-vmcnt pipeline
__device__ __forceinline__ void store_c(float* C, size_t idx, float v){ C[idx] = v; }
__device__ __forceinline__ void store_c(u16*   C, size_t idx, float v){ C[idx] = f2bf(v); }

__device__ __forceinline__ void stage256(const u16* __restrict__ A, const u16* __restrict__ Bt,
                                         size_t bm, size_t bn, int K, int k0,
                                         u16* Ab, u16* Bb, int wave, int lrow, int lg){
  const int g = lg ^ lrow;          // row&7 == lrow for all staged rows
  #pragma unroll
  for(int r = 0; r < 4; ++r){
    const int grow = r*64 + wave*8 + lrow;
    const int dst = (r>>1)*8192 + ((r&1)*64 + wave*8)*64;
    gl_lds16(&A [(bm + grow)*K + k0 + g*8], &Ab[dst]);
    gl_lds16(&Bt[(bn + grow)*K + k0 + g*8], &Bb[dst]);
  }
}

template<typename CT>
__global__ __launch_bounds__(512) void gemm256(const u16* __restrict__ A, const u16* __restrict__ Bt,
                                               CT* __restrict__ C, int M, int N, int K){
  (void)M;
  __shared__ u16 As[2][2][8192];   // [buf][half][128x64], 64KB
  __shared__ u16 Bs[2][2][8192];   // 64KB
  const int tid  = threadIdx.x;
  const int lane = tid & 63;
  const int wave = tid >> 6;       // 0..7
  const int lrow = lane >> 3, lg = lane & 7;
  // bijective XCD-chunked swizzle (all grids have nwg % 8 == 0)
  const int nwg = gridDim.x * gridDim.y;
  const int old = blockIdx.y * gridDim.x + blockIdx.x;
  const int nid = (old & 7) * (nwg >> 3) + (old >> 3);
  const int bx = nid % gridDim.x, by = nid / gridDim.x;
  const size_t bm = (size_t)by * 256;
  const size_t bn = (size_t)bx * 256;
  const int wm = (wave >> 2) * 128;     // 0 / 128
  const int wn = (wave & 3) * 64;       // 0 / 64 / 128 / 192
  const int ah = wave >> 2;             // this wave's A half
  const int bh = (wave & 3) >> 1;       // this wave's B half
  const int lwn = wn & 64;              // B row base within half
  const int cL15 = lane & 15, qq = lane >> 4;
  f32x4 acc[8][4] = {};
  const int nk = K >> 6;
  stage256(A, Bt, bm, bn, K, 0, &As[0][0][0], &Bs[0][0][0], wave, lrow, lg);
  for(int kt = 0; kt < nk; ++kt){
    if(kt+1 < nk){
      stage256(A, Bt, bm, bn, K, (kt+1) << 6, &As[(kt+1)&1][0][0], &Bs[(kt+1)&1][0][0], wave, lrow, lg);
      asm volatile("s_waitcnt vmcnt(8)" ::: "memory");   // tile kt landed; kt+1 in flight
    } else {
      asm volatile("s_waitcnt vmcnt(0)" ::: "memory");   // last tile: full drain
    }
    __builtin_amdgcn_s_barrier();
    __builtin_amdgcn_sched_barrier(0);
    const u16* Ah = As[kt&1][ah];
    const u16* Bh = Bs[kt&1][bh];
    __builtin_amdgcn_s_setprio(1);
    #pragma unroll
    for(int kk = 0; kk < 2; ++kk){
      bf16x8 af[8], bfr[4];
      #pragma unroll
      for(int mi = 0; mi < 8; ++mi){
        int lr = mi*16 + cL15;
        int cb = (kk*64 + qq*16) ^ ((lr & 7) << 4);
        af[mi] = *(const bf16x8*)((const char*)Ah + lr*128 + cb);
      }
      #pragma unroll
      for(int ni = 0; ni < 4; ++ni){
        int lr = lwn + ni*16 + cL15;
        int cb = (kk*64 + qq*16) ^ ((lr & 7) << 4);
        bfr[ni] = *(const bf16x8*)((const char*)Bh + lr*128 + cb);
      }
      #pragma unroll
      for(int mi = 0; mi < 8; ++mi)
        #pragma unroll
        for(int ni = 0; ni < 4; ++ni)
          acc[mi][ni] = __builtin_amdgcn_mfma_f32_16x16x32_bf16(af[mi], bfr[ni], acc[mi][ni], 0, 0, 0);
    }
    __builtin_amdgcn_s_setprio(0);
    __builtin_amdgcn_s_barrier();        // all waves done reading buf kt&1
    __builtin_amdgcn_sched_barrier(0);
  }
  const int c0 = (int)bn + wn + cL15;
  const int r0 = (int)bm + wm + qq*4;
  #pragma unroll
  for(int mi = 0; mi < 8; ++mi)
    #pragma unroll
    for(int ni = 0; ni < 4; ++ni)
      #pragma unroll
      for(int rr = 0; rr < 4; ++rr)
        store_c(C, (size_t)(r0 + mi*16 + rr)*N + (c0 + ni*16), acc[mi][ni][rr]);
}

// ---------------------------------------------------------------- beta/g projections (per batch), fp32 exact
__global__ __launch_bounds__(256) void proj_bg(const float* __restrict__ hs, const float* __restrict__ Wb,
      const float* __restrict__ Wa, const float* __restrict__ dtb, const float* __restrict__ A_log,
      float* __restrict__ betab, float* __restrict__ gbuf){
  __shared__ float h4[4][HID];          // 32KB: 4 rows of hs
  __shared__ float part[4][64][4];
  const int r0 = blockIdx.x * 4;
  const int tid = threadIdx.x;
  for(int i = tid; i < 4*HID/4; i += 256)
    ((float4*)&h4[0][0])[i] = ((const float4*)&hs[(size_t)r0*HID])[i];
  __syncthreads();
  const int o = tid & 63, pp = tid >> 6;
  const float* W = (o < 32) ? (Wb + o) : (Wa + (o - 32));
  float a0=0.f,a1=0.f,a2=0.f,a3=0.f;
  const int kbeg = pp*512;
  for(int kk = kbeg; kk < kbeg+512; ++kk){
    float wv = W[(size_t)kk*32];
    a0 += wv*h4[0][kk]; a1 += wv*h4[1][kk]; a2 += wv*h4[2][kk]; a3 += wv*h4[3][kk];
  }
  part[0][o][pp]=a0; part[1][o][pp]=a1; part[2][o][pp]=a2; part[3][o][pp]=a3;
  __syncthreads();
  {
    const int row = tid >> 6, oo = tid & 63;
    float sdot = part[row][oo][0]+part[row][oo][1]+part[row][oo][2]+part[row][oo][3];
    const int s = r0 + row;
    if(oo < 32){
      betab[(size_t)oo*SEQ + s] = 1.f/(1.f + __expf(-sdot));
    } else {
      const int hh = oo - 32;
      float x = sdot + dtb[hh];
      float sp = (x > 20.f) ? x : log1pf(__expf(x));
      gbuf[(size_t)hh*SEQ + s] = -__expf(A_log[hh]) * sp;
    }
  }
}

// ---------------------------------------------------------------- conv(4) + SiLU + split + l2norm -> bf16 (per batch)
__global__ __launch_bounds__(128) void conv_qkv(const u16* __restrict__ mixed, const float* __restrict__ conv_w,
      u16* __restrict__ qb, u16* __restrict__ kb, u16* __restrict__ vb){
  const int slot = blockIdx.x;          // 0..63  (16 q heads, 16 k heads, 32 v heads)
  const int s0 = blockIdx.y * CTS;      // 0..4095 step CTS
  const int t = threadIdx.x;            // 0..127
  const int c = slot*128 + t;
  __shared__ float red[CTS][2];
  float m[CTS+3];
  #pragma unroll
  for(int j = 0; j < CTS+3; ++j){
    int ss = s0 - 3 + j;
    m[j] = (ss >= 0) ? bf2f(mixed[(size_t)ss*CONV_DIM + c]) : 0.f;
  }
  const float w0 = conv_w[c*4+0], w1 = conv_w[c*4+1], w2 = conv_w[c*4+2], w3 = conv_w[c*4+3];
  float acc[CTS];
  #pragma unroll
  for(int i = 0; i < CTS; ++i){
    float a = 0.f;
    a += w0*m[i]; a += w1*m[i+1]; a += w2*m[i+2]; a += w3*m[i+3];
    acc[i] = a / (1.f + __expf(-a));    // SiLU
  }
  if(slot < 32){
    #pragma unroll
    for(int i = 0; i < CTS; ++i){
      float sq = acc[i]*acc[i];
      #pragma unroll
      for(int off = 1; off < 64; off <<= 1) sq += __shfl_xor(sq, off, 64);
      if((t & 63) == 0) red[i][t >> 6] = sq;
    }
    __syncthreads();
    #pragma unroll
    for(int i = 0; i < CTS; ++i){
      const int s = s0 + i;
      float rn = rsqrtf(red[i][0] + red[i][1] + 1e-6f);
      if(slot < 16)
        qb[((size_t)slot*SEQ + s)*DK + t] = f2bf(acc[i] * rn * 0.08838834764831845f); // * DK^-0.5
      else
        kb[((size_t)(slot-16)*SEQ + s)*DK + t] = f2bf(acc[i] * rn);
    }
  } else {
    #pragma unroll
    for(int i = 0; i < CTS; ++i)
      vb[((size_t)(slot-32)*SEQ + s0+i)*DV + t] = f2bf(acc[i]);
  }
}

// ---------------------------------------------------------------- phase A (per batch), MFMA version
__global__ __launch_bounds__(256) void phaseA(const u16* __restrict__ qb, const u16* __restrict__ kb,
      const u16* __restrict__ vb, const float* __restrict__ betab, const float* __restrict__ gb,
      float* __restrict__ gcb, u16* __restrict__ ub, u16* __restrict__ wb, u16* __restrict__ attnb){
  __shared__ __align__(16) char arena[63232];
  u16*   kS  = (u16*)(arena);
  u16*   qS  = (u16*)(arena + 17408);
  u16*   XT  = (u16*)(arena + 17408);
  u16*   VT  = (u16*)(arena + 17408);
  float* Ms  = (float*)(arena + 35840);
  u16*   vS  = (u16*)(arena + 35840);
  u16*   Tb  = (u16*)(arena + 53248);
  float* gcs   = (float*)(arena + 62464);
  float* betas = gcs + 64;
  float* wsc   = gcs + 128;

  const int n = blockIdx.x, h = blockIdx.y;
  const int hk = h >> 1;
  const int s0 = n * CHUNK;
  const int tid = threadIdx.x;
  const int lane = tid & 63;
  const int wave = tid >> 6;
  const int R0 = wave * 16;
  const size_t hS = (size_t)h*SEQ;
  const u16* kbase = kb + ((size_t)hk*SEQ + s0)*DK;
  const u16* qbase = qb + ((size_t)hk*SEQ + s0)*DK;
  const u16* vbase = vb + ((size_t)h*SEQ + s0)*DV;
  const size_t atbase = ((size_t)h*NCH + n)*64*64;
  const size_t uwbase = ((size_t)h*NCH + n)*64*128;

  // ---- phase 1: stage k,q; prefetch v into regs (used phase 5); gc scan ----
  u16x8 pv[4];
  #pragma unroll
  for(int e2 = 0; e2 < 4; ++e2){
    int e = tid + e2*256;
    int r = e >> 4, c8 = (e & 15)*8;
    pv[e2] = *(const u16x8*)&vbase[(size_t)r*128 + c8];
  }
  for(int e = tid; e < 1024; e += 256){
    int r = e >> 4, c8 = (e & 15)*8;
    *(u16x8*)&kS[r*136 + c8] = *(const u16x8*)&kbase[(size_t)r*128 + c8];
    *(u16x8*)&qS[r*136 + c8] = *(const u16x8*)&qbase[(size_t)r*128 + c8];
  }
  if(wave == 0){
    float v = gb[hS + s0 + lane];
    #pragma unroll
    for(int off = 1; off < 64; off <<= 1){
      float t = __shfl(v, (lane >= off) ? (lane - off) : lane, 64);
      if(lane >= off) v += t;
    }
    gcs[lane] = v;
    gcb[hS + s0 + lane] = v;
    float b = betab[hS + s0 + lane];
    betas[lane] = b;
    wsc[lane] = b * __expf(v);
  }
  __syncthreads();

  // ---- phase 2: S1 = k.k^T, S2 = q.k^T via MFMA; write Ms (f32) + attn (bf16) ----
  {
    f32x4 a1[4] = {}, a2[4] = {};
    #pragma unroll
    for(int ks = 0; ks < 4; ++ks){
      const int ab = (R0 + (lane & 15))*272 + ks*64 + (lane >> 4)*16;
      bf16x8 afk = *(const bf16x8*)((const char*)kS + ab);
      bf16x8 afq = *(const bf16x8*)((const char*)qS + ab);
      #pragma unroll
      for(int jt = 0; jt < 4; ++jt){
        const int bb = (jt*16 + (lane & 15))*272 + ks*64 + (lane >> 4)*16;
        bf16x8 bf = *(const bf16x8*)((const char*)kS + bb);
        a1[jt] = __builtin_amdgcn_mfma_f32_16x16x32_bf16(afk, bf, a1[jt], 0, 0, 0);
        a2[jt] = __builtin_amdgcn_mfma_f32_16x16x32_bf16(afq, bf, a2[jt], 0, 0, 0);
      }
    }
    #pragma unroll
    for(int jt = 0; jt < 4; ++jt){
      int j = jt*16 + (lane & 15);
      float gj = gcs[j];
      #pragma unroll
      for(int r = 0; r < 4; ++r){
        int i = R0 + (lane >> 4)*4 + r;
        float gi = gcs[i];
        float dec = (j <= i) ? __expf(gi - gj) : 0.f;
        Ms[i*64 + j] = (j < i) ? betas[i]*a1[jt][r]*dec : 0.f;
        attnb[atbase + (size_t)i*64 + j] = f2bf(a2[jt][r]*dec);
      }
    }
  }
  __syncthreads();

  // ---- phase 3: blocked inversion, f32 exact: Ms -> X = inv(I+M) ----
  {
    const int b0 = R0;
    const int j  = lane & 15;
    float x[16];
    #pragma unroll
    for(int i = 0; i < 16; ++i){
      float acc2 = (i == j) ? 1.f : 0.f;
      #pragma unroll
      for(int m = 0; m < 16; ++m){
        if(m < i) acc2 -= Ms[(b0+i)*64 + (b0+m)] * x[m];
      }
      x[i] = acc2;
    }
    if(lane < 16){
      #pragma unroll
      for(int i = 0; i < 16; ++i) Ms[(b0+i)*64 + (b0+j)] = x[i];
    }
  }
  __syncthreads();
  {
    float* Pscr = (float*)(arena + 17408);
    const int i = (tid >> 4) & 15, j = tid & 15;
    float P[2];
    #pragma unroll
    for(int gg = 0; gg < 2; ++gg){
      const int rb = 32*gg + 16, cb = 32*gg;
      float a = 0.f;
      #pragma unroll
      for(int k = 0; k < 16; ++k)
        a += Ms[(rb+i)*64 + cb+k] * Ms[(cb+k)*64 + cb+j];
      Pscr[gg*256 + i*16 + j] = a;
    }
    __syncthreads();
    #pragma unroll
    for(int gg = 0; gg < 2; ++gg){
      const int rb = 32*gg + 16;
      float a = 0.f;
      #pragma unroll
      for(int k = 0; k < 16; ++k)
        a -= Ms[(rb+i)*64 + rb+k] * Pscr[gg*256 + k*16 + j];
      P[gg] = a;
    }
    #pragma unroll
    for(int gg = 0; gg < 2; ++gg){
      const int rb = 32*gg + 16, cb = 32*gg;
      Ms[(rb+i)*64 + cb + j] = P[gg];
    }
  }
  __syncthreads();
  {
    float* Pscr = (float*)(arena + 17408);
    const int i = tid >> 3;
    const int j4 = (tid & 7) * 4;
    float p[4] = {0.f,0.f,0.f,0.f};
    #pragma unroll 8
    for(int k = 0; k < 32; ++k){
      float b = Ms[(32+i)*64 + k];
      #pragma unroll
      for(int c = 0; c < 4; ++c) p[c] += b * Ms[k*64 + j4 + c];
    }
    #pragma unroll
    for(int c = 0; c < 4; ++c) Pscr[i*32 + j4 + c] = p[c];
    __syncthreads();
    float q2[4] = {0.f,0.f,0.f,0.f};
    #pragma unroll 8
    for(int k = 0; k < 32; ++k){
      float xc = Ms[(32+i)*64 + 32+k];
      #pragma unroll
      for(int c = 0; c < 4; ++c) q2[c] -= xc * Pscr[k*32 + j4 + c];
    }
    #pragma unroll
    for(int c = 0; c < 4; ++c) Ms[(32+i)*64 + j4 + c] = q2[c];
  }
  __syncthreads();

  // ---- phase 4: Tb = bf16(T); XT[d][m] = bf16(k[m][d]*wsc[m]) ----
  for(int e = tid; e < 4096; e += 256){
    int i = e >> 6, j = e & 63;
    Tb[i*72 + j] = f2bf(Ms[e]);
  }
  {
    int m = tid & 63, dc = (tid >> 6)*32;
    float sc = wsc[m];
    #pragma unroll
    for(int d8 = 0; d8 < 32; d8 += 8){
      u16x8 kv = *(const u16x8*)&kS[m*136 + dc + d8];
      #pragma unroll
      for(int e = 0; e < 8; ++e)
        XT[(dc + d8 + e)*72 + m] = f2bf(bf2f(kv[e]) * sc);
    }
  }
  __syncthreads();

  // ---- phase 5: w = T @ (k*beta*e^gc) via MFMA; store prefetched v ----
  {
    f32x4 wa[8] = {};
    #pragma unroll
    for(int ks = 0; ks < 2; ++ks){
      bf16x8 at = *(const bf16x8*)((const char*)Tb + (R0 + (lane & 15))*144 + ks*64 + (lane >> 4)*16);
      #pragma unroll
      for(int dt = 0; dt < 8; ++dt){
        bf16x8 bx = *(const bf16x8*)((const char*)XT + (dt*16 + (lane & 15))*144 + ks*64 + (lane >> 4)*16);
        wa[dt] = __builtin_amdgcn_mfma_f32_16x16x32_bf16(at, bx, wa[dt], 0, 0, 0);
      }
    }
    #pragma unroll
    for(int dt = 0; dt < 8; ++dt){
      int d = dt*16 + (lane & 15);
      #pragma unroll
      for(int r = 0; r < 4; ++r){
        int i = R0 + (lane >> 4)*4 + r;
        wb[uwbase + (size_t)i*128 + d] = f2bf(wa[dt][r]);
      }
    }
  }
  #pragma unroll
  for(int e2 = 0; e2 < 4; ++e2){
    int e = tid + e2*256;
    int r = e >> 4, c8 = (e & 15)*8;
    *(u16x8*)&vS[r*136 + c8] = pv[e2];
  }
  __syncthreads();

  // ---- phase 6: VT[c][m] = bf16(v[m][c]*beta[m]) ----
  {
    int m = tid & 63, dc = (tid >> 6)*32;
    float bsc = betas[m];
    #pragma unroll
    for(int d8 = 0; d8 < 32; d8 += 8){
      u16x8 vv = *(const u16x8*)&vS[m*136 + dc + d8];
      #pragma unroll
      for(int e = 0; e < 8; ++e)
        VT[(dc + d8 + e)*72 + m] = f2bf(bf2f(vv[e]) * bsc);
    }
  }
  __syncthreads();

  // ---- phase 7: u = T @ (v*beta) via MFMA ----
  {
    f32x4 ua[8] = {};
    #pragma unroll
    for(int ks = 0; ks < 2; ++ks){
      bf16x8 at = *(const bf16x8*)((const char*)Tb + (R0 + (lane & 15))*144 + ks*64 + (lane >> 4)*16);
      #pragma unroll
      for(int dt = 0; dt < 8; ++dt){
        bf16x8 bx = *(const bf16x8*)((const char*)VT + (dt*16 + (lane & 15))*144 + ks*64 + (lane >> 4)*16);
        ua[dt] = __builtin_amdgcn_mfma_f32_16x16x32_bf16(at, bx, ua[dt], 0, 0, 0);
      }
    }
    #pragma unroll
    for(int dt = 0; dt < 8; ++dt){
      int d = dt*16 + (lane & 15);
      #pragma unroll
      for(int r = 0; r < 4; ++r){
        int i = R0 + (lane >> 4)*4 + r;
        ub[uwbase + (size_t)i*128 + d] = f2bf(ua[dt][r]);
      }
    }
  }
}

// ---------------------------------------------------------------- phase B (per batch): MFMA chunk scan, c-split x8
// Operand fetch software-pipelined one chunk ahead (register double-buffer):
// chunk n's regs are loaded during chunk n-1's MFMA phases; copy next->cur at
// iter end with constant indices (stays in VGPRs). Math order unchanged.
#define PB_LOAD(n_, W_, Q_, A_, K_, U_, G_) { \
    const int ls0 = (n_) * CHUNK; \
    const u16* lwrow = wb + uwb + (size_t)(n_)*8192; \
    const u16* larow = attnb + atb + (size_t)(n_)*4096; \
    _Pragma("unroll") \
    for(int ks = 0; ks < 4; ++ks){ \
      W_[ks] = *(const bf16x8*)&lwrow[(size_t)(i0w+cL)*128 + ks*32 + qq*8]; \
      Q_[ks] = *(const bf16x8*)&qbase[(size_t)(ls0 + i0w + cL)*128 + ks*32 + qq*8]; \
    } \
    _Pragma("unroll") \
    for(int ks = 0; ks < 2; ++ks) \
      A_[ks] = *(const bf16x8*)&larow[(size_t)(i0w+cL)*64 + ks*32 + qq*8]; \
    if((n_) < NCH-1){ \
      _Pragma("unroll") \
      for(int ks = 0; ks < 2; ++ks) \
        _Pragma("unroll") \
        for(int dt = 0; dt < 2; ++dt) \
          K_[ks*2+dt] = *(const bf16x8*)&kTb[(size_t)(d0w + dt*16 + cL)*SEQ + ls0 + ks*32 + qq*8]; \
    } \
    { \
      const u16* lurow = ub + uwb + (size_t)(n_)*8192; \
      U_ = *(const u16x4*)&lurow[(size_t)(tid>>2)*128 + cbb + (tid&3)*4]; \
    } \
    G_ = gcp[ls0 + lane]; \
  }

__global__ __launch_bounds__(256) void phaseB(const u16* __restrict__ qb, const u16* __restrict__ kbT,
      const u16* __restrict__ ub, const u16* __restrict__ wb, const u16* __restrict__ attnb,
      const float* __restrict__ gcb, u16* __restrict__ core){
  __shared__ __align__(16) u16 STbf[16][136];   // S^T: [16 c][128 d] + pad
  __shared__ __align__(16) u16 vnT[16][72];     // vn^T (for attn@vn)
  __shared__ __align__(16) u16 vnT2[16][72];    // (vn*e^{gl-gc})^T (for state update)
  __shared__ __align__(16) u16 uS[64][24];
  __shared__ float gcs[64];
  __shared__ float egm[64];
  const int f = blockIdx.x;              // 0..255
  const int xcd = f & 7, idx = f >> 3;   // idx 0..31
  const int h = xcd*4 + (idx >> 3);      // 0..31 (4 heads per XCD)
  const int split = idx & 7;             // 0..7
  const int cbb = split*16;              // state col base
  const int hk = h >> 1;
  const int tid = threadIdx.x;
  const int lane = tid & 63, wave = tid >> 6;
  const int cL = lane & 15, qq = lane >> 4;
  const int i0w = wave*16, d0w = wave*32;
  const float* gcp = gcb + (size_t)h*SEQ;
  const u16* qbase = qb + (size_t)hk*SEQ*DK;
  const u16* kTb   = kbT + (size_t)hk*DK*SEQ;
  const size_t uwb = (size_t)h*NCH*64*128;
  const size_t atb = (size_t)h*NCH*64*64;
  u16* corep = core + (size_t)h*SEQ*DV;
  f32x4 accS[2] = {};
  // prefetch chunk 0 operands
  bf16x8 cw[4], cq[4], ca[2], ck[4];
  u16x4 cu; float cg;
  PB_LOAD(0, cw, cq, ca, ck, cu, cg);
  for(int n = 0; n < NCH; ++n){
    const int s0 = n * CHUNK;
    // ---- top: STbf from accS; uS from prefetched regs; gc/egm from cg ----
    #pragma unroll
    for(int dt = 0; dt < 2; ++dt){
      u16x4 p;
      #pragma unroll
      for(int r = 0; r < 4; ++r) p[r] = f2bf(accS[dt][r]);
      *(u16x4*)&STbf[cL][d0w + dt*16 + qq*4] = p;
    }
    *(u16x4*)&uS[tid >> 2][(tid & 3)*4] = cu;
    if(wave == 0){
      gcs[lane] = cg;
      float gl = __shfl(cg, 63, 64);
      egm[lane] = __expf(gl - cg);
    }
    __syncthreads();
    // ---- issue next chunk's prefetch (latency hides under M1+tail MFMA) ----
    bf16x8 nw_[4], nq_[4], na_[2], nk_[4];
    u16x4 nu; float ng;
    if(n+1 < NCH) PB_LOAD(n+1, nw_, nq_, na_, nk_, nu, ng);
    // ---- M1: vn = u - w@S; write vnT and vnT2 ----
    bf16x8 bS[4];
    f32x4 accvn = {};
    #pragma unroll
    for(int ks = 0; ks < 4; ++ks){
      bS[ks] = *(const bf16x8*)&STbf[cL][ks*32 + qq*8];
      accvn = __builtin_amdgcn_mfma_f32_16x16x32_bf16(cw[ks], bS[ks], accvn, 0, 0, 0);
    }
    {
      u16x4 p, p2;
      #pragma unroll
      for(int r = 0; r < 4; ++r){
        int i = i0w + qq*4 + r;
        float vnv = bf2f(uS[i][cL]) - accvn[r];
        p[r]  = f2bf(vnv);
        p2[r] = f2bf(vnv * egm[i]);
      }
      *(u16x4*)&vnT [cL][i0w + qq*4] = p;
      *(u16x4*)&vnT2[cL][i0w + qq*4] = p2;
    }
    __syncthreads();
    // ---- tail: M2 o = q@S * e^gc; M3 o += attn@vn; store core; M4 state update ----
    f32x4 accO = {};
    #pragma unroll
    for(int ks = 0; ks < 4; ++ks)
      accO = __builtin_amdgcn_mfma_f32_16x16x32_bf16(cq[ks], bS[ks], accO, 0, 0, 0);
    #pragma unroll
    for(int r = 0; r < 4; ++r)
      accO[r] *= __expf(gcs[i0w + qq*4 + r]);
    #pragma unroll
    for(int ks = 0; ks < 2; ++ks){
      bf16x8 bV = *(const bf16x8*)&vnT[cL][ks*32 + qq*8];
      accO = __builtin_amdgcn_mfma_f32_16x16x32_bf16(ca[ks], bV, accO, 0, 0, 0);
    }
    #pragma unroll
    for(int r = 0; r < 4; ++r)
      corep[(size_t)(s0 + i0w + qq*4 + r)*DV + cbb + cL] = f2bf(accO[r]);
    if(n < NCH-1){
      float egl = __expf(gcs[63]);
      #pragma unroll
      for(int dt = 0; dt < 2; ++dt)
        accS[dt] *= egl;
      #pragma unroll
      for(int ks = 0; ks < 2; ++ks){
        bf16x8 bV2 = *(const bf16x8*)&vnT2[cL][ks*32 + qq*8];
        #pragma unroll
        for(int dt = 0; dt < 2; ++dt)
          accS[dt] = __builtin_amdgcn_mfma_f32_16x16x32_bf16(ck[ks*2+dt], bV2, accS[dt], 0, 0, 0);
      }
    }
    __syncthreads();
    // ---- rotate prefetched registers (constant indices -> stays in VGPRs) ----
    if(n+1 < NCH){
      #pragma unroll
      for(int i = 0; i < 4; ++i){ cw[i] = nw_[i]; cq[i] = nq_[i]; ck[i] = nk_[i]; }
      ca[0] = na_[0]; ca[1] = na_[1];
      cu = nu; cg = ng;
    }
  }
}

// ---------------------------------------------------------------- gated RMSNorm * silu(z) -> bf16 (per batch)
// 8 rows per 256-thread block (2 rows concurrently x 4 iters): 8x fewer blocks.
__global__ __launch_bounds__(256) void norm_gate(const u16* __restrict__ core, const u16* __restrict__ z_bf,
      const float* __restrict__ nw, u16* __restrict__ core2){
  const int h = blockIdx.y;
  const int s0 = blockIdx.x * 8;
  const int t = threadIdx.x & 127;      // elem within row
  const int rh = threadIdx.x >> 7;      // row pair half: 0/1
  __shared__ float red[8][2];
  const float nwv = nw[t];
  #pragma unroll
  for(int i = 0; i < 8; i += 2){
    const int s = s0 + i + rh;
    float x = bf2f(core[((size_t)h*SEQ + s)*DV + t]);
    float sq = x*x;
    #pragma unroll
    for(int off = 1; off < 64; off <<= 1) sq += __shfl_xor(sq, off, 64);
    if((t & 63) == 0) red[i+rh][t >> 6] = sq;
    __syncthreads();
    float var = (red[i+rh][0] + red[i+rh][1]) * (1.f/128.f);
    float y = x * rsqrtf(var + 1e-6f) * nwv;
    float zv = bf2f(z_bf[(size_t)s*VAL_DIM + h*DV + t]);
    y *= zv / (1.f + __expf(-zv));
    core2[(size_t)s*VAL_DIM + h*DV + t] = f2bf(y);
  }
}

// ---------------------------------------------------------------- launch
extern "C" void kernel_launch(void* const* d_in, const int* in_sizes, int n_in,
                              void* d_out, int out_size, void* d_ws, size_t ws_size,
                              hipStream_t stream){
  (void)in_sizes; (void)n_in; (void)out_size;
  const float* hs     = (const float*)d_in[0];
  const float* W_qkv  = (const float*)d_in[1];
  const float* conv_w = (const float*)d_in[2];
  const float* W_z    = (const float*)d_in[3];
  const float* W_b    = (const float*)d_in[4];
  const float* W_a    = (const float*)d_in[5];
  const float* dt_b   = (const float*)d_in[6];
  const float* A_log  = (const float*)d_in[7];
  const float* norm_w = (const float*)d_in[8];
  const float* W_out  = (const float*)d_in[9];
  float* out = (float*)d_out;

  const size_t MB = 1024ULL*1024ULL;
  if (ws_size < 160*MB) return;   // diagnostic: clean absmax-fail if ws too small
  const bool big  = (ws_size >= 208*MB);   // persistent weight transposes
  const bool big2 = (ws_size >= 224*MB);   // + persistent per-batch hs_bf (single cast)

  char* ws = (char*)d_ws;
  // ws map: [0,64M)=B  [64,96M)=C  [96,128M)=E  [128,160M)=D
  //         [160,208M)=persistent weights (big)  [208,224M)=hs_bf (big2)
  u16*   mixed  = (u16*)ws;                      // B: gemm1 -> conv
  u16*   attnB  = (u16*)ws;                      // B[0,16M): phaseA -> phaseB
  u16*   core_b = (u16*)(ws + 16*MB);            // B[16,48M): phaseB -> norm
  float* betab  = (float*)(ws + 48*MB);          // B[48M..): proj -> phaseA
  float* gbuf   = (float*)(ws + 48*MB + 512*1024);
  float* gcbuf  = (float*)(ws + 49*MB);          // phaseA -> phaseB
  u16*   WoutT  = (u16*)ws;                      // B[0,16M): after norm_b1
  u16*   qb     = (u16*)(ws + 64*MB);            // C[0,16M)
  u16*   kb     = (u16*)(ws + 80*MB);            // C[16,32M)
  u16*   zb     = (u16*)(ws + 64*MB);            // C: gemm2 -> norm (q,k dead after phaseB/transpose_k)
  u16*   core2  = (u16*)(ws + 96*MB);            // E+D: 64M contiguous [8192][4096]
  u16*   vb     = (u16*)(ws + 128*MB);           // D: conv -> phaseA
  u16*   kbT    = (u16*)(ws + 144*MB);           // D[16,32M): transpose_k -> phaseB (v dead)
  // weight homes: persistent (big) or per-batch scratch
  u16*   WqkvT  = big ? (u16*)(ws + 160*MB) : (u16*)d_out;           // 32MB
  u16*   WzT    = big ? (u16*)(ws + 192*MB) : (u16*)(ws + 128*MB);   // 16MB
  // d_out scratch (64M): (non-big) WqkvT [0,32M) + hs_bf1 [32,48.7M) during gemm1;
  // u [0,32M) + w [32,64M) phaseA->phaseB; hs_bf2 [0,16.7M) for gemm2 (after phaseB).
  u16*   hs_bf1 = big2 ? (u16*)(ws + 208*MB) : (u16*)((char*)d_out + 32*MB);
  u16*   u_d    = (u16*)d_out;
  u16*   w_d    = (u16*)((char*)d_out + 32*MB);
  u16*   hs_bf2 = big2 ? (u16*)(ws + 208*MB) : (u16*)d_out;   // big2: same persistent buffer

  if(big){
    transpose_cast<<<dim3(CONV_DIM/32, HID/32), 256, 0, stream>>>(W_qkv, WqkvT, HID, CONV_DIM);
    transpose_cast<<<dim3(VAL_DIM/32,  HID/32), 256, 0, stream>>>(W_z,   WzT,   HID, VAL_DIM);
  }
  for(int b = 0; b < BB; ++b){
    const float* hs_b = hs + (size_t)b*SEQ*HID;
    u16* core2_b = core2 + (size_t)b*SEQ*VAL_DIM;
    cast_bf<<<1024, 256, 0, stream>>>(hs_b, hs_bf1, SEQ*HID/8);
    if(!big) transpose_cast<<<dim3(CONV_DIM/32, HID/32), 256, 0, stream>>>(W_qkv, WqkvT, HID, CONV_DIM);
    gemm256<u16><<<dim3(CONV_DIM/256, SEQ/256), 512, 0, stream>>>(hs_bf1, WqkvT, mixed, SEQ, CONV_DIM, HID);
    conv_qkv<<<dim3(64, SEQ/CTS), 128, 0, stream>>>(mixed, conv_w, qb, kb, vb);
    proj_bg<<<SEQ/4, 256, 0, stream>>>(hs_b, W_b, W_a, dt_b, A_log, betab, gbuf);
    phaseA<<<dim3(NCH, HV), 256, 0, stream>>>(qb, kb, vb, betab, gbuf, gcbuf, u_d, w_d, attnB);
    transpose_k<<<dim3(SEQ/32, DK/32, HK), 256, 0, stream>>>(kb, kbT);   // after phaseA (vb dead)
    phaseB<<<256, 256, 0, stream>>>(qb, kbT, u_d, w_d, attnB, gcbuf, core_b);
    if(!big2) cast_bf<<<1024, 256, 0, stream>>>(hs_b, hs_bf2, SEQ*HID/8);
    if(!big) transpose_cast<<<dim3(VAL_DIM/32, HID/32), 256, 0, stream>>>(W_z, WzT, HID, VAL_DIM);
    gemm256<u16><<<dim3(VAL_DIM/256, SEQ/256), 512, 0, stream>>>(hs_bf2, WzT, zb, SEQ, VAL_DIM, HID);
    norm_gate<<<dim3(SEQ/8, HV), 256, 0, stream>>>(core_b, zb, norm_w, core2_b);
  }
  transpose_cast<<<dim3(HID/32, VAL_DIM/32), 256, 0, stream>>>(W_out, WoutT, VAL_DIM, HID);
  gemm256<float><<<dim3(HID/256, BS/256), 512, 0, stream>>>(core2, WoutT, out, BS, HID, VAL_DIM);
}

// Round 21
// 1319.111 us; speedup vs baseline: 1.1847x; 1.0018x over previous
//
#include <hip/hip_runtime.h>
#include <math.h>

#define BB 2
#define SEQ 4096
#define HID 2048
#define HV 32
#define HK 16
#define DK 128
#define DV 128
#define CHUNK 64
#define NCH 64
#define KEY_DIM 2048
#define VAL_DIM 4096
#define CONV_DIM 8192
#define BS 8192   // BB*SEQ
#define CTS 8     // conv s-tile

typedef unsigned short u16;
typedef __attribute__((ext_vector_type(8))) __bf16 bf16x8;
typedef __attribute__((ext_vector_type(4))) float f32x4;
typedef __attribute__((ext_vector_type(4))) unsigned short u16x4;
typedef __attribute__((ext_vector_type(8))) unsigned short u16x8;

__device__ __forceinline__ float bf2f(u16 x){
  return (float)__builtin_bit_cast(__bf16, x);
}
__device__ __forceinline__ u16 f2bf(float f){
  return __builtin_bit_cast(u16, (__bf16)f);
}

// async global->LDS, 16B per lane; LDS dest is wave-uniform base + lane*16
__device__ __forceinline__ void gl_lds16(const u16* g, u16* l){
  __builtin_amdgcn_global_load_lds((const __attribute__((address_space(1))) void*)g,
                                   (__attribute__((address_space(3))) void*)l, 16, 0, 0);
}

// ---------------------------------------------------------------- f32 -> bf16 cast (vectorized, grid-stride)
__global__ __launch_bounds__(256) void cast_bf(const float* __restrict__ in, u16* __restrict__ out, int n8){
  int i = blockIdx.x*256 + threadIdx.x;
  const int stride = gridDim.x*256;
  for(; i < n8; i += stride){
    float4 a = ((const float4*)in)[(size_t)i*2];
    float4 b = ((const float4*)in)[(size_t)i*2+1];
    u16x8 t;
    t[0]=f2bf(a.x); t[1]=f2bf(a.y); t[2]=f2bf(a.z); t[3]=f2bf(a.w);
    t[4]=f2bf(b.x); t[5]=f2bf(b.y); t[6]=f2bf(b.z); t[7]=f2bf(b.w);
    ((u16x8*)out)[i] = t;
  }
}

// ---------------------------------------------------------------- weight transpose: src [R,C] f32 -> dst [C,R] bf16
__global__ __launch_bounds__(256) void transpose_cast(const float* __restrict__ src, u16* __restrict__ dst, int R, int C){
  __shared__ float tile[32][33];
  int c0 = blockIdx.x*32, r0 = blockIdx.y*32;
  int tx = threadIdx.x & 31, ty = threadIdx.x >> 5;   // ty 0..7
  for(int i = ty; i < 32; i += 8) tile[i][tx] = src[(size_t)(r0+i)*C + c0 + tx];
  __syncthreads();
  for(int i = ty; i < 32; i += 8) dst[(size_t)(c0+i)*R + r0 + tx] = f2bf(tile[tx][i]);
}

// ---------------------------------------------------------------- k transpose (per batch): kb [HK][SEQ][DK] -> kbT [HK][DK][SEQ]
__global__ __launch_bounds__(256) void transpose_k(const u16* __restrict__ kb, u16* __restrict__ kbT){
  __shared__ u16 tile[32][33];
  const int h = blockIdx.z, d0 = blockIdx.y*32, s0 = blockIdx.x*32;
  const int tx = threadIdx.x & 31, ty = threadIdx.x >> 5;
  const u16* src = kb + (size_t)h*SEQ*DK;
  for(int i = ty; i < 32; i += 8) tile[i][tx] = src[(size_t)(s0+i)*DK + d0 + tx];
  __syncthreads();
  u16* dst = kbT + (size_t)h*DK*SEQ;
  for(int i = ty; i < 32; i += 8) dst[(size_t)(d0+i)*SEQ + s0 + tx] = tile[tx][i];
}

// ---------------------------------------------------------------- GEMM bf16, 256x256, BK=64, 8 waves, 2-buf counted-vmcnt pipeline
__device__ __forceinline__ void store_c(float* C, size_t idx, float v){ C[idx] = v; }
__device__ __forceinline__ void store_c(u16*   C, size_t idx, float v){ C[idx] = f2bf(v); }

__device__ __forceinline__ void stage256(const u16* __restrict__ A, const u16* __restrict__ Bt,
                                         size_t bm, size_t bn, int K, int k0,
                                         u16* Ab, u16* Bb, int wave, int lrow, int lg){
  const int g = lg ^ lrow;          // row&7 == lrow for all staged rows
  #pragma unroll
  for(int r = 0; r < 4; ++r){
    const int grow = r*64 + wave*8 + lrow;
    const int dst = (r>>1)*8192 + ((r&1)*64 + wave*8)*64;
    gl_lds16(&A [(bm + grow)*K + k0 + g*8], &Ab[dst]);
    gl_lds16(&Bt[(bn + grow)*K + k0 + g*8], &Bb[dst]);
  }
}

template<typename CT>
__global__ __launch_bounds__(512) void gemm256(const u16* __restrict__ A, const u16* __restrict__ Bt,
                                               CT* __restrict__ C, int M, int N, int K){
  (void)M;
  __shared__ u16 As[2][2][8192];   // [buf][half][128x64], 64KB
  __shared__ u16 Bs[2][2][8192];   // 64KB
  const int tid  = threadIdx.x;
  const int lane = tid & 63;
  const int wave = tid >> 6;       // 0..7
  const int lrow = lane >> 3, lg = lane & 7;
  // bijective XCD-chunked swizzle (all grids have nwg % 8 == 0)
  const int nwg = gridDim.x * gridDim.y;
  const int old = blockIdx.y * gridDim.x + blockIdx.x;
  const int nid = (old & 7) * (nwg >> 3) + (old >> 3);
  const int bx = nid % gridDim.x, by = nid / gridDim.x;
  const size_t bm = (size_t)by * 256;
  const size_t bn = (size_t)bx * 256;
  const int wm = (wave >> 2) * 128;     // 0 / 128
  const int wn = (wave & 3) * 64;       // 0 / 64 / 128 / 192
  const int ah = wave >> 2;             // this wave's A half
  const int bh = (wave & 3) >> 1;       // this wave's B half
  const int lwn = wn & 64;              // B row base within half
  const int cL15 = lane & 15, qq = lane >> 4;
  f32x4 acc[8][4] = {};
  const int nk = K >> 6;
  stage256(A, Bt, bm, bn, K, 0, &As[0][0][0], &Bs[0][0][0], wave, lrow, lg);
  for(int kt = 0; kt < nk; ++kt){
    if(kt+1 < nk){
      stage256(A, Bt, bm, bn, K, (kt+1) << 6, &As[(kt+1)&1][0][0], &Bs[(kt+1)&1][0][0], wave, lrow, lg);
      asm volatile("s_waitcnt vmcnt(8)" ::: "memory");   // tile kt landed; kt+1 in flight
    } else {
      asm volatile("s_waitcnt vmcnt(0)" ::: "memory");   // last tile: full drain
    }
    __builtin_amdgcn_s_barrier();
    __builtin_amdgcn_sched_barrier(0);
    const u16* Ah = As[kt&1][ah];
    const u16* Bh = Bs[kt&1][bh];
    __builtin_amdgcn_s_setprio(1);
    #pragma unroll
    for(int kk = 0; kk < 2; ++kk){
      bf16x8 af[8], bfr[4];
      #pragma unroll
      for(int mi = 0; mi < 8; ++mi){
        int lr = mi*16 + cL15;
        int cb = (kk*64 + qq*16) ^ ((lr & 7) << 4);
        af[mi] = *(const bf16x8*)((const char*)Ah + lr*128 + cb);
      }
      #pragma unroll
      for(int ni = 0; ni < 4; ++ni){
        int lr = lwn + ni*16 + cL15;
        int cb = (kk*64 + qq*16) ^ ((lr & 7) << 4);
        bfr[ni] = *(const bf16x8*)((const char*)Bh + lr*128 + cb);
      }
      #pragma unroll
      for(int mi = 0; mi < 8; ++mi)
        #pragma unroll
        for(int ni = 0; ni < 4; ++ni)
          acc[mi][ni] = __builtin_amdgcn_mfma_f32_16x16x32_bf16(af[mi], bfr[ni], acc[mi][ni], 0, 0, 0);
    }
    __builtin_amdgcn_s_setprio(0);
    __builtin_amdgcn_s_barrier();        // all waves done reading buf kt&1
    __builtin_amdgcn_sched_barrier(0);
  }
  const int c0 = (int)bn + wn + cL15;
  const int r0 = (int)bm + wm + qq*4;
  #pragma unroll
  for(int mi = 0; mi < 8; ++mi)
    #pragma unroll
    for(int ni = 0; ni < 4; ++ni)
      #pragma unroll
      for(int rr = 0; rr < 4; ++rr)
        store_c(C, (size_t)(r0 + mi*16 + rr)*N + (c0 + ni*16), acc[mi][ni][rr]);
}

// ---------------------------------------------------------------- beta/g projections (per batch), fp32 exact
__global__ __launch_bounds__(256) void proj_bg(const float* __restrict__ hs, const float* __restrict__ Wb,
      const float* __restrict__ Wa, const float* __restrict__ dtb, const float* __restrict__ A_log,
      float* __restrict__ betab, float* __restrict__ gbuf){
  __shared__ float h4[4][HID];          // 32KB: 4 rows of hs
  __shared__ float part[4][64][4];
  const int r0 = blockIdx.x * 4;
  const int tid = threadIdx.x;
  for(int i = tid; i < 4*HID/4; i += 256)
    ((float4*)&h4[0][0])[i] = ((const float4*)&hs[(size_t)r0*HID])[i];
  __syncthreads();
  const int o = tid & 63, pp = tid >> 6;
  const float* W = (o < 32) ? (Wb + o) : (Wa + (o - 32));
  float a0=0.f,a1=0.f,a2=0.f,a3=0.f;
  const int kbeg = pp*512;
  for(int kk = kbeg; kk < kbeg+512; ++kk){
    float wv = W[(size_t)kk*32];
    a0 += wv*h4[0][kk]; a1 += wv*h4[1][kk]; a2 += wv*h4[2][kk]; a3 += wv*h4[3][kk];
  }
  part[0][o][pp]=a0; part[1][o][pp]=a1; part[2][o][pp]=a2; part[3][o][pp]=a3;
  __syncthreads();
  {
    const int row = tid >> 6, oo = tid & 63;
    float sdot = part[row][oo][0]+part[row][oo][1]+part[row][oo][2]+part[row][oo][3];
    const int s = r0 + row;
    if(oo < 32){
      betab[(size_t)oo*SEQ + s] = 1.f/(1.f + __expf(-sdot));
    } else {
      const int hh = oo - 32;
      float x = sdot + dtb[hh];
      float sp = (x > 20.f) ? x : log1pf(__expf(x));
      gbuf[(size_t)hh*SEQ + s] = -__expf(A_log[hh]) * sp;
    }
  }
}

// ---------------------------------------------------------------- conv(4) + SiLU + split + l2norm -> bf16 (per batch)
__global__ __launch_bounds__(128) void conv_qkv(const u16* __restrict__ mixed, const float* __restrict__ conv_w,
      u16* __restrict__ qb, u16* __restrict__ kb, u16* __restrict__ vb){
  const int slot = blockIdx.x;          // 0..63  (16 q heads, 16 k heads, 32 v heads)
  const int s0 = blockIdx.y * CTS;      // 0..4095 step CTS
  const int t = threadIdx.x;            // 0..127
  const int c = slot*128 + t;
  __shared__ float red[CTS][2];
  float m[CTS+3];
  #pragma unroll
  for(int j = 0; j < CTS+3; ++j){
    int ss = s0 - 3 + j;
    m[j] = (ss >= 0) ? bf2f(mixed[(size_t)ss*CONV_DIM + c]) : 0.f;
  }
  const float w0 = conv_w[c*4+0], w1 = conv_w[c*4+1], w2 = conv_w[c*4+2], w3 = conv_w[c*4+3];
  float acc[CTS];
  #pragma unroll
  for(int i = 0; i < CTS; ++i){
    float a = 0.f;
    a += w0*m[i]; a += w1*m[i+1]; a += w2*m[i+2]; a += w3*m[i+3];
    acc[i] = a / (1.f + __expf(-a));    // SiLU
  }
  if(slot < 32){
    #pragma unroll
    for(int i = 0; i < CTS; ++i){
      float sq = acc[i]*acc[i];
      #pragma unroll
      for(int off = 1; off < 64; off <<= 1) sq += __shfl_xor(sq, off, 64);
      if((t & 63) == 0) red[i][t >> 6] = sq;
    }
    __syncthreads();
    #pragma unroll
    for(int i = 0; i < CTS; ++i){
      const int s = s0 + i;
      float rn = rsqrtf(red[i][0] + red[i][1] + 1e-6f);
      if(slot < 16)
        qb[((size_t)slot*SEQ + s)*DK + t] = f2bf(acc[i] * rn * 0.08838834764831845f); // * DK^-0.5
      else
        kb[((size_t)(slot-16)*SEQ + s)*DK + t] = f2bf(acc[i] * rn);
    }
  } else {
    #pragma unroll
    for(int i = 0; i < CTS; ++i)
      vb[((size_t)(slot-32)*SEQ + s0+i)*DV + t] = f2bf(acc[i]);
  }
}

// ---------------------------------------------------------------- phase A (per batch), MFMA version
__global__ __launch_bounds__(256) void phaseA(const u16* __restrict__ qb, const u16* __restrict__ kb,
      const u16* __restrict__ vb, const float* __restrict__ betab, const float* __restrict__ gb,
      float* __restrict__ gcb, u16* __restrict__ ub, u16* __restrict__ wb, u16* __restrict__ attnb){
  __shared__ __align__(16) char arena[63232];
  u16*   kS  = (u16*)(arena);
  u16*   qS  = (u16*)(arena + 17408);
  u16*   XT  = (u16*)(arena + 17408);
  u16*   VT  = (u16*)(arena + 17408);
  float* Ms  = (float*)(arena + 35840);
  u16*   vS  = (u16*)(arena + 35840);
  u16*   Tb  = (u16*)(arena + 53248);
  float* gcs   = (float*)(arena + 62464);
  float* betas = gcs + 64;
  float* wsc   = gcs + 128;

  const int n = blockIdx.x, h = blockIdx.y;
  const int hk = h >> 1;
  const int s0 = n * CHUNK;
  const int tid = threadIdx.x;
  const int lane = tid & 63;
  const int wave = tid >> 6;
  const int R0 = wave * 16;
  const size_t hS = (size_t)h*SEQ;
  const u16* kbase = kb + ((size_t)hk*SEQ + s0)*DK;
  const u16* qbase = qb + ((size_t)hk*SEQ + s0)*DK;
  const u16* vbase = vb + ((size_t)h*SEQ + s0)*DV;
  const size_t atbase = ((size_t)h*NCH + n)*64*64;
  const size_t uwbase = ((size_t)h*NCH + n)*64*128;

  // ---- phase 1: stage k,q; prefetch v into regs (used phase 5); gc scan ----
  u16x8 pv[4];
  #pragma unroll
  for(int e2 = 0; e2 < 4; ++e2){
    int e = tid + e2*256;
    int r = e >> 4, c8 = (e & 15)*8;
    pv[e2] = *(const u16x8*)&vbase[(size_t)r*128 + c8];
  }
  for(int e = tid; e < 1024; e += 256){
    int r = e >> 4, c8 = (e & 15)*8;
    *(u16x8*)&kS[r*136 + c8] = *(const u16x8*)&kbase[(size_t)r*128 + c8];
    *(u16x8*)&qS[r*136 + c8] = *(const u16x8*)&qbase[(size_t)r*128 + c8];
  }
  if(wave == 0){
    float v = gb[hS + s0 + lane];
    #pragma unroll
    for(int off = 1; off < 64; off <<= 1){
      float t = __shfl(v, (lane >= off) ? (lane - off) : lane, 64);
      if(lane >= off) v += t;
    }
    gcs[lane] = v;
    gcb[hS + s0 + lane] = v;
    float b = betab[hS + s0 + lane];
    betas[lane] = b;
    wsc[lane] = b * __expf(v);
  }
  __syncthreads();

  // ---- phase 2: S1 = k.k^T, S2 = q.k^T via MFMA; write Ms (f32) + attn (bf16) ----
  {
    f32x4 a1[4] = {}, a2[4] = {};
    #pragma unroll
    for(int ks = 0; ks < 4; ++ks){
      const int ab = (R0 + (lane & 15))*272 + ks*64 + (lane >> 4)*16;
      bf16x8 afk = *(const bf16x8*)((const char*)kS + ab);
      bf16x8 afq = *(const bf16x8*)((const char*)qS + ab);
      #pragma unroll
      for(int jt = 0; jt < 4; ++jt){
        const int bb = (jt*16 + (lane & 15))*272 + ks*64 + (lane >> 4)*16;
        bf16x8 bf = *(const bf16x8*)((const char*)kS + bb);
        a1[jt] = __builtin_amdgcn_mfma_f32_16x16x32_bf16(afk, bf, a1[jt], 0, 0, 0);
        a2[jt] = __builtin_amdgcn_mfma_f32_16x16x32_bf16(afq, bf, a2[jt], 0, 0, 0);
      }
    }
    #pragma unroll
    for(int jt = 0; jt < 4; ++jt){
      int j = jt*16 + (lane & 15);
      float gj = gcs[j];
      #pragma unroll
      for(int r = 0; r < 4; ++r){
        int i = R0 + (lane >> 4)*4 + r;
        float gi = gcs[i];
        float dec = (j <= i) ? __expf(gi - gj) : 0.f;
        Ms[i*64 + j] = (j < i) ? betas[i]*a1[jt][r]*dec : 0.f;
        attnb[atbase + (size_t)i*64 + j] = f2bf(a2[jt][r]*dec);
      }
    }
  }
  __syncthreads();

  // ---- phase 3: blocked inversion, f32 exact: Ms -> X = inv(I+M) ----
  {
    const int b0 = R0;
    const int j  = lane & 15;
    float x[16];
    #pragma unroll
    for(int i = 0; i < 16; ++i){
      float acc2 = (i == j) ? 1.f : 0.f;
      #pragma unroll
      for(int m = 0; m < 16; ++m){
        if(m < i) acc2 -= Ms[(b0+i)*64 + (b0+m)] * x[m];
      }
      x[i] = acc2;
    }
    if(lane < 16){
      #pragma unroll
      for(int i = 0; i < 16; ++i) Ms[(b0+i)*64 + (b0+j)] = x[i];
    }
  }
  __syncthreads();
  {
    float* Pscr = (float*)(arena + 17408);
    const int i = (tid >> 4) & 15, j = tid & 15;
    float P[2];
    #pragma unroll
    for(int gg = 0; gg < 2; ++gg){
      const int rb = 32*gg + 16, cb = 32*gg;
      float a = 0.f;
      #pragma unroll
      for(int k = 0; k < 16; ++k)
        a += Ms[(rb+i)*64 + cb+k] * Ms[(cb+k)*64 + cb+j];
      Pscr[gg*256 + i*16 + j] = a;
    }
    __syncthreads();
    #pragma unroll
    for(int gg = 0; gg < 2; ++gg){
      const int rb = 32*gg + 16;
      float a = 0.f;
      #pragma unroll
      for(int k = 0; k < 16; ++k)
        a -= Ms[(rb+i)*64 + rb+k] * Pscr[gg*256 + k*16 + j];
      P[gg] = a;
    }
    #pragma unroll
    for(int gg = 0; gg < 2; ++gg){
      const int rb = 32*gg + 16, cb = 32*gg;
      Ms[(rb+i)*64 + cb + j] = P[gg];
    }
  }
  __syncthreads();
  {
    float* Pscr = (float*)(arena + 17408);
    const int i = tid >> 3;
    const int j4 = (tid & 7) * 4;
    float p[4] = {0.f,0.f,0.f,0.f};
    #pragma unroll 8
    for(int k = 0; k < 32; ++k){
      float b = Ms[(32+i)*64 + k];
      #pragma unroll
      for(int c = 0; c < 4; ++c) p[c] += b * Ms[k*64 + j4 + c];
    }
    #pragma unroll
    for(int c = 0; c < 4; ++c) Pscr[i*32 + j4 + c] = p[c];
    __syncthreads();
    float q2[4] = {0.f,0.f,0.f,0.f};
    #pragma unroll 8
    for(int k = 0; k < 32; ++k){
      float xc = Ms[(32+i)*64 + 32+k];
      #pragma unroll
      for(int c = 0; c < 4; ++c) q2[c] -= xc * Pscr[k*32 + j4 + c];
    }
    #pragma unroll
    for(int c = 0; c < 4; ++c) Ms[(32+i)*64 + j4 + c] = q2[c];
  }
  __syncthreads();

  // ---- phase 4: Tb = bf16(T); XT[d][m] = bf16(k[m][d]*wsc[m]) ----
  for(int e = tid; e < 4096; e += 256){
    int i = e >> 6, j = e & 63;
    Tb[i*72 + j] = f2bf(Ms[e]);
  }
  {
    int m = tid & 63, dc = (tid >> 6)*32;
    float sc = wsc[m];
    #pragma unroll
    for(int d8 = 0; d8 < 32; d8 += 8){
      u16x8 kv = *(const u16x8*)&kS[m*136 + dc + d8];
      #pragma unroll
      for(int e = 0; e < 8; ++e)
        XT[(dc + d8 + e)*72 + m] = f2bf(bf2f(kv[e]) * sc);
    }
  }
  __syncthreads();

  // ---- phase 5: w = T @ (k*beta*e^gc) via MFMA; store prefetched v ----
  {
    f32x4 wa[8] = {};
    #pragma unroll
    for(int ks = 0; ks < 2; ++ks){
      bf16x8 at = *(const bf16x8*)((const char*)Tb + (R0 + (lane & 15))*144 + ks*64 + (lane >> 4)*16);
      #pragma unroll
      for(int dt = 0; dt < 8; ++dt){
        bf16x8 bx = *(const bf16x8*)((const char*)XT + (dt*16 + (lane & 15))*144 + ks*64 + (lane >> 4)*16);
        wa[dt] = __builtin_amdgcn_mfma_f32_16x16x32_bf16(at, bx, wa[dt], 0, 0, 0);
      }
    }
    #pragma unroll
    for(int dt = 0; dt < 8; ++dt){
      int d = dt*16 + (lane & 15);
      #pragma unroll
      for(int r = 0; r < 4; ++r){
        int i = R0 + (lane >> 4)*4 + r;
        wb[uwbase + (size_t)i*128 + d] = f2bf(wa[dt][r]);
      }
    }
  }
  #pragma unroll
  for(int e2 = 0; e2 < 4; ++e2){
    int e = tid + e2*256;
    int r = e >> 4, c8 = (e & 15)*8;
    *(u16x8*)&vS[r*136 + c8] = pv[e2];
  }
  __syncthreads();

  // ---- phase 6: VT[c][m] = bf16(v[m][c]*beta[m]) ----
  {
    int m = tid & 63, dc = (tid >> 6)*32;
    float bsc = betas[m];
    #pragma unroll
    for(int d8 = 0; d8 < 32; d8 += 8){
      u16x8 vv = *(const u16x8*)&vS[m*136 + dc + d8];
      #pragma unroll
      for(int e = 0; e < 8; ++e)
        VT[(dc + d8 + e)*72 + m] = f2bf(bf2f(vv[e]) * bsc);
    }
  }
  __syncthreads();

  // ---- phase 7: u = T @ (v*beta) via MFMA ----
  {
    f32x4 ua[8] = {};
    #pragma unroll
    for(int ks = 0; ks < 2; ++ks){
      bf16x8 at = *(const bf16x8*)((const char*)Tb + (R0 + (lane & 15))*144 + ks*64 + (lane >> 4)*16);
      #pragma unroll
      for(int dt = 0; dt < 8; ++dt){
        bf16x8 bx = *(const bf16x8*)((const char*)VT + (dt*16 + (lane & 15))*144 + ks*64 + (lane >> 4)*16);
        ua[dt] = __builtin_amdgcn_mfma_f32_16x16x32_bf16(at, bx, ua[dt], 0, 0, 0);
      }
    }
    #pragma unroll
    for(int dt = 0; dt < 8; ++dt){
      int d = dt*16 + (lane & 15);
      #pragma unroll
      for(int r = 0; r < 4; ++r){
        int i = R0 + (lane >> 4)*4 + r;
        ub[uwbase + (size_t)i*128 + d] = f2bf(ua[dt][r]);
      }
    }
  }
}

// ---------------------------------------------------------------- phase B (per batch): MFMA chunk scan, c-split x8
// r20 register prefetch + raw barriers: lgkmcnt(0)-only before s_barrier so the
// prefetched GLOBAL loads (to registers) stay in flight across both barriers;
// compiler auto-inserts vmcnt waits at first register use (next chunk).
#define PB_BAR() { \
    asm volatile("s_waitcnt lgkmcnt(0)" ::: "memory"); \
    __builtin_amdgcn_s_barrier(); \
    __builtin_amdgcn_sched_barrier(0); \
  }

#define PB_LOAD(n_, W_, Q_, A_, K_, U_, G_) { \
    const int ls0 = (n_) * CHUNK; \
    const u16* lwrow = wb + uwb + (size_t)(n_)*8192; \
    const u16* larow = attnb + atb + (size_t)(n_)*4096; \
    _Pragma("unroll") \
    for(int ks = 0; ks < 4; ++ks){ \
      W_[ks] = *(const bf16x8*)&lwrow[(size_t)(i0w+cL)*128 + ks*32 + qq*8]; \
      Q_[ks] = *(const bf16x8*)&qbase[(size_t)(ls0 + i0w + cL)*128 + ks*32 + qq*8]; \
    } \
    _Pragma("unroll") \
    for(int ks = 0; ks < 2; ++ks) \
      A_[ks] = *(const bf16x8*)&larow[(size_t)(i0w+cL)*64 + ks*32 + qq*8]; \
    if((n_) < NCH-1){ \
      _Pragma("unroll") \
      for(int ks = 0; ks < 2; ++ks) \
        _Pragma("unroll") \
        for(int dt = 0; dt < 2; ++dt) \
          K_[ks*2+dt] = *(const bf16x8*)&kTb[(size_t)(d0w + dt*16 + cL)*SEQ + ls0 + ks*32 + qq*8]; \
    } \
    { \
      const u16* lurow = ub + uwb + (size_t)(n_)*8192; \
      U_ = *(const u16x4*)&lurow[(size_t)(tid>>2)*128 + cbb + (tid&3)*4]; \
    } \
    G_ = gcp[ls0 + lane]; \
  }

__global__ __launch_bounds__(256) void phaseB(const u16* __restrict__ qb, const u16* __restrict__ kbT,
      const u16* __restrict__ ub, const u16* __restrict__ wb, const u16* __restrict__ attnb,
      const float* __restrict__ gcb, u16* __restrict__ core){
  __shared__ __align__(16) u16 STbf[16][136];   // S^T: [16 c][128 d] + pad
  __shared__ __align__(16) u16 vnT[16][72];     // vn^T (for attn@vn)
  __shared__ __align__(16) u16 vnT2[16][72];    // (vn*e^{gl-gc})^T (for state update)
  __shared__ __align__(16) u16 uS[64][24];
  __shared__ float gcs[64];
  __shared__ float egm[64];
  const int f = blockIdx.x;              // 0..255
  const int xcd = f & 7, idx = f >> 3;   // idx 0..31
  const int h = xcd*4 + (idx >> 3);      // 0..31 (4 heads per XCD)
  const int split = idx & 7;             // 0..7
  const int cbb = split*16;              // state col base
  const int hk = h >> 1;
  const int tid = threadIdx.x;
  const int lane = tid & 63, wave = tid >> 6;
  const int cL = lane & 15, qq = lane >> 4;
  const int i0w = wave*16, d0w = wave*32;
  const float* gcp = gcb + (size_t)h*SEQ;
  const u16* qbase = qb + (size_t)hk*SEQ*DK;
  const u16* kTb   = kbT + (size_t)hk*DK*SEQ;
  const size_t uwb = (size_t)h*NCH*64*128;
  const size_t atb = (size_t)h*NCH*64*64;
  u16* corep = core + (size_t)h*SEQ*DV;
  f32x4 accS[2] = {};
  // prefetch chunk 0 operands
  bf16x8 cw[4], cq[4], ca[2], ck[4];
  u16x4 cu; float cg;
  PB_LOAD(0, cw, cq, ca, ck, cu, cg);
  for(int n = 0; n < NCH; ++n){
    const int s0 = n * CHUNK;
    // ---- top: STbf from accS; uS from prefetched regs; gc/egm from cg ----
    #pragma unroll
    for(int dt = 0; dt < 2; ++dt){
      u16x4 p;
      #pragma unroll
      for(int r = 0; r < 4; ++r) p[r] = f2bf(accS[dt][r]);
      *(u16x4*)&STbf[cL][d0w + dt*16 + qq*4] = p;
    }
    *(u16x4*)&uS[tid >> 2][(tid & 3)*4] = cu;
    if(wave == 0){
      gcs[lane] = cg;
      float gl = __shfl(cg, 63, 64);
      egm[lane] = __expf(gl - cg);
    }
    PB_BAR();
    // ---- issue next chunk's prefetch (stays in flight across both barriers) ----
    bf16x8 nw_[4], nq_[4], na_[2], nk_[4];
    u16x4 nu; float ng;
    if(n+1 < NCH) PB_LOAD(n+1, nw_, nq_, na_, nk_, nu, ng);
    // ---- M1: vn = u - w@S; write vnT and vnT2 ----
    bf16x8 bS[4];
    f32x4 accvn = {};
    #pragma unroll
    for(int ks = 0; ks < 4; ++ks){
      bS[ks] = *(const bf16x8*)&STbf[cL][ks*32 + qq*8];
      accvn = __builtin_amdgcn_mfma_f32_16x16x32_bf16(cw[ks], bS[ks], accvn, 0, 0, 0);
    }
    {
      u16x4 p, p2;
      #pragma unroll
      for(int r = 0; r < 4; ++r){
        int i = i0w + qq*4 + r;
        float vnv = bf2f(uS[i][cL]) - accvn[r];
        p[r]  = f2bf(vnv);
        p2[r] = f2bf(vnv * egm[i]);
      }
      *(u16x4*)&vnT [cL][i0w + qq*4] = p;
      *(u16x4*)&vnT2[cL][i0w + qq*4] = p2;
    }
    PB_BAR();
    // ---- tail: M2 o = q@S * e^gc; M3 o += attn@vn; store core; M4 state update ----
    f32x4 accO = {};
    #pragma unroll
    for(int ks = 0; ks < 4; ++ks)
      accO = __builtin_amdgcn_mfma_f32_16x16x32_bf16(cq[ks], bS[ks], accO, 0, 0, 0);
    #pragma unroll
    for(int r = 0; r < 4; ++r)
      accO[r] *= __expf(gcs[i0w + qq*4 + r]);
    #pragma unroll
    for(int ks = 0; ks < 2; ++ks){
      bf16x8 bV = *(const bf16x8*)&vnT[cL][ks*32 + qq*8];
      accO = __builtin_amdgcn_mfma_f32_16x16x32_bf16(ca[ks], bV, accO, 0, 0, 0);
    }
    #pragma unroll
    for(int r = 0; r < 4; ++r)
      corep[(size_t)(s0 + i0w + qq*4 + r)*DV + cbb + cL] = f2bf(accO[r]);
    if(n < NCH-1){
      float egl = __expf(gcs[63]);
      #pragma unroll
      for(int dt = 0; dt < 2; ++dt)
        accS[dt] *= egl;
      #pragma unroll
      for(int ks = 0; ks < 2; ++ks){
        bf16x8 bV2 = *(const bf16x8*)&vnT2[cL][ks*32 + qq*8];
        #pragma unroll
        for(int dt = 0; dt < 2; ++dt)
          accS[dt] = __builtin_amdgcn_mfma_f32_16x16x32_bf16(ck[ks*2+dt], bV2, accS[dt], 0, 0, 0);
      }
    }
    PB_BAR();
    // ---- rotate prefetched registers (constant indices -> stays in VGPRs) ----
    if(n+1 < NCH){
      #pragma unroll
      for(int i = 0; i < 4; ++i){ cw[i] = nw_[i]; cq[i] = nq_[i]; ck[i] = nk_[i]; }
      ca[0] = na_[0]; ca[1] = na_[1];
      cu = nu; cg = ng;
    }
  }
}

// ---------------------------------------------------------------- gated RMSNorm * silu(z) -> bf16 (per batch)
// 8 rows per 256-thread block (2 rows concurrently x 4 iters): 8x fewer blocks.
__global__ __launch_bounds__(256) void norm_gate(const u16* __restrict__ core, const u16* __restrict__ z_bf,
      const float* __restrict__ nw, u16* __restrict__ core2){
  const int h = blockIdx.y;
  const int s0 = blockIdx.x * 8;
  const int t = threadIdx.x & 127;      // elem within row
  const int rh = threadIdx.x >> 7;      // row pair half: 0/1
  __shared__ float red[8][2];
  const float nwv = nw[t];
  #pragma unroll
  for(int i = 0; i < 8; i += 2){
    const int s = s0 + i + rh;
    float x = bf2f(core[((size_t)h*SEQ + s)*DV + t]);
    float sq = x*x;
    #pragma unroll
    for(int off = 1; off < 64; off <<= 1) sq += __shfl_xor(sq, off, 64);
    if((t & 63) == 0) red[i+rh][t >> 6] = sq;
    __syncthreads();
    float var = (red[i+rh][0] + red[i+rh][1]) * (1.f/128.f);
    float y = x * rsqrtf(var + 1e-6f) * nwv;
    float zv = bf2f(z_bf[(size_t)s*VAL_DIM + h*DV + t]);
    y *= zv / (1.f + __expf(-zv));
    core2[(size_t)s*VAL_DIM + h*DV + t] = f2bf(y);
  }
}

// ---------------------------------------------------------------- launch
extern "C" void kernel_launch(void* const* d_in, const int* in_sizes, int n_in,
                              void* d_out, int out_size, void* d_ws, size_t ws_size,
                              hipStream_t stream){
  (void)in_sizes; (void)n_in; (void)out_size;
  const float* hs     = (const float*)d_in[0];
  const float* W_qkv  = (const float*)d_in[1];
  const float* conv_w = (const float*)d_in[2];
  const float* W_z    = (const float*)d_in[3];
  const float* W_b    = (const float*)d_in[4];
  const float* W_a    = (const float*)d_in[5];
  const float* dt_b   = (const float*)d_in[6];
  const float* A_log  = (const float*)d_in[7];
  const float* norm_w = (const float*)d_in[8];
  const float* W_out  = (const float*)d_in[9];
  float* out = (float*)d_out;

  const size_t MB = 1024ULL*1024ULL;
  if (ws_size < 160*MB) return;   // diagnostic: clean absmax-fail if ws too small
  const bool big  = (ws_size >= 208*MB);   // persistent weight transposes
  const bool big2 = (ws_size >= 224*MB);   // + persistent per-batch hs_bf (single cast)

  char* ws = (char*)d_ws;
  // ws map: [0,64M)=B  [64,96M)=C  [96,128M)=E  [128,160M)=D
  //         [160,208M)=persistent weights (big)  [208,224M)=hs_bf (big2)
  u16*   mixed  = (u16*)ws;                      // B: gemm1 -> conv
  u16*   attnB  = (u16*)ws;                      // B[0,16M): phaseA -> phaseB
  u16*   core_b = (u16*)(ws + 16*MB);            // B[16,48M): phaseB -> norm
  float* betab  = (float*)(ws + 48*MB);          // B[48M..): proj -> phaseA
  float* gbuf   = (float*)(ws + 48*MB + 512*1024);
  float* gcbuf  = (float*)(ws + 49*MB);          // phaseA -> phaseB
  u16*   WoutT  = (u16*)ws;                      // B[0,16M): after norm_b1
  u16*   qb     = (u16*)(ws + 64*MB);            // C[0,16M)
  u16*   kb     = (u16*)(ws + 80*MB);            // C[16,32M)
  u16*   zb     = (u16*)(ws + 64*MB);            // C: gemm2 -> norm (q,k dead after phaseB/transpose_k)
  u16*   core2  = (u16*)(ws + 96*MB);            // E+D: 64M contiguous [8192][4096]
  u16*   vb     = (u16*)(ws + 128*MB);           // D: conv -> phaseA
  u16*   kbT    = (u16*)(ws + 144*MB);           // D[16,32M): transpose_k -> phaseB (v dead)
  // weight homes: persistent (big) or per-batch scratch
  u16*   WqkvT  = big ? (u16*)(ws + 160*MB) : (u16*)d_out;           // 32MB
  u16*   WzT    = big ? (u16*)(ws + 192*MB) : (u16*)(ws + 128*MB);   // 16MB
  // d_out scratch (64M): (non-big) WqkvT [0,32M) + hs_bf1 [32,48.7M) during gemm1;
  // u [0,32M) + w [32,64M) phaseA->phaseB; hs_bf2 [0,16.7M) for gemm2 (after phaseB).
  u16*   hs_bf1 = big2 ? (u16*)(ws + 208*MB) : (u16*)((char*)d_out + 32*MB);
  u16*   u_d    = (u16*)d_out;
  u16*   w_d    = (u16*)((char*)d_out + 32*MB);
  u16*   hs_bf2 = big2 ? (u16*)(ws + 208*MB) : (u16*)d_out;   // big2: same persistent buffer

  if(big){
    transpose_cast<<<dim3(CONV_DIM/32, HID/32), 256, 0, stream>>>(W_qkv, WqkvT, HID, CONV_DIM);
    transpose_cast<<<dim3(VAL_DIM/32,  HID/32), 256, 0, stream>>>(W_z,   WzT,   HID, VAL_DIM);
  }
  for(int b = 0; b < BB; ++b){
    const float* hs_b = hs + (size_t)b*SEQ*HID;
    u16* core2_b = core2 + (size_t)b*SEQ*VAL_DIM;
    cast_bf<<<1024, 256, 0, stream>>>(hs_b, hs_bf1, SEQ*HID/8);
    if(!big) transpose_cast<<<dim3(CONV_DIM/32, HID/32), 256, 0, stream>>>(W_qkv, WqkvT, HID, CONV_DIM);
    gemm256<u16><<<dim3(CONV_DIM/256, SEQ/256), 512, 0, stream>>>(hs_bf1, WqkvT, mixed, SEQ, CONV_DIM, HID);
    conv_qkv<<<dim3(64, SEQ/CTS), 128, 0, stream>>>(mixed, conv_w, qb, kb, vb);
    proj_bg<<<SEQ/4, 256, 0, stream>>>(hs_b, W_b, W_a, dt_b, A_log, betab, gbuf);
    phaseA<<<dim3(NCH, HV), 256, 0, stream>>>(qb, kb, vb, betab, gbuf, gcbuf, u_d, w_d, attnB);
    transpose_k<<<dim3(SEQ/32, DK/32, HK), 256, 0, stream>>>(kb, kbT);   // after phaseA (vb dead)
    phaseB<<<256, 256, 0, stream>>>(qb, kbT, u_d, w_d, attnB, gcbuf, core_b);
    if(!big2) cast_bf<<<1024, 256, 0, stream>>>(hs_b, hs_bf2, SEQ*HID/8);
    if(!big) transpose_cast<<<dim3(VAL_DIM/32, HID/32), 256, 0, stream>>>(W_z, WzT, HID, VAL_DIM);
    gemm256<u16><<<dim3(VAL_DIM/256, SEQ/256), 512, 0, stream>>>(hs_bf2, WzT, zb, SEQ, VAL_DIM, HID);
    norm_gate<<<dim3(SEQ/8, HV), 256, 0, stream>>>(core_b, zb, norm_w, core2_b);
  }
  transpose_cast<<<dim3(HID/32, VAL_DIM/32), 256, 0, stream>>>(W_out, WoutT, VAL_DIM, HID);
  gemm256<float><<<dim3(HID/256, BS/256), 512, 0, stream>>>(core2, WoutT, out, BS, HID, VAL_DIM);
}

// Round 22
// 1294.482 us; speedup vs baseline: 1.2073x; 1.0190x over previous
//
#include <hip/hip_runtime.h>
#include <math.h>

#define BB 2
#define SEQ 4096
#define HID 2048
#define HV 32
#define HK 16
#define DK 128
#define DV 128
#define CHUNK 64
#define NCH 64
#define KEY_DIM 2048
#define VAL_DIM 4096
#define CONV_DIM 8192
#define BS 8192   // BB*SEQ
#define CTS 8     // conv s-tile

typedef unsigned short u16;
typedef __attribute__((ext_vector_type(8))) __bf16 bf16x8;
typedef __attribute__((ext_vector_type(4))) float f32x4;
typedef __attribute__((ext_vector_type(4))) unsigned short u16x4;
typedef __attribute__((ext_vector_type(8))) unsigned short u16x8;

__device__ __forceinline__ float bf2f(u16 x){
  return (float)__builtin_bit_cast(__bf16, x);
}
__device__ __forceinline__ u16 f2bf(float f){
  return __builtin_bit_cast(u16, (__bf16)f);
}

// async global->LDS, 16B per lane; LDS dest is wave-uniform base + lane*16
__device__ __forceinline__ void gl_lds16(const u16* g, u16* l){
  __builtin_amdgcn_global_load_lds((const __attribute__((address_space(1))) void*)g,
                                   (__attribute__((address_space(3))) void*)l, 16, 0, 0);
}

// ---------------------------------------------------------------- f32 -> bf16 cast (vectorized, grid-stride)
__global__ __launch_bounds__(256) void cast_bf(const float* __restrict__ in, u16* __restrict__ out, int n8){
  int i = blockIdx.x*256 + threadIdx.x;
  const int stride = gridDim.x*256;
  for(; i < n8; i += stride){
    float4 a = ((const float4*)in)[(size_t)i*2];
    float4 b = ((const float4*)in)[(size_t)i*2+1];
    u16x8 t;
    t[0]=f2bf(a.x); t[1]=f2bf(a.y); t[2]=f2bf(a.z); t[3]=f2bf(a.w);
    t[4]=f2bf(b.x); t[5]=f2bf(b.y); t[6]=f2bf(b.z); t[7]=f2bf(b.w);
    ((u16x8*)out)[i] = t;
  }
}

// ---------------------------------------------------------------- weight transpose: src [R,C] f32 -> dst [C,R] bf16
__global__ __launch_bounds__(256) void transpose_cast(const float* __restrict__ src, u16* __restrict__ dst, int R, int C){
  __shared__ float tile[32][33];
  int c0 = blockIdx.x*32, r0 = blockIdx.y*32;
  int tx = threadIdx.x & 31, ty = threadIdx.x >> 5;   // ty 0..7
  for(int i = ty; i < 32; i += 8) tile[i][tx] = src[(size_t)(r0+i)*C + c0 + tx];
  __syncthreads();
  for(int i = ty; i < 32; i += 8) dst[(size_t)(c0+i)*R + r0 + tx] = f2bf(tile[tx][i]);
}

// ---------------------------------------------------------------- k transpose (per batch): kb [HK][SEQ][DK] -> kbT [HK][DK][SEQ]
__global__ __launch_bounds__(256) void transpose_k(const u16* __restrict__ kb, u16* __restrict__ kbT){
  __shared__ u16 tile[32][33];
  const int h = blockIdx.z, d0 = blockIdx.y*32, s0 = blockIdx.x*32;
  const int tx = threadIdx.x & 31, ty = threadIdx.x >> 5;
  const u16* src = kb + (size_t)h*SEQ*DK;
  for(int i = ty; i < 32; i += 8) tile[i][tx] = src[(size_t)(s0+i)*DK + d0 + tx];
  __syncthreads();
  u16* dst = kbT + (size_t)h*DK*SEQ;
  for(int i = ty; i < 32; i += 8) dst[(size_t)(d0+i)*SEQ + s0 + tx] = tile[tx][i];
}

// ---------------------------------------------------------------- GEMM bf16, 256x256, BK=64, 8 waves, 2-buf counted-vmcnt pipeline
__device__ __forceinline__ void store_c(float* C, size_t idx, float v){ C[idx] = v; }
__device__ __forceinline__ void store_c(u16*   C, size_t idx, float v){ C[idx] = f2bf(v); }

__device__ __forceinline__ void stage256(const u16* __restrict__ A, const u16* __restrict__ Bt,
                                         size_t bm, size_t bn, int K, int k0,
                                         u16* Ab, u16* Bb, int wave, int lrow, int lg){
  const int g = lg ^ lrow;          // row&7 == lrow for all staged rows
  #pragma unroll
  for(int r = 0; r < 4; ++r){
    const int grow = r*64 + wave*8 + lrow;
    const int dst = (r>>1)*8192 + ((r&1)*64 + wave*8)*64;
    gl_lds16(&A [(bm + grow)*K + k0 + g*8], &Ab[dst]);
    gl_lds16(&Bt[(bn + grow)*K + k0 + g*8], &Bb[dst]);
  }
}

template<typename CT>
__global__ __launch_bounds__(512) void gemm256(const u16* __restrict__ A, const u16* __restrict__ Bt,
                                               CT* __restrict__ C, int M, int N, int K){
  (void)M;
  __shared__ u16 As[2][2][8192];   // [buf][half][128x64], 64KB
  __shared__ u16 Bs[2][2][8192];   // 64KB
  const int tid  = threadIdx.x;
  const int lane = tid & 63;
  const int wave = tid >> 6;       // 0..7
  const int lrow = lane >> 3, lg = lane & 7;
  // bijective XCD-chunked swizzle (all grids have nwg % 8 == 0)
  const int nwg = gridDim.x * gridDim.y;
  const int old = blockIdx.y * gridDim.x + blockIdx.x;
  const int nid = (old & 7) * (nwg >> 3) + (old >> 3);
  const int bx = nid % gridDim.x, by = nid / gridDim.x;
  const size_t bm = (size_t)by * 256;
  const size_t bn = (size_t)bx * 256;
  const int wm = (wave >> 2) * 128;     // 0 / 128
  const int wn = (wave & 3) * 64;       // 0 / 64 / 128 / 192
  const int ah = wave >> 2;             // this wave's A half
  const int bh = (wave & 3) >> 1;       // this wave's B half
  const int lwn = wn & 64;              // B row base within half
  const int cL15 = lane & 15, qq = lane >> 4;
  f32x4 acc[8][4] = {};
  const int nk = K >> 6;
  stage256(A, Bt, bm, bn, K, 0, &As[0][0][0], &Bs[0][0][0], wave, lrow, lg);
  for(int kt = 0; kt < nk; ++kt){
    if(kt+1 < nk){
      stage256(A, Bt, bm, bn, K, (kt+1) << 6, &As[(kt+1)&1][0][0], &Bs[(kt+1)&1][0][0], wave, lrow, lg);
      asm volatile("s_waitcnt vmcnt(8)" ::: "memory");   // tile kt landed; kt+1 in flight
    } else {
      asm volatile("s_waitcnt vmcnt(0)" ::: "memory");   // last tile: full drain
    }
    __builtin_amdgcn_s_barrier();
    __builtin_amdgcn_sched_barrier(0);
    const u16* Ah = As[kt&1][ah];
    const u16* Bh = Bs[kt&1][bh];
    __builtin_amdgcn_s_setprio(1);
    #pragma unroll
    for(int kk = 0; kk < 2; ++kk){
      bf16x8 af[8], bfr[4];
      #pragma unroll
      for(int mi = 0; mi < 8; ++mi){
        int lr = mi*16 + cL15;
        int cb = (kk*64 + qq*16) ^ ((lr & 7) << 4);
        af[mi] = *(const bf16x8*)((const char*)Ah + lr*128 + cb);
      }
      #pragma unroll
      for(int ni = 0; ni < 4; ++ni){
        int lr = lwn + ni*16 + cL15;
        int cb = (kk*64 + qq*16) ^ ((lr & 7) << 4);
        bfr[ni] = *(const bf16x8*)((const char*)Bh + lr*128 + cb);
      }
      #pragma unroll
      for(int mi = 0; mi < 8; ++mi)
        #pragma unroll
        for(int ni = 0; ni < 4; ++ni)
          acc[mi][ni] = __builtin_amdgcn_mfma_f32_16x16x32_bf16(af[mi], bfr[ni], acc[mi][ni], 0, 0, 0);
    }
    __builtin_amdgcn_s_setprio(0);
    __builtin_amdgcn_s_barrier();        // all waves done reading buf kt&1
    __builtin_amdgcn_sched_barrier(0);
  }
  const int c0 = (int)bn + wn + cL15;
  const int r0 = (int)bm + wm + qq*4;
  #pragma unroll
  for(int mi = 0; mi < 8; ++mi)
    #pragma unroll
    for(int ni = 0; ni < 4; ++ni)
      #pragma unroll
      for(int rr = 0; rr < 4; ++rr)
        store_c(C, (size_t)(r0 + mi*16 + rr)*N + (c0 + ni*16), acc[mi][ni][rr]);
}

// ---------------------------------------------------------------- beta/g projections (per batch), fp32 exact
__global__ __launch_bounds__(256) void proj_bg(const float* __restrict__ hs, const float* __restrict__ Wb,
      const float* __restrict__ Wa, const float* __restrict__ dtb, const float* __restrict__ A_log,
      float* __restrict__ betab, float* __restrict__ gbuf){
  __shared__ float h4[4][HID];          // 32KB: 4 rows of hs
  __shared__ float part[4][64][4];
  const int r0 = blockIdx.x * 4;
  const int tid = threadIdx.x;
  for(int i = tid; i < 4*HID/4; i += 256)
    ((float4*)&h4[0][0])[i] = ((const float4*)&hs[(size_t)r0*HID])[i];
  __syncthreads();
  const int o = tid & 63, pp = tid >> 6;
  const float* W = (o < 32) ? (Wb + o) : (Wa + (o - 32));
  float a0=0.f,a1=0.f,a2=0.f,a3=0.f;
  const int kbeg = pp*512;
  for(int kk = kbeg; kk < kbeg+512; ++kk){
    float wv = W[(size_t)kk*32];
    a0 += wv*h4[0][kk]; a1 += wv*h4[1][kk]; a2 += wv*h4[2][kk]; a3 += wv*h4[3][kk];
  }
  part[0][o][pp]=a0; part[1][o][pp]=a1; part[2][o][pp]=a2; part[3][o][pp]=a3;
  __syncthreads();
  {
    const int row = tid >> 6, oo = tid & 63;
    float sdot = part[row][oo][0]+part[row][oo][1]+part[row][oo][2]+part[row][oo][3];
    const int s = r0 + row;
    if(oo < 32){
      betab[(size_t)oo*SEQ + s] = 1.f/(1.f + __expf(-sdot));
    } else {
      const int hh = oo - 32;
      float x = sdot + dtb[hh];
      float sp = (x > 20.f) ? x : log1pf(__expf(x));
      gbuf[(size_t)hh*SEQ + s] = -__expf(A_log[hh]) * sp;
    }
  }
}

// ---------------------------------------------------------------- conv(4) + SiLU + split + l2norm -> bf16 (per batch)
__global__ __launch_bounds__(128) void conv_qkv(const u16* __restrict__ mixed, const float* __restrict__ conv_w,
      u16* __restrict__ qb, u16* __restrict__ kb, u16* __restrict__ vb){
  const int slot = blockIdx.x;          // 0..63  (16 q heads, 16 k heads, 32 v heads)
  const int s0 = blockIdx.y * CTS;      // 0..4095 step CTS
  const int t = threadIdx.x;            // 0..127
  const int c = slot*128 + t;
  __shared__ float red[CTS][2];
  float m[CTS+3];
  #pragma unroll
  for(int j = 0; j < CTS+3; ++j){
    int ss = s0 - 3 + j;
    m[j] = (ss >= 0) ? bf2f(mixed[(size_t)ss*CONV_DIM + c]) : 0.f;
  }
  const float w0 = conv_w[c*4+0], w1 = conv_w[c*4+1], w2 = conv_w[c*4+2], w3 = conv_w[c*4+3];
  float acc[CTS];
  #pragma unroll
  for(int i = 0; i < CTS; ++i){
    float a = 0.f;
    a += w0*m[i]; a += w1*m[i+1]; a += w2*m[i+2]; a += w3*m[i+3];
    acc[i] = a / (1.f + __expf(-a));    // SiLU
  }
  if(slot < 32){
    #pragma unroll
    for(int i = 0; i < CTS; ++i){
      float sq = acc[i]*acc[i];
      #pragma unroll
      for(int off = 1; off < 64; off <<= 1) sq += __shfl_xor(sq, off, 64);
      if((t & 63) == 0) red[i][t >> 6] = sq;
    }
    __syncthreads();
    #pragma unroll
    for(int i = 0; i < CTS; ++i){
      const int s = s0 + i;
      float rn = rsqrtf(red[i][0] + red[i][1] + 1e-6f);
      if(slot < 16)
        qb[((size_t)slot*SEQ + s)*DK + t] = f2bf(acc[i] * rn * 0.08838834764831845f); // * DK^-0.5
      else
        kb[((size_t)(slot-16)*SEQ + s)*DK + t] = f2bf(acc[i] * rn);
    }
  } else {
    #pragma unroll
    for(int i = 0; i < CTS; ++i)
      vb[((size_t)(slot-32)*SEQ + s0+i)*DV + t] = f2bf(acc[i]);
  }
}

// ---------------------------------------------------------------- phase A (per batch), MFMA version
__global__ __launch_bounds__(256) void phaseA(const u16* __restrict__ qb, const u16* __restrict__ kb,
      const u16* __restrict__ vb, const float* __restrict__ betab, const float* __restrict__ gb,
      float* __restrict__ gcb, u16* __restrict__ ub, u16* __restrict__ wb, u16* __restrict__ attnb){
  __shared__ __align__(16) char arena[63232];
  u16*   kS  = (u16*)(arena);
  u16*   qS  = (u16*)(arena + 17408);
  u16*   XT  = (u16*)(arena + 17408);
  u16*   VT  = (u16*)(arena + 17408);
  float* Ms  = (float*)(arena + 35840);
  u16*   vS  = (u16*)(arena + 35840);
  u16*   Tb  = (u16*)(arena + 53248);
  float* gcs   = (float*)(arena + 62464);
  float* betas = gcs + 64;
  float* wsc   = gcs + 128;

  const int n = blockIdx.x, h = blockIdx.y;
  const int hk = h >> 1;
  const int s0 = n * CHUNK;
  const int tid = threadIdx.x;
  const int lane = tid & 63;
  const int wave = tid >> 6;
  const int R0 = wave * 16;
  const size_t hS = (size_t)h*SEQ;
  const u16* kbase = kb + ((size_t)hk*SEQ + s0)*DK;
  const u16* qbase = qb + ((size_t)hk*SEQ + s0)*DK;
  const u16* vbase = vb + ((size_t)h*SEQ + s0)*DV;
  const size_t atbase = ((size_t)h*NCH + n)*64*64;
  const size_t uwbase = ((size_t)h*NCH + n)*64*128;

  // ---- phase 1: stage k,q; prefetch v into regs (used phase 5); gc scan ----
  u16x8 pv[4];
  #pragma unroll
  for(int e2 = 0; e2 < 4; ++e2){
    int e = tid + e2*256;
    int r = e >> 4, c8 = (e & 15)*8;
    pv[e2] = *(const u16x8*)&vbase[(size_t)r*128 + c8];
  }
  for(int e = tid; e < 1024; e += 256){
    int r = e >> 4, c8 = (e & 15)*8;
    *(u16x8*)&kS[r*136 + c8] = *(const u16x8*)&kbase[(size_t)r*128 + c8];
    *(u16x8*)&qS[r*136 + c8] = *(const u16x8*)&qbase[(size_t)r*128 + c8];
  }
  if(wave == 0){
    float v = gb[hS + s0 + lane];
    #pragma unroll
    for(int off = 1; off < 64; off <<= 1){
      float t = __shfl(v, (lane >= off) ? (lane - off) : lane, 64);
      if(lane >= off) v += t;
    }
    gcs[lane] = v;
    gcb[hS + s0 + lane] = v;
    float b = betab[hS + s0 + lane];
    betas[lane] = b;
    wsc[lane] = b * __expf(v);
  }
  __syncthreads();

  // ---- phase 2: S1 = k.k^T, S2 = q.k^T via MFMA; write Ms (f32) + attn (bf16) ----
  {
    f32x4 a1[4] = {}, a2[4] = {};
    #pragma unroll
    for(int ks = 0; ks < 4; ++ks){
      const int ab = (R0 + (lane & 15))*272 + ks*64 + (lane >> 4)*16;
      bf16x8 afk = *(const bf16x8*)((const char*)kS + ab);
      bf16x8 afq = *(const bf16x8*)((const char*)qS + ab);
      #pragma unroll
      for(int jt = 0; jt < 4; ++jt){
        const int bb = (jt*16 + (lane & 15))*272 + ks*64 + (lane >> 4)*16;
        bf16x8 bf = *(const bf16x8*)((const char*)kS + bb);
        a1[jt] = __builtin_amdgcn_mfma_f32_16x16x32_bf16(afk, bf, a1[jt], 0, 0, 0);
        a2[jt] = __builtin_amdgcn_mfma_f32_16x16x32_bf16(afq, bf, a2[jt], 0, 0, 0);
      }
    }
    #pragma unroll
    for(int jt = 0; jt < 4; ++jt){
      int j = jt*16 + (lane & 15);
      float gj = gcs[j];
      #pragma unroll
      for(int r = 0; r < 4; ++r){
        int i = R0 + (lane >> 4)*4 + r;
        float gi = gcs[i];
        float dec = (j <= i) ? __expf(gi - gj) : 0.f;
        Ms[i*64 + j] = (j < i) ? betas[i]*a1[jt][r]*dec : 0.f;
        attnb[atbase + (size_t)i*64 + j] = f2bf(a2[jt][r]*dec);
      }
    }
  }
  __syncthreads();

  // ---- phase 3: blocked inversion, f32 exact: Ms -> X = inv(I+M) ----
  {
    const int b0 = R0;
    const int j  = lane & 15;
    float x[16];
    #pragma unroll
    for(int i = 0; i < 16; ++i){
      float acc2 = (i == j) ? 1.f : 0.f;
      #pragma unroll
      for(int m = 0; m < 16; ++m){
        if(m < i) acc2 -= Ms[(b0+i)*64 + (b0+m)] * x[m];
      }
      x[i] = acc2;
    }
    if(lane < 16){
      #pragma unroll
      for(int i = 0; i < 16; ++i) Ms[(b0+i)*64 + (b0+j)] = x[i];
    }
  }
  __syncthreads();
  {
    float* Pscr = (float*)(arena + 17408);
    const int i = (tid >> 4) & 15, j = tid & 15;
    float P[2];
    #pragma unroll
    for(int gg = 0; gg < 2; ++gg){
      const int rb = 32*gg + 16, cb = 32*gg;
      float a = 0.f;
      #pragma unroll
      for(int k = 0; k < 16; ++k)
        a += Ms[(rb+i)*64 + cb+k] * Ms[(cb+k)*64 + cb+j];
      Pscr[gg*256 + i*16 + j] = a;
    }
    __syncthreads();
    #pragma unroll
    for(int gg = 0; gg < 2; ++gg){
      const int rb = 32*gg + 16;
      float a = 0.f;
      #pragma unroll
      for(int k = 0; k < 16; ++k)
        a -= Ms[(rb+i)*64 + rb+k] * Pscr[gg*256 + k*16 + j];
      P[gg] = a;
    }
    #pragma unroll
    for(int gg = 0; gg < 2; ++gg){
      const int rb = 32*gg + 16, cb = 32*gg;
      Ms[(rb+i)*64 + cb + j] = P[gg];
    }
  }
  __syncthreads();
  {
    float* Pscr = (float*)(arena + 17408);
    const int i = tid >> 3;
    const int j4 = (tid & 7) * 4;
    float p[4] = {0.f,0.f,0.f,0.f};
    #pragma unroll 8
    for(int k = 0; k < 32; ++k){
      float b = Ms[(32+i)*64 + k];
      #pragma unroll
      for(int c = 0; c < 4; ++c) p[c] += b * Ms[k*64 + j4 + c];
    }
    #pragma unroll
    for(int c = 0; c < 4; ++c) Pscr[i*32 + j4 + c] = p[c];
    __syncthreads();
    float q2[4] = {0.f,0.f,0.f,0.f};
    #pragma unroll 8
    for(int k = 0; k < 32; ++k){
      float xc = Ms[(32+i)*64 + 32+k];
      #pragma unroll
      for(int c = 0; c < 4; ++c) q2[c] -= xc * Pscr[k*32 + j4 + c];
    }
    #pragma unroll
    for(int c = 0; c < 4; ++c) Ms[(32+i)*64 + j4 + c] = q2[c];
  }
  __syncthreads();

  // ---- phase 4: Tb = bf16(T); XT[d][m] = bf16(k[m][d]*wsc[m]) ----
  for(int e = tid; e < 4096; e += 256){
    int i = e >> 6, j = e & 63;
    Tb[i*72 + j] = f2bf(Ms[e]);
  }
  {
    int m = tid & 63, dc = (tid >> 6)*32;
    float sc = wsc[m];
    #pragma unroll
    for(int d8 = 0; d8 < 32; d8 += 8){
      u16x8 kv = *(const u16x8*)&kS[m*136 + dc + d8];
      #pragma unroll
      for(int e = 0; e < 8; ++e)
        XT[(dc + d8 + e)*72 + m] = f2bf(bf2f(kv[e]) * sc);
    }
  }
  __syncthreads();

  // ---- phase 5: w = T @ (k*beta*e^gc) via MFMA; store prefetched v ----
  {
    f32x4 wa[8] = {};
    #pragma unroll
    for(int ks = 0; ks < 2; ++ks){
      bf16x8 at = *(const bf16x8*)((const char*)Tb + (R0 + (lane & 15))*144 + ks*64 + (lane >> 4)*16);
      #pragma unroll
      for(int dt = 0; dt < 8; ++dt){
        bf16x8 bx = *(const bf16x8*)((const char*)XT + (dt*16 + (lane & 15))*144 + ks*64 + (lane >> 4)*16);
        wa[dt] = __builtin_amdgcn_mfma_f32_16x16x32_bf16(at, bx, wa[dt], 0, 0, 0);
      }
    }
    #pragma unroll
    for(int dt = 0; dt < 8; ++dt){
      int d = dt*16 + (lane & 15);
      #pragma unroll
      for(int r = 0; r < 4; ++r){
        int i = R0 + (lane >> 4)*4 + r;
        wb[uwbase + (size_t)i*128 + d] = f2bf(wa[dt][r]);
      }
    }
  }
  #pragma unroll
  for(int e2 = 0; e2 < 4; ++e2){
    int e = tid + e2*256;
    int r = e >> 4, c8 = (e & 15)*8;
    *(u16x8*)&vS[r*136 + c8] = pv[e2];
  }
  __syncthreads();

  // ---- phase 6: VT[c][m] = bf16(v[m][c]*beta[m]) ----
  {
    int m = tid & 63, dc = (tid >> 6)*32;
    float bsc = betas[m];
    #pragma unroll
    for(int d8 = 0; d8 < 32; d8 += 8){
      u16x8 vv = *(const u16x8*)&vS[m*136 + dc + d8];
      #pragma unroll
      for(int e = 0; e < 8; ++e)
        VT[(dc + d8 + e)*72 + m] = f2bf(bf2f(vv[e]) * bsc);
    }
  }
  __syncthreads();

  // ---- phase 7: u = T @ (v*beta) via MFMA ----
  {
    f32x4 ua[8] = {};
    #pragma unroll
    for(int ks = 0; ks < 2; ++ks){
      bf16x8 at = *(const bf16x8*)((const char*)Tb + (R0 + (lane & 15))*144 + ks*64 + (lane >> 4)*16);
      #pragma unroll
      for(int dt = 0; dt < 8; ++dt){
        bf16x8 bx = *(const bf16x8*)((const char*)VT + (dt*16 + (lane & 15))*144 + ks*64 + (lane >> 4)*16);
        ua[dt] = __builtin_amdgcn_mfma_f32_16x16x32_bf16(at, bx, ua[dt], 0, 0, 0);
      }
    }
    #pragma unroll
    for(int dt = 0; dt < 8; ++dt){
      int d = dt*16 + (lane & 15);
      #pragma unroll
      for(int r = 0; r < 4; ++r){
        int i = R0 + (lane >> 4)*4 + r;
        ub[uwbase + (size_t)i*128 + d] = f2bf(ua[dt][r]);
      }
    }
  }
}

// ---------------------------------------------------------------- phase B (per batch): MFMA chunk scan, c-split x8
// 2 barriers per chunk: end-of-chunk barrier removed (hazard-free because
// BAR1(n+1) orders tail(n) reads before M1(n+1)'s vnT writes; STbf/uS top(n+1)
// overwrites are safe past BAR2(n); gcs/egm double-buffered by n&1).
#define PB_BAR() { \
    asm volatile("s_waitcnt lgkmcnt(0)" ::: "memory"); \
    __builtin_amdgcn_s_barrier(); \
    __builtin_amdgcn_sched_barrier(0); \
  }

#define PB_LOAD(n_, W_, Q_, A_, K_, U_, G_) { \
    const int ls0 = (n_) * CHUNK; \
    const u16* lwrow = wb + uwb + (size_t)(n_)*8192; \
    const u16* larow = attnb + atb + (size_t)(n_)*4096; \
    _Pragma("unroll") \
    for(int ks = 0; ks < 4; ++ks){ \
      W_[ks] = *(const bf16x8*)&lwrow[(size_t)(i0w+cL)*128 + ks*32 + qq*8]; \
      Q_[ks] = *(const bf16x8*)&qbase[(size_t)(ls0 + i0w + cL)*128 + ks*32 + qq*8]; \
    } \
    _Pragma("unroll") \
    for(int ks = 0; ks < 2; ++ks) \
      A_[ks] = *(const bf16x8*)&larow[(size_t)(i0w+cL)*64 + ks*32 + qq*8]; \
    if((n_) < NCH-1){ \
      _Pragma("unroll") \
      for(int ks = 0; ks < 2; ++ks) \
        _Pragma("unroll") \
        for(int dt = 0; dt < 2; ++dt) \
          K_[ks*2+dt] = *(const bf16x8*)&kTb[(size_t)(d0w + dt*16 + cL)*SEQ + ls0 + ks*32 + qq*8]; \
    } \
    { \
      const u16* lurow = ub + uwb + (size_t)(n_)*8192; \
      U_ = *(const u16x4*)&lurow[(size_t)(tid>>2)*128 + cbb + (tid&3)*4]; \
    } \
    G_ = gcp[ls0 + lane]; \
  }

__global__ __launch_bounds__(256) void phaseB(const u16* __restrict__ qb, const u16* __restrict__ kbT,
      const u16* __restrict__ ub, const u16* __restrict__ wb, const u16* __restrict__ attnb,
      const float* __restrict__ gcb, u16* __restrict__ core){
  __shared__ __align__(16) u16 STbf[16][136];   // S^T: [16 c][128 d] + pad
  __shared__ __align__(16) u16 vnT[16][72];     // vn^T (for attn@vn)
  __shared__ __align__(16) u16 vnT2[16][72];    // (vn*e^{gl-gc})^T (for state update)
  __shared__ __align__(16) u16 uS[64][24];
  __shared__ float gcs2[2][64];                 // double-buffered: n&1
  __shared__ float egm2[2][64];
  const int f = blockIdx.x;              // 0..255
  const int xcd = f & 7, idx = f >> 3;   // idx 0..31
  const int h = xcd*4 + (idx >> 3);      // 0..31 (4 heads per XCD)
  const int split = idx & 7;             // 0..7
  const int cbb = split*16;              // state col base
  const int hk = h >> 1;
  const int tid = threadIdx.x;
  const int lane = tid & 63, wave = tid >> 6;
  const int cL = lane & 15, qq = lane >> 4;
  const int i0w = wave*16, d0w = wave*32;
  const float* gcp = gcb + (size_t)h*SEQ;
  const u16* qbase = qb + (size_t)hk*SEQ*DK;
  const u16* kTb   = kbT + (size_t)hk*DK*SEQ;
  const size_t uwb = (size_t)h*NCH*64*128;
  const size_t atb = (size_t)h*NCH*64*64;
  u16* corep = core + (size_t)h*SEQ*DV;
  f32x4 accS[2] = {};
  // prefetch chunk 0 operands
  bf16x8 cw[4], cq[4], ca[2], ck[4];
  u16x4 cu; float cg;
  PB_LOAD(0, cw, cq, ca, ck, cu, cg);
  for(int n = 0; n < NCH; ++n){
    const int s0 = n * CHUNK;
    const int pb = n & 1;
    // ---- top: STbf from accS; uS from prefetched regs; gc/egm (buffer pb) ----
    #pragma unroll
    for(int dt = 0; dt < 2; ++dt){
      u16x4 p;
      #pragma unroll
      for(int r = 0; r < 4; ++r) p[r] = f2bf(accS[dt][r]);
      *(u16x4*)&STbf[cL][d0w + dt*16 + qq*4] = p;
    }
    *(u16x4*)&uS[tid >> 2][(tid & 3)*4] = cu;
    if(wave == 0){
      gcs2[pb][lane] = cg;
      float gl = __shfl(cg, 63, 64);
      egm2[pb][lane] = __expf(gl - cg);
    }
    PB_BAR();
    // ---- issue next chunk's prefetch (stays in flight across both barriers) ----
    bf16x8 nw_[4], nq_[4], na_[2], nk_[4];
    u16x4 nu; float ng;
    if(n+1 < NCH) PB_LOAD(n+1, nw_, nq_, na_, nk_, nu, ng);
    // ---- M1: vn = u - w@S; write vnT and vnT2 ----
    bf16x8 bS[4];
    f32x4 accvn = {};
    #pragma unroll
    for(int ks = 0; ks < 4; ++ks){
      bS[ks] = *(const bf16x8*)&STbf[cL][ks*32 + qq*8];
      accvn = __builtin_amdgcn_mfma_f32_16x16x32_bf16(cw[ks], bS[ks], accvn, 0, 0, 0);
    }
    {
      u16x4 p, p2;
      #pragma unroll
      for(int r = 0; r < 4; ++r){
        int i = i0w + qq*4 + r;
        float vnv = bf2f(uS[i][cL]) - accvn[r];
        p[r]  = f2bf(vnv);
        p2[r] = f2bf(vnv * egm2[pb][i]);
      }
      *(u16x4*)&vnT [cL][i0w + qq*4] = p;
      *(u16x4*)&vnT2[cL][i0w + qq*4] = p2;
    }
    PB_BAR();
    // ---- tail: M2 o = q@S * e^gc; M3 o += attn@vn; store core; M4 state update ----
    f32x4 accO = {};
    #pragma unroll
    for(int ks = 0; ks < 4; ++ks)
      accO = __builtin_amdgcn_mfma_f32_16x16x32_bf16(cq[ks], bS[ks], accO, 0, 0, 0);
    #pragma unroll
    for(int r = 0; r < 4; ++r)
      accO[r] *= __expf(gcs2[pb][i0w + qq*4 + r]);
    #pragma unroll
    for(int ks = 0; ks < 2; ++ks){
      bf16x8 bV = *(const bf16x8*)&vnT[cL][ks*32 + qq*8];
      accO = __builtin_amdgcn_mfma_f32_16x16x32_bf16(ca[ks], bV, accO, 0, 0, 0);
    }
    #pragma unroll
    for(int r = 0; r < 4; ++r)
      corep[(size_t)(s0 + i0w + qq*4 + r)*DV + cbb + cL] = f2bf(accO[r]);
    if(n < NCH-1){
      float egl = __expf(gcs2[pb][63]);
      #pragma unroll
      for(int dt = 0; dt < 2; ++dt)
        accS[dt] *= egl;
      #pragma unroll
      for(int ks = 0; ks < 2; ++ks){
        bf16x8 bV2 = *(const bf16x8*)&vnT2[cL][ks*32 + qq*8];
        #pragma unroll
        for(int dt = 0; dt < 2; ++dt)
          accS[dt] = __builtin_amdgcn_mfma_f32_16x16x32_bf16(ck[ks*2+dt], bV2, accS[dt], 0, 0, 0);
      }
    }
    // (end-of-chunk barrier removed: BAR1 of the next chunk provides the ordering)
    // ---- rotate prefetched registers (constant indices -> stays in VGPRs) ----
    if(n+1 < NCH){
      #pragma unroll
      for(int i = 0; i < 4; ++i){ cw[i] = nw_[i]; cq[i] = nq_[i]; ck[i] = nk_[i]; }
      ca[0] = na_[0]; ca[1] = na_[1];
      cu = nu; cg = ng;
    }
  }
}

// ---------------------------------------------------------------- gated RMSNorm * silu(z) -> bf16 (per batch)
// 8 rows per 256-thread block (2 rows concurrently x 4 iters): 8x fewer blocks.
__global__ __launch_bounds__(256) void norm_gate(const u16* __restrict__ core, const u16* __restrict__ z_bf,
      const float* __restrict__ nw, u16* __restrict__ core2){
  const int h = blockIdx.y;
  const int s0 = blockIdx.x * 8;
  const int t = threadIdx.x & 127;      // elem within row
  const int rh = threadIdx.x >> 7;      // row pair half: 0/1
  __shared__ float red[8][2];
  const float nwv = nw[t];
  #pragma unroll
  for(int i = 0; i < 8; i += 2){
    const int s = s0 + i + rh;
    float x = bf2f(core[((size_t)h*SEQ + s)*DV + t]);
    float sq = x*x;
    #pragma unroll
    for(int off = 1; off < 64; off <<= 1) sq += __shfl_xor(sq, off, 64);
    if((t & 63) == 0) red[i+rh][t >> 6] = sq;
    __syncthreads();
    float var = (red[i+rh][0] + red[i+rh][1]) * (1.f/128.f);
    float y = x * rsqrtf(var + 1e-6f) * nwv;
    float zv = bf2f(z_bf[(size_t)s*VAL_DIM + h*DV + t]);
    y *= zv / (1.f + __expf(-zv));
    core2[(size_t)s*VAL_DIM + h*DV + t] = f2bf(y);
  }
}

// ---------------------------------------------------------------- launch
extern "C" void kernel_launch(void* const* d_in, const int* in_sizes, int n_in,
                              void* d_out, int out_size, void* d_ws, size_t ws_size,
                              hipStream_t stream){
  (void)in_sizes; (void)n_in; (void)out_size;
  const float* hs     = (const float*)d_in[0];
  const float* W_qkv  = (const float*)d_in[1];
  const float* conv_w = (const float*)d_in[2];
  const float* W_z    = (const float*)d_in[3];
  const float* W_b    = (const float*)d_in[4];
  const float* W_a    = (const float*)d_in[5];
  const float* dt_b   = (const float*)d_in[6];
  const float* A_log  = (const float*)d_in[7];
  const float* norm_w = (const float*)d_in[8];
  const float* W_out  = (const float*)d_in[9];
  float* out = (float*)d_out;

  const size_t MB = 1024ULL*1024ULL;
  if (ws_size < 160*MB) return;   // diagnostic: clean absmax-fail if ws too small
  const bool big  = (ws_size >= 208*MB);   // persistent weight transposes
  const bool big2 = (ws_size >= 224*MB);   // + persistent per-batch hs_bf (single cast)

  char* ws = (char*)d_ws;
  // ws map: [0,64M)=B  [64,96M)=C  [96,128M)=E  [128,160M)=D
  //         [160,208M)=persistent weights (big)  [208,224M)=hs_bf (big2)
  u16*   mixed  = (u16*)ws;                      // B: gemm1 -> conv
  u16*   attnB  = (u16*)ws;                      // B[0,16M): phaseA -> phaseB
  u16*   core_b = (u16*)(ws + 16*MB);            // B[16,48M): phaseB -> norm
  float* betab  = (float*)(ws + 48*MB);          // B[48M..): proj -> phaseA
  float* gbuf   = (float*)(ws + 48*MB + 512*1024);
  float* gcbuf  = (float*)(ws + 49*MB);          // phaseA -> phaseB
  u16*   WoutT  = (u16*)ws;                      // B[0,16M): after norm_b1
  u16*   qb     = (u16*)(ws + 64*MB);            // C[0,16M)
  u16*   kb     = (u16*)(ws + 80*MB);            // C[16,32M)
  u16*   zb     = (u16*)(ws + 64*MB);            // C: gemm2 -> norm (q,k dead after phaseB/transpose_k)
  u16*   core2  = (u16*)(ws + 96*MB);            // E+D: 64M contiguous [8192][4096]
  u16*   vb     = (u16*)(ws + 128*MB);           // D: conv -> phaseA
  u16*   kbT    = (u16*)(ws + 144*MB);           // D[16,32M): transpose_k -> phaseB (v dead)
  // weight homes: persistent (big) or per-batch scratch
  u16*   WqkvT  = big ? (u16*)(ws + 160*MB) : (u16*)d_out;           // 32MB
  u16*   WzT    = big ? (u16*)(ws + 192*MB) : (u16*)(ws + 128*MB);   // 16MB
  // d_out scratch (64M): (non-big) WqkvT [0,32M) + hs_bf1 [32,48.7M) during gemm1;
  // u [0,32M) + w [32,64M) phaseA->phaseB; hs_bf2 [0,16.7M) for gemm2 (after phaseB).
  u16*   hs_bf1 = big2 ? (u16*)(ws + 208*MB) : (u16*)((char*)d_out + 32*MB);
  u16*   u_d    = (u16*)d_out;
  u16*   w_d    = (u16*)((char*)d_out + 32*MB);
  u16*   hs_bf2 = big2 ? (u16*)(ws + 208*MB) : (u16*)d_out;   // big2: same persistent buffer

  if(big){
    transpose_cast<<<dim3(CONV_DIM/32, HID/32), 256, 0, stream>>>(W_qkv, WqkvT, HID, CONV_DIM);
    transpose_cast<<<dim3(VAL_DIM/32,  HID/32), 256, 0, stream>>>(W_z,   WzT,   HID, VAL_DIM);
  }
  for(int b = 0; b < BB; ++b){
    const float* hs_b = hs + (size_t)b*SEQ*HID;
    u16* core2_b = core2 + (size_t)b*SEQ*VAL_DIM;
    cast_bf<<<1024, 256, 0, stream>>>(hs_b, hs_bf1, SEQ*HID/8);
    if(!big) transpose_cast<<<dim3(CONV_DIM/32, HID/32), 256, 0, stream>>>(W_qkv, WqkvT, HID, CONV_DIM);
    gemm256<u16><<<dim3(CONV_DIM/256, SEQ/256), 512, 0, stream>>>(hs_bf1, WqkvT, mixed, SEQ, CONV_DIM, HID);
    conv_qkv<<<dim3(64, SEQ/CTS), 128, 0, stream>>>(mixed, conv_w, qb, kb, vb);
    proj_bg<<<SEQ/4, 256, 0, stream>>>(hs_b, W_b, W_a, dt_b, A_log, betab, gbuf);
    phaseA<<<dim3(NCH, HV), 256, 0, stream>>>(qb, kb, vb, betab, gbuf, gcbuf, u_d, w_d, attnB);
    transpose_k<<<dim3(SEQ/32, DK/32, HK), 256, 0, stream>>>(kb, kbT);   // after phaseA (vb dead)
    phaseB<<<256, 256, 0, stream>>>(qb, kbT, u_d, w_d, attnB, gcbuf, core_b);
    if(!big2) cast_bf<<<1024, 256, 0, stream>>>(hs_b, hs_bf2, SEQ*HID/8);
    if(!big) transpose_cast<<<dim3(VAL_DIM/32, HID/32), 256, 0, stream>>>(W_z, WzT, HID, VAL_DIM);
    gemm256<u16><<<dim3(VAL_DIM/256, SEQ/256), 512, 0, stream>>>(hs_bf2, WzT, zb, SEQ, VAL_DIM, HID);
    norm_gate<<<dim3(SEQ/8, HV), 256, 0, stream>>>(core_b, zb, norm_w, core2_b);
  }
  transpose_cast<<<dim3(HID/32, VAL_DIM/32), 256, 0, stream>>>(W_out, WoutT, VAL_DIM, HID);
  gemm256<float><<<dim3(HID/256, BS/256), 512, 0, stream>>>(core2, WoutT, out, BS, HID, VAL_DIM);
}

// Round 23
// 1292.645 us; speedup vs baseline: 1.2090x; 1.0014x over previous
//
#include <hip/hip_runtime.h>
#include <math.h>

#define BB 2
#define SEQ 4096
#define HID 2048
#define HV 32
#define HK 16
#define DK 128
#define DV 128
#define CHUNK 64
#define NCH 64
#define KEY_DIM 2048
#define VAL_DIM 4096
#define CONV_DIM 8192
#define BS 8192   // BB*SEQ
#define CTS 8     // conv s-tile

typedef unsigned short u16;
typedef __attribute__((ext_vector_type(8))) __bf16 bf16x8;
typedef __attribute__((ext_vector_type(4))) float f32x4;
typedef __attribute__((ext_vector_type(4))) unsigned short u16x4;
typedef __attribute__((ext_vector_type(8))) unsigned short u16x8;

__device__ __forceinline__ float bf2f(u16 x){
  return (float)__builtin_bit_cast(__bf16, x);
}
__device__ __forceinline__ u16 f2bf(float f){
  return __builtin_bit_cast(u16, (__bf16)f);
}

// raw barrier: LDS-only ordering (no vmcnt drain) — valid when all cross-wave
// communication is via LDS; global loads-to-reg keep HW per-wave dependency.
#define LDS_BAR() { \
    asm volatile("s_waitcnt lgkmcnt(0)" ::: "memory"); \
    __builtin_amdgcn_s_barrier(); \
    __builtin_amdgcn_sched_barrier(0); \
  }

// async global->LDS, 16B per lane; LDS dest is wave-uniform base + lane*16
__device__ __forceinline__ void gl_lds16(const u16* g, u16* l){
  __builtin_amdgcn_global_load_lds((const __attribute__((address_space(1))) void*)g,
                                   (__attribute__((address_space(3))) void*)l, 16, 0, 0);
}

// ---------------------------------------------------------------- f32 -> bf16 cast (vectorized, grid-stride)
__global__ __launch_bounds__(256) void cast_bf(const float* __restrict__ in, u16* __restrict__ out, int n8){
  int i = blockIdx.x*256 + threadIdx.x;
  const int stride = gridDim.x*256;
  for(; i < n8; i += stride){
    float4 a = ((const float4*)in)[(size_t)i*2];
    float4 b = ((const float4*)in)[(size_t)i*2+1];
    u16x8 t;
    t[0]=f2bf(a.x); t[1]=f2bf(a.y); t[2]=f2bf(a.z); t[3]=f2bf(a.w);
    t[4]=f2bf(b.x); t[5]=f2bf(b.y); t[6]=f2bf(b.z); t[7]=f2bf(b.w);
    ((u16x8*)out)[i] = t;
  }
}

// ---------------------------------------------------------------- weight transpose: src [R,C] f32 -> dst [C,R] bf16
__global__ __launch_bounds__(256) void transpose_cast(const float* __restrict__ src, u16* __restrict__ dst, int R, int C){
  __shared__ float tile[32][33];
  int c0 = blockIdx.x*32, r0 = blockIdx.y*32;
  int tx = threadIdx.x & 31, ty = threadIdx.x >> 5;   // ty 0..7
  for(int i = ty; i < 32; i += 8) tile[i][tx] = src[(size_t)(r0+i)*C + c0 + tx];
  __syncthreads();
  for(int i = ty; i < 32; i += 8) dst[(size_t)(c0+i)*R + r0 + tx] = f2bf(tile[tx][i]);
}

// ---------------------------------------------------------------- k transpose (per batch): kb [HK][SEQ][DK] -> kbT [HK][DK][SEQ]
__global__ __launch_bounds__(256) void transpose_k(const u16* __restrict__ kb, u16* __restrict__ kbT){
  __shared__ u16 tile[32][33];
  const int h = blockIdx.z, d0 = blockIdx.y*32, s0 = blockIdx.x*32;
  const int tx = threadIdx.x & 31, ty = threadIdx.x >> 5;
  const u16* src = kb + (size_t)h*SEQ*DK;
  for(int i = ty; i < 32; i += 8) tile[i][tx] = src[(size_t)(s0+i)*DK + d0 + tx];
  __syncthreads();
  u16* dst = kbT + (size_t)h*DK*SEQ;
  for(int i = ty; i < 32; i += 8) dst[(size_t)(d0+i)*SEQ + s0 + tx] = tile[tx][i];
}

// ---------------------------------------------------------------- GEMM bf16, 256x256, BK=64, 8 waves, 2-buf counted-vmcnt pipeline
__device__ __forceinline__ void store_c(float* C, size_t idx, float v){ C[idx] = v; }
__device__ __forceinline__ void store_c(u16*   C, size_t idx, float v){ C[idx] = f2bf(v); }

__device__ __forceinline__ void stage256(const u16* __restrict__ A, const u16* __restrict__ Bt,
                                         size_t bm, size_t bn, int K, int k0,
                                         u16* Ab, u16* Bb, int wave, int lrow, int lg){
  const int g = lg ^ lrow;          // row&7 == lrow for all staged rows
  #pragma unroll
  for(int r = 0; r < 4; ++r){
    const int grow = r*64 + wave*8 + lrow;
    const int dst = (r>>1)*8192 + ((r&1)*64 + wave*8)*64;
    gl_lds16(&A [(bm + grow)*K + k0 + g*8], &Ab[dst]);
    gl_lds16(&Bt[(bn + grow)*K + k0 + g*8], &Bb[dst]);
  }
}

template<typename CT>
__global__ __launch_bounds__(512) void gemm256(const u16* __restrict__ A, const u16* __restrict__ Bt,
                                               CT* __restrict__ C, int M, int N, int K){
  (void)M;
  __shared__ u16 As[2][2][8192];   // [buf][half][128x64], 64KB
  __shared__ u16 Bs[2][2][8192];   // 64KB
  const int tid  = threadIdx.x;
  const int lane = tid & 63;
  const int wave = tid >> 6;       // 0..7
  const int lrow = lane >> 3, lg = lane & 7;
  // bijective XCD-chunked swizzle (all grids have nwg % 8 == 0)
  const int nwg = gridDim.x * gridDim.y;
  const int old = blockIdx.y * gridDim.x + blockIdx.x;
  const int nid = (old & 7) * (nwg >> 3) + (old >> 3);
  const int bx = nid % gridDim.x, by = nid / gridDim.x;
  const size_t bm = (size_t)by * 256;
  const size_t bn = (size_t)bx * 256;
  const int wm = (wave >> 2) * 128;     // 0 / 128
  const int wn = (wave & 3) * 64;       // 0 / 64 / 128 / 192
  const int ah = wave >> 2;             // this wave's A half
  const int bh = (wave & 3) >> 1;       // this wave's B half
  const int lwn = wn & 64;              // B row base within half
  const int cL15 = lane & 15, qq = lane >> 4;
  f32x4 acc[8][4] = {};
  const int nk = K >> 6;
  stage256(A, Bt, bm, bn, K, 0, &As[0][0][0], &Bs[0][0][0], wave, lrow, lg);
  for(int kt = 0; kt < nk; ++kt){
    if(kt+1 < nk){
      stage256(A, Bt, bm, bn, K, (kt+1) << 6, &As[(kt+1)&1][0][0], &Bs[(kt+1)&1][0][0], wave, lrow, lg);
      asm volatile("s_waitcnt vmcnt(8)" ::: "memory");   // tile kt landed; kt+1 in flight
    } else {
      asm volatile("s_waitcnt vmcnt(0)" ::: "memory");   // last tile: full drain
    }
    __builtin_amdgcn_s_barrier();
    __builtin_amdgcn_sched_barrier(0);
    const u16* Ah = As[kt&1][ah];
    const u16* Bh = Bs[kt&1][bh];
    __builtin_amdgcn_s_setprio(1);
    #pragma unroll
    for(int kk = 0; kk < 2; ++kk){
      bf16x8 af[8], bfr[4];
      #pragma unroll
      for(int mi = 0; mi < 8; ++mi){
        int lr = mi*16 + cL15;
        int cb = (kk*64 + qq*16) ^ ((lr & 7) << 4);
        af[mi] = *(const bf16x8*)((const char*)Ah + lr*128 + cb);
      }
      #pragma unroll
      for(int ni = 0; ni < 4; ++ni){
        int lr = lwn + ni*16 + cL15;
        int cb = (kk*64 + qq*16) ^ ((lr & 7) << 4);
        bfr[ni] = *(const bf16x8*)((const char*)Bh + lr*128 + cb);
      }
      #pragma unroll
      for(int mi = 0; mi < 8; ++mi)
        #pragma unroll
        for(int ni = 0; ni < 4; ++ni)
          acc[mi][ni] = __builtin_amdgcn_mfma_f32_16x16x32_bf16(af[mi], bfr[ni], acc[mi][ni], 0, 0, 0);
    }
    __builtin_amdgcn_s_setprio(0);
    __builtin_amdgcn_s_barrier();        // all waves done reading buf kt&1
    __builtin_amdgcn_sched_barrier(0);
  }
  const int c0 = (int)bn + wn + cL15;
  const int r0 = (int)bm + wm + qq*4;
  #pragma unroll
  for(int mi = 0; mi < 8; ++mi)
    #pragma unroll
    for(int ni = 0; ni < 4; ++ni)
      #pragma unroll
      for(int rr = 0; rr < 4; ++rr)
        store_c(C, (size_t)(r0 + mi*16 + rr)*N + (c0 + ni*16), acc[mi][ni][rr]);
}

// ---------------------------------------------------------------- beta/g projections (per batch), fp32 exact
__global__ __launch_bounds__(256) void proj_bg(const float* __restrict__ hs, const float* __restrict__ Wb,
      const float* __restrict__ Wa, const float* __restrict__ dtb, const float* __restrict__ A_log,
      float* __restrict__ betab, float* __restrict__ gbuf){
  __shared__ float h4[4][HID];          // 32KB: 4 rows of hs
  __shared__ float part[4][64][4];
  const int r0 = blockIdx.x * 4;
  const int tid = threadIdx.x;
  for(int i = tid; i < 4*HID/4; i += 256)
    ((float4*)&h4[0][0])[i] = ((const float4*)&hs[(size_t)r0*HID])[i];
  __syncthreads();
  const int o = tid & 63, pp = tid >> 6;
  const float* W = (o < 32) ? (Wb + o) : (Wa + (o - 32));
  float a0=0.f,a1=0.f,a2=0.f,a3=0.f;
  const int kbeg = pp*512;
  for(int kk = kbeg; kk < kbeg+512; ++kk){
    float wv = W[(size_t)kk*32];
    a0 += wv*h4[0][kk]; a1 += wv*h4[1][kk]; a2 += wv*h4[2][kk]; a3 += wv*h4[3][kk];
  }
  part[0][o][pp]=a0; part[1][o][pp]=a1; part[2][o][pp]=a2; part[3][o][pp]=a3;
  __syncthreads();
  {
    const int row = tid >> 6, oo = tid & 63;
    float sdot = part[row][oo][0]+part[row][oo][1]+part[row][oo][2]+part[row][oo][3];
    const int s = r0 + row;
    if(oo < 32){
      betab[(size_t)oo*SEQ + s] = 1.f/(1.f + __expf(-sdot));
    } else {
      const int hh = oo - 32;
      float x = sdot + dtb[hh];
      float sp = (x > 20.f) ? x : log1pf(__expf(x));
      gbuf[(size_t)hh*SEQ + s] = -__expf(A_log[hh]) * sp;
    }
  }
}

// ---------------------------------------------------------------- conv(4) + SiLU + split + l2norm -> bf16 (per batch)
__global__ __launch_bounds__(128) void conv_qkv(const u16* __restrict__ mixed, const float* __restrict__ conv_w,
      u16* __restrict__ qb, u16* __restrict__ kb, u16* __restrict__ vb){
  const int slot = blockIdx.x;          // 0..63  (16 q heads, 16 k heads, 32 v heads)
  const int s0 = blockIdx.y * CTS;      // 0..4095 step CTS
  const int t = threadIdx.x;            // 0..127
  const int c = slot*128 + t;
  __shared__ float red[CTS][2];
  float m[CTS+3];
  #pragma unroll
  for(int j = 0; j < CTS+3; ++j){
    int ss = s0 - 3 + j;
    m[j] = (ss >= 0) ? bf2f(mixed[(size_t)ss*CONV_DIM + c]) : 0.f;
  }
  const float w0 = conv_w[c*4+0], w1 = conv_w[c*4+1], w2 = conv_w[c*4+2], w3 = conv_w[c*4+3];
  float acc[CTS];
  #pragma unroll
  for(int i = 0; i < CTS; ++i){
    float a = 0.f;
    a += w0*m[i]; a += w1*m[i+1]; a += w2*m[i+2]; a += w3*m[i+3];
    acc[i] = a / (1.f + __expf(-a));    // SiLU
  }
  if(slot < 32){
    #pragma unroll
    for(int i = 0; i < CTS; ++i){
      float sq = acc[i]*acc[i];
      #pragma unroll
      for(int off = 1; off < 64; off <<= 1) sq += __shfl_xor(sq, off, 64);
      if((t & 63) == 0) red[i][t >> 6] = sq;
    }
    __syncthreads();
    #pragma unroll
    for(int i = 0; i < CTS; ++i){
      const int s = s0 + i;
      float rn = rsqrtf(red[i][0] + red[i][1] + 1e-6f);
      if(slot < 16)
        qb[((size_t)slot*SEQ + s)*DK + t] = f2bf(acc[i] * rn * 0.08838834764831845f); // * DK^-0.5
      else
        kb[((size_t)(slot-16)*SEQ + s)*DK + t] = f2bf(acc[i] * rn);
    }
  } else {
    #pragma unroll
    for(int i = 0; i < CTS; ++i)
      vb[((size_t)(slot-32)*SEQ + s0+i)*DV + t] = f2bf(acc[i]);
  }
}

// ---------------------------------------------------------------- phase A (per batch), MFMA version
// All cross-wave communication is via LDS -> every barrier is LDS_BAR()
// (lgkmcnt-only): the v-prefetch loads and attn/w/u global stores are never
// force-drained at barriers.
__global__ __launch_bounds__(256) void phaseA(const u16* __restrict__ qb, const u16* __restrict__ kb,
      const u16* __restrict__ vb, const float* __restrict__ betab, const float* __restrict__ gb,
      float* __restrict__ gcb, u16* __restrict__ ub, u16* __restrict__ wb, u16* __restrict__ attnb){
  __shared__ __align__(16) char arena[63232];
  u16*   kS  = (u16*)(arena);
  u16*   qS  = (u16*)(arena + 17408);
  u16*   XT  = (u16*)(arena + 17408);
  u16*   VT  = (u16*)(arena + 17408);
  float* Ms  = (float*)(arena + 35840);
  u16*   vS  = (u16*)(arena + 35840);
  u16*   Tb  = (u16*)(arena + 53248);
  float* gcs   = (float*)(arena + 62464);
  float* betas = gcs + 64;
  float* wsc   = gcs + 128;

  const int n = blockIdx.x, h = blockIdx.y;
  const int hk = h >> 1;
  const int s0 = n * CHUNK;
  const int tid = threadIdx.x;
  const int lane = tid & 63;
  const int wave = tid >> 6;
  const int R0 = wave * 16;
  const size_t hS = (size_t)h*SEQ;
  const u16* kbase = kb + ((size_t)hk*SEQ + s0)*DK;
  const u16* qbase = qb + ((size_t)hk*SEQ + s0)*DK;
  const u16* vbase = vb + ((size_t)h*SEQ + s0)*DV;
  const size_t atbase = ((size_t)h*NCH + n)*64*64;
  const size_t uwbase = ((size_t)h*NCH + n)*64*128;

  // ---- phase 1: stage k,q; prefetch v into regs (used phase 5); gc scan ----
  u16x8 pv[4];
  #pragma unroll
  for(int e2 = 0; e2 < 4; ++e2){
    int e = tid + e2*256;
    int r = e >> 4, c8 = (e & 15)*8;
    pv[e2] = *(const u16x8*)&vbase[(size_t)r*128 + c8];
  }
  for(int e = tid; e < 1024; e += 256){
    int r = e >> 4, c8 = (e & 15)*8;
    *(u16x8*)&kS[r*136 + c8] = *(const u16x8*)&kbase[(size_t)r*128 + c8];
    *(u16x8*)&qS[r*136 + c8] = *(const u16x8*)&qbase[(size_t)r*128 + c8];
  }
  if(wave == 0){
    float v = gb[hS + s0 + lane];
    #pragma unroll
    for(int off = 1; off < 64; off <<= 1){
      float t = __shfl(v, (lane >= off) ? (lane - off) : lane, 64);
      if(lane >= off) v += t;
    }
    gcs[lane] = v;
    gcb[hS + s0 + lane] = v;
    float b = betab[hS + s0 + lane];
    betas[lane] = b;
    wsc[lane] = b * __expf(v);
  }
  LDS_BAR();

  // ---- phase 2: S1 = k.k^T, S2 = q.k^T via MFMA; write Ms (f32) + attn (bf16) ----
  {
    f32x4 a1[4] = {}, a2[4] = {};
    #pragma unroll
    for(int ks = 0; ks < 4; ++ks){
      const int ab = (R0 + (lane & 15))*272 + ks*64 + (lane >> 4)*16;
      bf16x8 afk = *(const bf16x8*)((const char*)kS + ab);
      bf16x8 afq = *(const bf16x8*)((const char*)qS + ab);
      #pragma unroll
      for(int jt = 0; jt < 4; ++jt){
        const int bb = (jt*16 + (lane & 15))*272 + ks*64 + (lane >> 4)*16;
        bf16x8 bf = *(const bf16x8*)((const char*)kS + bb);
        a1[jt] = __builtin_amdgcn_mfma_f32_16x16x32_bf16(afk, bf, a1[jt], 0, 0, 0);
        a2[jt] = __builtin_amdgcn_mfma_f32_16x16x32_bf16(afq, bf, a2[jt], 0, 0, 0);
      }
    }
    #pragma unroll
    for(int jt = 0; jt < 4; ++jt){
      int j = jt*16 + (lane & 15);
      float gj = gcs[j];
      #pragma unroll
      for(int r = 0; r < 4; ++r){
        int i = R0 + (lane >> 4)*4 + r;
        float gi = gcs[i];
        float dec = (j <= i) ? __expf(gi - gj) : 0.f;
        Ms[i*64 + j] = (j < i) ? betas[i]*a1[jt][r]*dec : 0.f;
        attnb[atbase + (size_t)i*64 + j] = f2bf(a2[jt][r]*dec);
      }
    }
  }
  LDS_BAR();

  // ---- phase 3: blocked inversion, f32 exact: Ms -> X = inv(I+M) ----
  {
    const int b0 = R0;
    const int j  = lane & 15;
    float x[16];
    #pragma unroll
    for(int i = 0; i < 16; ++i){
      float acc2 = (i == j) ? 1.f : 0.f;
      #pragma unroll
      for(int m = 0; m < 16; ++m){
        if(m < i) acc2 -= Ms[(b0+i)*64 + (b0+m)] * x[m];
      }
      x[i] = acc2;
    }
    if(lane < 16){
      #pragma unroll
      for(int i = 0; i < 16; ++i) Ms[(b0+i)*64 + (b0+j)] = x[i];
    }
  }
  LDS_BAR();
  {
    float* Pscr = (float*)(arena + 17408);
    const int i = (tid >> 4) & 15, j = tid & 15;
    float P[2];
    #pragma unroll
    for(int gg = 0; gg < 2; ++gg){
      const int rb = 32*gg + 16, cb = 32*gg;
      float a = 0.f;
      #pragma unroll
      for(int k = 0; k < 16; ++k)
        a += Ms[(rb+i)*64 + cb+k] * Ms[(cb+k)*64 + cb+j];
      Pscr[gg*256 + i*16 + j] = a;
    }
    LDS_BAR();
    #pragma unroll
    for(int gg = 0; gg < 2; ++gg){
      const int rb = 32*gg + 16;
      float a = 0.f;
      #pragma unroll
      for(int k = 0; k < 16; ++k)
        a -= Ms[(rb+i)*64 + rb+k] * Pscr[gg*256 + k*16 + j];
      P[gg] = a;
    }
    #pragma unroll
    for(int gg = 0; gg < 2; ++gg){
      const int rb = 32*gg + 16, cb = 32*gg;
      Ms[(rb+i)*64 + cb + j] = P[gg];
    }
  }
  LDS_BAR();
  {
    float* Pscr = (float*)(arena + 17408);
    const int i = tid >> 3;
    const int j4 = (tid & 7) * 4;
    float p[4] = {0.f,0.f,0.f,0.f};
    #pragma unroll 8
    for(int k = 0; k < 32; ++k){
      float b = Ms[(32+i)*64 + k];
      #pragma unroll
      for(int c = 0; c < 4; ++c) p[c] += b * Ms[k*64 + j4 + c];
    }
    #pragma unroll
    for(int c = 0; c < 4; ++c) Pscr[i*32 + j4 + c] = p[c];
    LDS_BAR();
    float q2[4] = {0.f,0.f,0.f,0.f};
    #pragma unroll 8
    for(int k = 0; k < 32; ++k){
      float xc = Ms[(32+i)*64 + 32+k];
      #pragma unroll
      for(int c = 0; c < 4; ++c) q2[c] -= xc * Pscr[k*32 + j4 + c];
    }
    #pragma unroll
    for(int c = 0; c < 4; ++c) Ms[(32+i)*64 + j4 + c] = q2[c];
  }
  LDS_BAR();

  // ---- phase 4: Tb = bf16(T); XT[d][m] = bf16(k[m][d]*wsc[m]) ----
  for(int e = tid; e < 4096; e += 256){
    int i = e >> 6, j = e & 63;
    Tb[i*72 + j] = f2bf(Ms[e]);
  }
  {
    int m = tid & 63, dc = (tid >> 6)*32;
    float sc = wsc[m];
    #pragma unroll
    for(int d8 = 0; d8 < 32; d8 += 8){
      u16x8 kv = *(const u16x8*)&kS[m*136 + dc + d8];
      #pragma unroll
      for(int e = 0; e < 8; ++e)
        XT[(dc + d8 + e)*72 + m] = f2bf(bf2f(kv[e]) * sc);
    }
  }
  LDS_BAR();

  // ---- phase 5: w = T @ (k*beta*e^gc) via MFMA; store prefetched v ----
  {
    f32x4 wa[8] = {};
    #pragma unroll
    for(int ks = 0; ks < 2; ++ks){
      bf16x8 at = *(const bf16x8*)((const char*)Tb + (R0 + (lane & 15))*144 + ks*64 + (lane >> 4)*16);
      #pragma unroll
      for(int dt = 0; dt < 8; ++dt){
        bf16x8 bx = *(const bf16x8*)((const char*)XT + (dt*16 + (lane & 15))*144 + ks*64 + (lane >> 4)*16);
        wa[dt] = __builtin_amdgcn_mfma_f32_16x16x32_bf16(at, bx, wa[dt], 0, 0, 0);
      }
    }
    #pragma unroll
    for(int dt = 0; dt < 8; ++dt){
      int d = dt*16 + (lane & 15);
      #pragma unroll
      for(int r = 0; r < 4; ++r){
        int i = R0 + (lane >> 4)*4 + r;
        wb[uwbase + (size_t)i*128 + d] = f2bf(wa[dt][r]);
      }
    }
  }
  #pragma unroll
  for(int e2 = 0; e2 < 4; ++e2){
    int e = tid + e2*256;
    int r = e >> 4, c8 = (e & 15)*8;
    *(u16x8*)&vS[r*136 + c8] = pv[e2];
  }
  LDS_BAR();

  // ---- phase 6: VT[c][m] = bf16(v[m][c]*beta[m]) ----
  {
    int m = tid & 63, dc = (tid >> 6)*32;
    float bsc = betas[m];
    #pragma unroll
    for(int d8 = 0; d8 < 32; d8 += 8){
      u16x8 vv = *(const u16x8*)&vS[m*136 + dc + d8];
      #pragma unroll
      for(int e = 0; e < 8; ++e)
        VT[(dc + d8 + e)*72 + m] = f2bf(bf2f(vv[e]) * bsc);
    }
  }
  LDS_BAR();

  // ---- phase 7: u = T @ (v*beta) via MFMA ----
  {
    f32x4 ua[8] = {};
    #pragma unroll
    for(int ks = 0; ks < 2; ++ks){
      bf16x8 at = *(const bf16x8*)((const char*)Tb + (R0 + (lane & 15))*144 + ks*64 + (lane >> 4)*16);
      #pragma unroll
      for(int dt = 0; dt < 8; ++dt){
        bf16x8 bx = *(const bf16x8*)((const char*)VT + (dt*16 + (lane & 15))*144 + ks*64 + (lane >> 4)*16);
        ua[dt] = __builtin_amdgcn_mfma_f32_16x16x32_bf16(at, bx, ua[dt], 0, 0, 0);
      }
    }
    #pragma unroll
    for(int dt = 0; dt < 8; ++dt){
      int d = dt*16 + (lane & 15);
      #pragma unroll
      for(int r = 0; r < 4; ++r){
        int i = R0 + (lane >> 4)*4 + r;
        ub[uwbase + (size_t)i*128 + d] = f2bf(ua[dt][r]);
      }
    }
  }
}

// ---------------------------------------------------------------- phase B (per batch): MFMA chunk scan, c-split x8
#define PB_LOAD(n_, W_, Q_, A_, K_, U_, G_) { \
    const int ls0 = (n_) * CHUNK; \
    const u16* lwrow = wb + uwb + (size_t)(n_)*8192; \
    const u16* larow = attnb + atb + (size_t)(n_)*4096; \
    _Pragma("unroll") \
    for(int ks = 0; ks < 4; ++ks){ \
      W_[ks] = *(const bf16x8*)&lwrow[(size_t)(i0w+cL)*128 + ks*32 + qq*8]; \
      Q_[ks] = *(const bf16x8*)&qbase[(size_t)(ls0 + i0w + cL)*128 + ks*32 + qq*8]; \
    } \
    _Pragma("unroll") \
    for(int ks = 0; ks < 2; ++ks) \
      A_[ks] = *(const bf16x8*)&larow[(size_t)(i0w+cL)*64 + ks*32 + qq*8]; \
    if((n_) < NCH-1){ \
      _Pragma("unroll") \
      for(int ks = 0; ks < 2; ++ks) \
        _Pragma("unroll") \
        for(int dt = 0; dt < 2; ++dt) \
          K_[ks*2+dt] = *(const bf16x8*)&kTb[(size_t)(d0w + dt*16 + cL)*SEQ + ls0 + ks*32 + qq*8]; \
    } \
    { \
      const u16* lurow = ub + uwb + (size_t)(n_)*8192; \
      U_ = *(const u16x4*)&lurow[(size_t)(tid>>2)*128 + cbb + (tid&3)*4]; \
    } \
    G_ = gcp[ls0 + lane]; \
  }

__global__ __launch_bounds__(256) void phaseB(const u16* __restrict__ qb, const u16* __restrict__ kbT,
      const u16* __restrict__ ub, const u16* __restrict__ wb, const u16* __restrict__ attnb,
      const float* __restrict__ gcb, u16* __restrict__ core){
  __shared__ __align__(16) u16 STbf[16][136];   // S^T: [16 c][128 d] + pad
  __shared__ __align__(16) u16 vnT[16][72];     // vn^T (for attn@vn)
  __shared__ __align__(16) u16 vnT2[16][72];    // (vn*e^{gl-gc})^T (for state update)
  __shared__ __align__(16) u16 uS[64][24];
  __shared__ float gcs2[2][64];                 // double-buffered: n&1
  __shared__ float egm2[2][64];
  const int f = blockIdx.x;              // 0..255
  const int xcd = f & 7, idx = f >> 3;   // idx 0..31
  const int h = xcd*4 + (idx >> 3);      // 0..31 (4 heads per XCD)
  const int split = idx & 7;             // 0..7
  const int cbb = split*16;              // state col base
  const int hk = h >> 1;
  const int tid = threadIdx.x;
  const int lane = tid & 63, wave = tid >> 6;
  const int cL = lane & 15, qq = lane >> 4;
  const int i0w = wave*16, d0w = wave*32;
  const float* gcp = gcb + (size_t)h*SEQ;
  const u16* qbase = qb + (size_t)hk*SEQ*DK;
  const u16* kTb   = kbT + (size_t)hk*DK*SEQ;
  const size_t uwb = (size_t)h*NCH*64*128;
  const size_t atb = (size_t)h*NCH*64*64;
  u16* corep = core + (size_t)h*SEQ*DV;
  f32x4 accS[2] = {};
  // prefetch chunk 0 operands
  bf16x8 cw[4], cq[4], ca[2], ck[4];
  u16x4 cu; float cg;
  PB_LOAD(0, cw, cq, ca, ck, cu, cg);
  for(int n = 0; n < NCH; ++n){
    const int s0 = n * CHUNK;
    const int pb = n & 1;
    // ---- top: STbf from accS; uS from prefetched regs; gc/egm (buffer pb) ----
    #pragma unroll
    for(int dt = 0; dt < 2; ++dt){
      u16x4 p;
      #pragma unroll
      for(int r = 0; r < 4; ++r) p[r] = f2bf(accS[dt][r]);
      *(u16x4*)&STbf[cL][d0w + dt*16 + qq*4] = p;
    }
    *(u16x4*)&uS[tid >> 2][(tid & 3)*4] = cu;
    if(wave == 0){
      gcs2[pb][lane] = cg;
      float gl = __shfl(cg, 63, 64);
      egm2[pb][lane] = __expf(gl - cg);
    }
    LDS_BAR();
    // ---- issue next chunk's prefetch (stays in flight across both barriers) ----
    bf16x8 nw_[4], nq_[4], na_[2], nk_[4];
    u16x4 nu; float ng;
    if(n+1 < NCH) PB_LOAD(n+1, nw_, nq_, na_, nk_, nu, ng);
    // ---- M1: vn = u - w@S; write vnT and vnT2 ----
    bf16x8 bS[4];
    f32x4 accvn = {};
    #pragma unroll
    for(int ks = 0; ks < 4; ++ks){
      bS[ks] = *(const bf16x8*)&STbf[cL][ks*32 + qq*8];
      accvn = __builtin_amdgcn_mfma_f32_16x16x32_bf16(cw[ks], bS[ks], accvn, 0, 0, 0);
    }
    {
      u16x4 p, p2;
      #pragma unroll
      for(int r = 0; r < 4; ++r){
        int i = i0w + qq*4 + r;
        float vnv = bf2f(uS[i][cL]) - accvn[r];
        p[r]  = f2bf(vnv);
        p2[r] = f2bf(vnv * egm2[pb][i]);
      }
      *(u16x4*)&vnT [cL][i0w + qq*4] = p;
      *(u16x4*)&vnT2[cL][i0w + qq*4] = p2;
    }
    LDS_BAR();
    // ---- tail: M2 o = q@S * e^gc; M3 o += attn@vn; store core; M4 state update ----
    f32x4 accO = {};
    #pragma unroll
    for(int ks = 0; ks < 4; ++ks)
      accO = __builtin_amdgcn_mfma_f32_16x16x32_bf16(cq[ks], bS[ks], accO, 0, 0, 0);
    #pragma unroll
    for(int r = 0; r < 4; ++r)
      accO[r] *= __expf(gcs2[pb][i0w + qq*4 + r]);
    #pragma unroll
    for(int ks = 0; ks < 2; ++ks){
      bf16x8 bV = *(const bf16x8*)&vnT[cL][ks*32 + qq*8];
      accO = __builtin_amdgcn_mfma_f32_16x16x32_bf16(ca[ks], bV, accO, 0, 0, 0);
    }
    #pragma unroll
    for(int r = 0; r < 4; ++r)
      corep[(size_t)(s0 + i0w + qq*4 + r)*DV + cbb + cL] = f2bf(accO[r]);
    if(n < NCH-1){
      float egl = __expf(gcs2[pb][63]);
      #pragma unroll
      for(int dt = 0; dt < 2; ++dt)
        accS[dt] *= egl;
      #pragma unroll
      for(int ks = 0; ks < 2; ++ks){
        bf16x8 bV2 = *(const bf16x8*)&vnT2[cL][ks*32 + qq*8];
        #pragma unroll
        for(int dt = 0; dt < 2; ++dt)
          accS[dt] = __builtin_amdgcn_mfma_f32_16x16x32_bf16(ck[ks*2+dt], bV2, accS[dt], 0, 0, 0);
      }
    }
    // (end-of-chunk barrier removed: BAR1 of the next chunk provides the ordering)
    // ---- rotate prefetched registers (constant indices -> stays in VGPRs) ----
    if(n+1 < NCH){
      #pragma unroll
      for(int i = 0; i < 4; ++i){ cw[i] = nw_[i]; cq[i] = nq_[i]; ck[i] = nk_[i]; }
      ca[0] = na_[0]; ca[1] = na_[1];
      cu = nu; cg = ng;
    }
  }
}

// ---------------------------------------------------------------- gated RMSNorm * silu(z) -> bf16 (per batch)
// 8 rows per 256-thread block (2 rows concurrently x 4 iters): 8x fewer blocks.
__global__ __launch_bounds__(256) void norm_gate(const u16* __restrict__ core, const u16* __restrict__ z_bf,
      const float* __restrict__ nw, u16* __restrict__ core2){
  const int h = blockIdx.y;
  const int s0 = blockIdx.x * 8;
  const int t = threadIdx.x & 127;      // elem within row
  const int rh = threadIdx.x >> 7;      // row pair half: 0/1
  __shared__ float red[8][2];
  const float nwv = nw[t];
  #pragma unroll
  for(int i = 0; i < 8; i += 2){
    const int s = s0 + i + rh;
    float x = bf2f(core[((size_t)h*SEQ + s)*DV + t]);
    float sq = x*x;
    #pragma unroll
    for(int off = 1; off < 64; off <<= 1) sq += __shfl_xor(sq, off, 64);
    if((t & 63) == 0) red[i+rh][t >> 6] = sq;
    __syncthreads();
    float var = (red[i+rh][0] + red[i+rh][1]) * (1.f/128.f);
    float y = x * rsqrtf(var + 1e-6f) * nwv;
    float zv = bf2f(z_bf[(size_t)s*VAL_DIM + h*DV + t]);
    y *= zv / (1.f + __expf(-zv));
    core2[(size_t)s*VAL_DIM + h*DV + t] = f2bf(y);
  }
}

// ---------------------------------------------------------------- launch
extern "C" void kernel_launch(void* const* d_in, const int* in_sizes, int n_in,
                              void* d_out, int out_size, void* d_ws, size_t ws_size,
                              hipStream_t stream){
  (void)in_sizes; (void)n_in; (void)out_size;
  const float* hs     = (const float*)d_in[0];
  const float* W_qkv  = (const float*)d_in[1];
  const float* conv_w = (const float*)d_in[2];
  const float* W_z    = (const float*)d_in[3];
  const float* W_b    = (const float*)d_in[4];
  const float* W_a    = (const float*)d_in[5];
  const float* dt_b   = (const float*)d_in[6];
  const float* A_log  = (const float*)d_in[7];
  const float* norm_w = (const float*)d_in[8];
  const float* W_out  = (const float*)d_in[9];
  float* out = (float*)d_out;

  const size_t MB = 1024ULL*1024ULL;
  if (ws_size < 160*MB) return;   // diagnostic: clean absmax-fail if ws too small
  const bool big  = (ws_size >= 208*MB);   // persistent weight transposes
  const bool big2 = (ws_size >= 224*MB);   // + persistent per-batch hs_bf (single cast)

  char* ws = (char*)d_ws;
  // ws map: [0,64M)=B  [64,96M)=C  [96,128M)=E  [128,160M)=D
  //         [160,208M)=persistent weights (big)  [208,224M)=hs_bf (big2)
  u16*   mixed  = (u16*)ws;                      // B: gemm1 -> conv
  u16*   attnB  = (u16*)ws;                      // B[0,16M): phaseA -> phaseB
  u16*   core_b = (u16*)(ws + 16*MB);            // B[16,48M): phaseB -> norm
  float* betab  = (float*)(ws + 48*MB);          // B[48M..): proj -> phaseA
  float* gbuf   = (float*)(ws + 48*MB + 512*1024);
  float* gcbuf  = (float*)(ws + 49*MB);          // phaseA -> phaseB
  u16*   WoutT  = (u16*)ws;                      // B[0,16M): after norm_b1
  u16*   qb     = (u16*)(ws + 64*MB);            // C[0,16M)
  u16*   kb     = (u16*)(ws + 80*MB);            // C[16,32M)
  u16*   zb     = (u16*)(ws + 64*MB);            // C: gemm2 -> norm (q,k dead after phaseB/transpose_k)
  u16*   core2  = (u16*)(ws + 96*MB);            // E+D: 64M contiguous [8192][4096]
  u16*   vb     = (u16*)(ws + 128*MB);           // D: conv -> phaseA
  u16*   kbT    = (u16*)(ws + 144*MB);           // D[16,32M): transpose_k -> phaseB (v dead)
  // weight homes: persistent (big) or per-batch scratch
  u16*   WqkvT  = big ? (u16*)(ws + 160*MB) : (u16*)d_out;           // 32MB
  u16*   WzT    = big ? (u16*)(ws + 192*MB) : (u16*)(ws + 128*MB);   // 16MB
  // d_out scratch (64M): (non-big) WqkvT [0,32M) + hs_bf1 [32,48.7M) during gemm1;
  // u [0,32M) + w [32,64M) phaseA->phaseB; hs_bf2 [0,16.7M) for gemm2 (after phaseB).
  u16*   hs_bf1 = big2 ? (u16*)(ws + 208*MB) : (u16*)((char*)d_out + 32*MB);
  u16*   u_d    = (u16*)d_out;
  u16*   w_d    = (u16*)((char*)d_out + 32*MB);
  u16*   hs_bf2 = big2 ? (u16*)(ws + 208*MB) : (u16*)d_out;   // big2: same persistent buffer

  if(big){
    transpose_cast<<<dim3(CONV_DIM/32, HID/32), 256, 0, stream>>>(W_qkv, WqkvT, HID, CONV_DIM);
    transpose_cast<<<dim3(VAL_DIM/32,  HID/32), 256, 0, stream>>>(W_z,   WzT,   HID, VAL_DIM);
  }
  for(int b = 0; b < BB; ++b){
    const float* hs_b = hs + (size_t)b*SEQ*HID;
    u16* core2_b = core2 + (size_t)b*SEQ*VAL_DIM;
    cast_bf<<<1024, 256, 0, stream>>>(hs_b, hs_bf1, SEQ*HID/8);
    if(!big) transpose_cast<<<dim3(CONV_DIM/32, HID/32), 256, 0, stream>>>(W_qkv, WqkvT, HID, CONV_DIM);
    gemm256<u16><<<dim3(CONV_DIM/256, SEQ/256), 512, 0, stream>>>(hs_bf1, WqkvT, mixed, SEQ, CONV_DIM, HID);
    conv_qkv<<<dim3(64, SEQ/CTS), 128, 0, stream>>>(mixed, conv_w, qb, kb, vb);
    proj_bg<<<SEQ/4, 256, 0, stream>>>(hs_b, W_b, W_a, dt_b, A_log, betab, gbuf);
    phaseA<<<dim3(NCH, HV), 256, 0, stream>>>(qb, kb, vb, betab, gbuf, gcbuf, u_d, w_d, attnB);
    transpose_k<<<dim3(SEQ/32, DK/32, HK), 256, 0, stream>>>(kb, kbT);   // after phaseA (vb dead)
    phaseB<<<256, 256, 0, stream>>>(qb, kbT, u_d, w_d, attnB, gcbuf, core_b);
    if(!big2) cast_bf<<<1024, 256, 0, stream>>>(hs_b, hs_bf2, SEQ*HID/8);
    if(!big) transpose_cast<<<dim3(VAL_DIM/32, HID/32), 256, 0, stream>>>(W_z, WzT, HID, VAL_DIM);
    gemm256<u16><<<dim3(VAL_DIM/256, SEQ/256), 512, 0, stream>>>(hs_bf2, WzT, zb, SEQ, VAL_DIM, HID);
    norm_gate<<<dim3(SEQ/8, HV), 256, 0, stream>>>(core_b, zb, norm_w, core2_b);
  }
  transpose_cast<<<dim3(HID/32, VAL_DIM/32), 256, 0, stream>>>(W_out, WoutT, VAL_DIM, HID);
  gemm256<float><<<dim3(HID/256, BS/256), 512, 0, stream>>>(core2, WoutT, out, BS, HID, VAL_DIM);
}